// Round 1
// baseline (1688.243 us; speedup 1.0000x reference)
//
#include <hip/hip_runtime.h>
#include <math.h>

namespace {

constexpr int NROW = 32768;   // BS*A rows
constexpr int IN_F = 96;
constexpr int HDIM = 64;
constexpr int DH   = 512;     // latent half-dim

__device__ __forceinline__ float sigmoidf_(float x) { return 1.f / (1.f + __expf(-x)); }
__device__ __forceinline__ float lrelu_(float x) { return x > 0.f ? x : 0.01f * x; }

// K1: x = relu(inputs @ fc1_w^T + b) -> xT [64][N]
__global__ __launch_bounds__(256) void k_fc1(const float* __restrict__ in,
    const float* __restrict__ w, const float* __restrict__ bias,
    float* __restrict__ xT) {
  int t = threadIdx.x;
  int n = blockIdx.x * 128 + (t & 127);
  int half = t >> 7;
  float inr[IN_F];
  const float4* p4 = (const float4*)(in + (size_t)n * IN_F);
#pragma unroll
  for (int k4 = 0; k4 < IN_F / 4; ++k4) {
    float4 v = p4[k4];
    inr[4 * k4] = v.x; inr[4 * k4 + 1] = v.y; inr[4 * k4 + 2] = v.z; inr[4 * k4 + 3] = v.w;
  }
  int c0 = half * 32;
#pragma unroll 1
  for (int c = c0; c < c0 + 32; ++c) {
    float acc = bias[c];
#pragma unroll
    for (int k = 0; k < IN_F; ++k) acc = fmaf(inr[k], w[c * IN_F + k], acc);
    xT[(size_t)c * NROW + n] = fmaxf(acc, 0.f);
  }
}

// K2: GRU -> hT [64][N] (transposed) and h row-major to d_out
__global__ __launch_bounds__(256) void k_gru(const float* __restrict__ xT,
    const float* __restrict__ hprev,
    const float* __restrict__ wih, const float* __restrict__ whh,
    const float* __restrict__ bih, const float* __restrict__ bhh,
    float* __restrict__ hT, float* __restrict__ hout) {
  int t = threadIdx.x;
  int n = blockIdx.x * 64 + (t & 63);
  int cq = t >> 6;  // 0..3 -> c in [cq*16, cq*16+16)
  float xv[HDIM], hv[HDIM];
#pragma unroll 1
  for (int k = 0; k < HDIM; ++k) xv[k] = xT[(size_t)k * NROW + n];
  const float4* p4 = (const float4*)(hprev + (size_t)n * HDIM);
#pragma unroll
  for (int k4 = 0; k4 < HDIM / 4; ++k4) {
    float4 v = p4[k4];
    hv[4 * k4] = v.x; hv[4 * k4 + 1] = v.y; hv[4 * k4 + 2] = v.z; hv[4 * k4 + 3] = v.w;
  }
  float hb[16];
  int c0 = cq * 16;
#pragma unroll 1
  for (int ci = 0; ci < 16; ++ci) {
    int c = c0 + ci;
    float ir = bih[c], iz = bih[64 + c], in_ = bih[128 + c];
    float hr = bhh[c], hz = bhh[64 + c], hn = bhh[128 + c];
#pragma unroll
    for (int k = 0; k < HDIM; ++k) {
      float a = xv[k], b = hv[k];
      ir = fmaf(a, wih[c * HDIM + k], ir);
      iz = fmaf(a, wih[(64 + c) * HDIM + k], iz);
      in_ = fmaf(a, wih[(128 + c) * HDIM + k], in_);
      hr = fmaf(b, whh[c * HDIM + k], hr);
      hz = fmaf(b, whh[(64 + c) * HDIM + k], hz);
      hn = fmaf(b, whh[(128 + c) * HDIM + k], hn);
    }
    float r = sigmoidf_(ir + hr);
    float z = sigmoidf_(iz + hz);
    float nn_ = tanhf(in_ + r * hn);
    float hc = (1.f - z) * nn_ + z * hv[c];
    hT[(size_t)c * NROW + n] = hc;
    hb[ci] = hc;
  }
  float4* o4 = (float4*)(hout + (size_t)n * HDIM + c0);
#pragma unroll
  for (int i4 = 0; i4 < 4; ++i4)
    o4[i4] = make_float4(hb[4 * i4], hb[4 * i4 + 1], hb[4 * i4 + 2], hb[4 * i4 + 3]);
}

// K3: q, query(scaled), z1 heads + BN partial sums per block
__global__ __launch_bounds__(256) void k_heads(const float* __restrict__ hT,
    const float* __restrict__ fc2w, const float* __restrict__ fc2b,
    const float* __restrict__ wqw, const float* __restrict__ wqb,
    const float* __restrict__ ew1, const float* __restrict__ eb1,
    float* __restrict__ qT, float* __restrict__ queryT, float* __restrict__ z1T,
    float* __restrict__ part) {
  int t = threadIdx.x;
  int n = blockIdx.x * 64 + (t & 63);
  int cq = t >> 6;
  float hv[HDIM];
#pragma unroll 1
  for (int k = 0; k < HDIM; ++k) hv[k] = hT[(size_t)k * NROW + n];
#pragma unroll 1
  for (int ci = 0; ci < 4; ++ci) {
    int c = cq * 4 + ci;
    float acc = fc2b[c];
#pragma unroll
    for (int k = 0; k < HDIM; ++k) acc = fmaf(hv[k], fc2w[c * HDIM + k], acc);
    qT[(size_t)c * NROW + n] = acc;
  }
  const float qs = 0.17677669529663687f;  // 1/sqrt(32)
#pragma unroll 1
  for (int ai = 0; ai < 8; ++ai) {
    int a = cq * 8 + ai;
    float acc = wqb[a];
#pragma unroll
    for (int k = 0; k < HDIM; ++k) acc = fmaf(hv[k], wqw[a * HDIM + k], acc);
    queryT[(size_t)a * NROW + n] = acc * qs;
  }
  __shared__ float ssum[64], ssq[64];
#pragma unroll 1
  for (int ci = 0; ci < 16; ++ci) {
    int c = cq * 16 + ci;
    float acc = eb1[c];
#pragma unroll
    for (int k = 0; k < HDIM; ++k) acc = fmaf(hv[k], ew1[c * HDIM + k], acc);
    z1T[(size_t)c * NROW + n] = acc;
    float s1 = acc, s2 = acc * acc;
#pragma unroll
    for (int off = 32; off > 0; off >>= 1) {
      s1 += __shfl_down(s1, off, 64);
      s2 += __shfl_down(s2, off, 64);
    }
    if ((t & 63) == 0) { ssum[c] = s1; ssq[c] = s2; }
  }
  __syncthreads();
  if (t < 64) {
    part[(size_t)blockIdx.x * 128 + t] = ssum[t];
    part[(size_t)blockIdx.x * 128 + 64 + t] = ssq[t];
  }
}

// K4: finalize BN stats: stat[c]=bn_g*rstd, stat[64+c]=bn_b-mean*that
__global__ void k_bnstat(const float* __restrict__ part,
    const float* __restrict__ bng, const float* __restrict__ bnb,
    float* __restrict__ stat) {
  int c = threadIdx.x;  // 64 threads
  float s1 = 0.f, s2 = 0.f;
  for (int b = 0; b < 512; ++b) {
    s1 += part[(size_t)b * 128 + c];
    s2 += part[(size_t)b * 128 + 64 + c];
  }
  float mean = s1 * (1.f / NROW);
  float var = s2 * (1.f / NROW) - mean * mean;
  float rstd = rsqrtf(var + 1e-5f);
  float sc = bng[c] * rstd;
  stat[c] = sc;
  stat[64 + c] = bnb[c] - mean * sc;
}

// K5: BN+lrelu -> emb_w2 -> latent (latT [512][N]) ; key -> alpha softmax (alphaT [32][N])
__global__ __launch_bounds__(256) void k_emb(const float* __restrict__ z1T,
    const float* __restrict__ stat,
    const float* __restrict__ ew2, const float* __restrict__ eb2,
    const float* __restrict__ eps, const float* __restrict__ queryT,
    const float* __restrict__ wkw, const float* __restrict__ wkb,
    float* __restrict__ latT, float* __restrict__ alphaT) {
  int t = threadIdx.x;
  int r = t & 63;
  int jq = t >> 6;  // handles j in [jq*8, jq*8+8)
  int n = blockIdx.x * 64 + r;
  float zr[64];
#pragma unroll 1
  for (int k = 0; k < 64; ++k)
    zr[k] = lrelu_(fmaf(stat[k], z1T[(size_t)k * NROW + n], stat[64 + k]));
  float qr[32];
#pragma unroll 1
  for (int a = 0; a < 32; ++a) qr[a] = queryT[(size_t)a * NROW + n];
  __shared__ float alBuf[64 * 33];
  int idiag = n & 31;
  float alj[8];
#pragma unroll 1
  for (int jj = 0; jj < 8; ++jj) {
    int j = jq * 8 + jj;
    float er[16];
    const float4* e4 = (const float4*)(eps + (size_t)n * DH + j * 16);
#pragma unroll
    for (int l4 = 0; l4 < 4; ++l4) {
      float4 v = e4[l4];
      er[4 * l4] = v.x; er[4 * l4 + 1] = v.y; er[4 * l4 + 2] = v.z; er[4 * l4 + 3] = v.w;
    }
    float lat[16];
#pragma unroll
    for (int l = 0; l < 16; ++l) {
      int o = j * 16 + l;
      float mu = eb2[o], lv = eb2[DH + o];
#pragma unroll
      for (int k = 0; k < 64; ++k) {
        mu = fmaf(zr[k], ew2[(size_t)o * 64 + k], mu);
        lv = fmaf(zr[k], ew2[(size_t)(DH + o) * 64 + k], lv);
      }
      float var = fmaxf(__expf(lv), 0.002f);
      float lt = fmaf(sqrtf(var), er[l], mu);
      lat[l] = lt;
      latT[(size_t)o * NROW + n] = lt;
    }
    float aj = 0.f;
#pragma unroll
    for (int a = 0; a < 32; ++a) {
      float ka = wkb[a];
#pragma unroll
      for (int l = 0; l < 16; ++l) ka = fmaf(lat[l], wkw[a * 16 + l], ka);
      aj = fmaf(qr[a], ka, aj);
    }
    alj[jj] = (j == idiag) ? -1e9f : aj;
    alBuf[r * 33 + j] = alj[jj];
  }
  __syncthreads();
  float m = -1e30f;
#pragma unroll 1
  for (int j = 0; j < 32; ++j) m = fmaxf(m, alBuf[r * 33 + j]);
  float se = 0.f;
#pragma unroll 1
  for (int j = 0; j < 32; ++j) se += __expf(alBuf[r * 33 + j] - m);
  float inv = 1.f / se;
#pragma unroll 1
  for (int jj = 0; jj < 8; ++jj) {
    int j = jq * 8 + jj;
    alphaT[(size_t)j * NROW + n] = __expf(alj[jj] - m) * inv;
  }
}

// K7: per (b, j-half): hp = msg_w1[:, :64] @ h3 ; msg latent part ; w2 ; weighted agg ; + q
__global__ __launch_bounds__(256) void k_msg(const float* __restrict__ hT,
    const float* __restrict__ latT, const float* __restrict__ alphaT,
    const float* __restrict__ qT,
    const float* __restrict__ w1, const float* __restrict__ b1,
    const float* __restrict__ w2, const float* __restrict__ b2,
    float* __restrict__ out) {
  int t = threadIdx.x;
  int b = blockIdx.x >> 1;
  int jh = (blockIdx.x & 1) * 16;  // j base within [0,32)
  __shared__ float latL[32 * 273];   // i*273 + j'*17 + l
  __shared__ float h3L[16 * 65];     // j'*65 + k
  __shared__ float hpL[16 * 65];     // j'*65 + c
  __shared__ float alL[32 * 17];     // i*17 + j'
  __shared__ float aggL[16 * 16 * 16];  // (g*16+j')*16 + nn
  int base_n = b * 32;
  for (int idx = t; idx < 16 * 64; idx += 256) {
    int k = idx >> 4, jp = idx & 15;
    h3L[jp * 65 + k] = hT[(size_t)k * NROW + base_n + jh + jp];
  }
  for (int idx = t; idx < 8192; idx += 256) {
    int i = idx & 31, ol = idx >> 5;  // ol = j'*16 + l
    int jp = ol >> 4, l = ol & 15;
    latL[i * 273 + jp * 17 + l] = latT[(size_t)(jh * 16 + ol) * NROW + base_n + i];
  }
  for (int idx = t; idx < 512; idx += 256) {
    int i = idx & 31, jp = idx >> 5;
    alL[i * 17 + jp] = alphaT[(size_t)(jh + jp) * NROW + base_n + i];
  }
  __syncthreads();
  {
    int c = t & 63;
    int j0 = t >> 6;
#pragma unroll 1
    for (int jj = 0; jj < 4; ++jj) {
      int jp = j0 + jj * 4;
      float acc = b1[c];
#pragma unroll
      for (int k = 0; k < 64; ++k) acc = fmaf(h3L[jp * 65 + k], w1[c * 80 + k], acc);
      hpL[jp * 65 + c] = acc;
    }
  }
  __syncthreads();
  int jp = t & 15;
  int g = t >> 4;  // 0..15
  float aggp[16];
#pragma unroll
  for (int nn = 0; nn < 16; ++nn) aggp[nn] = 0.f;
#pragma unroll 1
  for (int ii = 0; ii < 2; ++ii) {
    int i = g + ii * 16;
    float lat[16];
#pragma unroll
    for (int l = 0; l < 16; ++l) lat[l] = latL[i * 273 + jp * 17 + l];
    float aw = alL[i * 17 + jp];
    float m1[64];
#pragma unroll 1
    for (int c = 0; c < 64; ++c) {
      float acc = hpL[jp * 65 + c];
#pragma unroll
      for (int l = 0; l < 16; ++l) acc = fmaf(lat[l], w1[c * 80 + 64 + l], acc);
      m1[c] = lrelu_(acc);
    }
#pragma unroll 1
    for (int nn = 0; nn < 16; ++nn) {
      float acc = b2[nn];
#pragma unroll
      for (int c = 0; c < 64; ++c) acc = fmaf(m1[c], w2[nn * 64 + c], acc);
      aggp[nn] = fmaf(aw, acc, aggp[nn]);
    }
  }
  float4* ag4 = (float4*)&aggL[t * 16];
#pragma unroll
  for (int n4 = 0; n4 < 4; ++n4)
    ag4[n4] = make_float4(aggp[4 * n4], aggp[4 * n4 + 1], aggp[4 * n4 + 2], aggp[4 * n4 + 3]);
  __syncthreads();
  // reduce over g groups; thread t -> (j' = t>>4, nn = t&15)
  float acc = qT[(size_t)(t & 15) * NROW + base_n + jh + (t >> 4)];
#pragma unroll 1
  for (int g2 = 0; g2 < 16; ++g2) acc += aggL[g2 * 256 + t];
  out[(size_t)b * 512 + jh * 16 + t] = acc;
}

}  // namespace

extern "C" void kernel_launch(void* const* d_in, const int* in_sizes, int n_in,
                              void* d_out, int out_size, void* d_ws, size_t ws_size,
                              hipStream_t stream) {
  (void)in_sizes; (void)n_in; (void)out_size; (void)ws_size;
  const float* inputs = (const float*)d_in[0];
  const float* hidden = (const float*)d_in[1];
  const float* eps    = (const float*)d_in[2];
  const float* fc1w   = (const float*)d_in[3];
  const float* fc1b   = (const float*)d_in[4];
  const float* wih    = (const float*)d_in[5];
  const float* whh    = (const float*)d_in[6];
  const float* bih    = (const float*)d_in[7];
  const float* bhh    = (const float*)d_in[8];
  const float* fc2w   = (const float*)d_in[9];
  const float* fc2b   = (const float*)d_in[10];
  const float* ew1    = (const float*)d_in[11];
  const float* eb1    = (const float*)d_in[12];
  const float* bng    = (const float*)d_in[13];
  const float* bnb    = (const float*)d_in[14];
  const float* ew2    = (const float*)d_in[15];
  const float* eb2    = (const float*)d_in[16];
  const float* w1     = (const float*)d_in[17];
  const float* b1     = (const float*)d_in[18];
  const float* w2     = (const float*)d_in[19];
  const float* b2     = (const float*)d_in[20];
  const float* wqw    = (const float*)d_in[21];
  const float* wqb    = (const float*)d_in[22];
  const float* wkw    = (const float*)d_in[23];
  const float* wkb    = (const float*)d_in[24];

  float* ws = (float*)d_ws;
  float* hT     = ws;                 // 2097152
  float* qT     = ws + 2097152;       // 524288
  float* queryT = ws + 2621440;       // 1048576
  float* z1T    = ws + 3670016;       // 2097152
  float* part   = ws + 5767168;       // 65536
  float* stat   = ws + 5832704;       // 128
  float* latT   = ws + 5832832;       // 16777216
  float* xT     = latT;               // aliased: xT dead before K5 writes latT
  float* alphaT = ws + 22610048;      // 1048576

  float* out_q = (float*)d_out;             // 32768 x 16
  float* out_h = (float*)d_out + 524288;    // 32768 x 64

  hipLaunchKernelGGL(k_fc1, dim3(256), dim3(256), 0, stream, inputs, fc1w, fc1b, xT);
  hipLaunchKernelGGL(k_gru, dim3(512), dim3(256), 0, stream, xT, hidden, wih, whh, bih, bhh, hT, out_h);
  hipLaunchKernelGGL(k_heads, dim3(512), dim3(256), 0, stream, hT, fc2w, fc2b, wqw, wqb, ew1, eb1, qT, queryT, z1T, part);
  hipLaunchKernelGGL(k_bnstat, dim3(1), dim3(64), 0, stream, part, bng, bnb, stat);
  hipLaunchKernelGGL(k_emb, dim3(512), dim3(256), 0, stream, z1T, stat, ew2, eb2, eps, queryT, wkw, wkb, latT, alphaT);
  hipLaunchKernelGGL(k_msg, dim3(2048), dim3(256), 0, stream, hT, latT, alphaT, qT, w1, b1, w2, b2, out_q);
}

// Round 2
// 922.337 us; speedup vs baseline: 1.8304x; 1.8304x over previous
//
#include <hip/hip_runtime.h>
#include <math.h>

namespace {

constexpr int NROW = 32768;   // BS*A rows
constexpr int IN_F = 96;
constexpr int HDIM = 64;
constexpr int DH   = 512;     // latent half-dim

typedef __attribute__((ext_vector_type(8))) short bf16x8;
typedef __attribute__((ext_vector_type(4))) float f32x4;

__device__ __forceinline__ float sigmoidf_(float x) { return 1.f / (1.f + __expf(-x)); }
__device__ __forceinline__ float lrelu_(float x) { return x > 0.f ? x : 0.01f * x; }
__device__ __forceinline__ unsigned f2bf(float x) {  // RNE float->bf16 (as low 16 bits)
  unsigned u = __float_as_uint(x);
  return (u + 0x7fffu + ((u >> 16) & 1u)) >> 16;
}

// K1: x = relu(inputs @ fc1_w^T + b) -> xT [64][N]
__global__ __launch_bounds__(256) void k_fc1(const float* __restrict__ in,
    const float* __restrict__ w, const float* __restrict__ bias,
    float* __restrict__ xT) {
  int t = threadIdx.x;
  int n = blockIdx.x * 128 + (t & 127);
  int half = t >> 7;
  float inr[IN_F];
  const float4* p4 = (const float4*)(in + (size_t)n * IN_F);
#pragma unroll
  for (int k4 = 0; k4 < IN_F / 4; ++k4) {
    float4 v = p4[k4];
    inr[4 * k4] = v.x; inr[4 * k4 + 1] = v.y; inr[4 * k4 + 2] = v.z; inr[4 * k4 + 3] = v.w;
  }
  int c0 = half * 32;
#pragma unroll 1
  for (int c = c0; c < c0 + 32; ++c) {
    float acc = bias[c];
#pragma unroll
    for (int k = 0; k < IN_F; ++k) acc = fmaf(inr[k], w[c * IN_F + k], acc);
    xT[(size_t)c * NROW + n] = fmaxf(acc, 0.f);
  }
}

// K2: GRU -> hT [64][N] (transposed) and h row-major to d_out
__global__ __launch_bounds__(256) void k_gru(const float* __restrict__ xT,
    const float* __restrict__ hprev,
    const float* __restrict__ wih, const float* __restrict__ whh,
    const float* __restrict__ bih, const float* __restrict__ bhh,
    float* __restrict__ hT, float* __restrict__ hout) {
  int t = threadIdx.x;
  int n = blockIdx.x * 64 + (t & 63);
  int cq = t >> 6;  // 0..3 -> c in [cq*16, cq*16+16)
  float xv[HDIM], hv[HDIM];
#pragma unroll 1
  for (int k = 0; k < HDIM; ++k) xv[k] = xT[(size_t)k * NROW + n];
  const float4* p4 = (const float4*)(hprev + (size_t)n * HDIM);
#pragma unroll
  for (int k4 = 0; k4 < HDIM / 4; ++k4) {
    float4 v = p4[k4];
    hv[4 * k4] = v.x; hv[4 * k4 + 1] = v.y; hv[4 * k4 + 2] = v.z; hv[4 * k4 + 3] = v.w;
  }
  float hb[16];
  int c0 = cq * 16;
#pragma unroll 1
  for (int ci = 0; ci < 16; ++ci) {
    int c = c0 + ci;
    float ir = bih[c], iz = bih[64 + c], in_ = bih[128 + c];
    float hr = bhh[c], hz = bhh[64 + c], hn = bhh[128 + c];
#pragma unroll
    for (int k = 0; k < HDIM; ++k) {
      float a = xv[k], b = hv[k];
      ir = fmaf(a, wih[c * HDIM + k], ir);
      iz = fmaf(a, wih[(64 + c) * HDIM + k], iz);
      in_ = fmaf(a, wih[(128 + c) * HDIM + k], in_);
      hr = fmaf(b, whh[c * HDIM + k], hr);
      hz = fmaf(b, whh[(64 + c) * HDIM + k], hz);
      hn = fmaf(b, whh[(128 + c) * HDIM + k], hn);
    }
    float r = sigmoidf_(ir + hr);
    float z = sigmoidf_(iz + hz);
    float nn_ = tanhf(in_ + r * hn);
    float hc = (1.f - z) * nn_ + z * hv[c];
    hT[(size_t)c * NROW + n] = hc;
    hb[ci] = hc;
  }
  float4* o4 = (float4*)(hout + (size_t)n * HDIM + c0);
#pragma unroll
  for (int i4 = 0; i4 < 4; ++i4)
    o4[i4] = make_float4(hb[4 * i4], hb[4 * i4 + 1], hb[4 * i4 + 2], hb[4 * i4 + 3]);
}

// K3: q, query(scaled), z1 heads + BN partial sums per block
__global__ __launch_bounds__(256) void k_heads(const float* __restrict__ hT,
    const float* __restrict__ fc2w, const float* __restrict__ fc2b,
    const float* __restrict__ wqw, const float* __restrict__ wqb,
    const float* __restrict__ ew1, const float* __restrict__ eb1,
    float* __restrict__ qT, float* __restrict__ queryT, float* __restrict__ z1T,
    float* __restrict__ part) {
  int t = threadIdx.x;
  int n = blockIdx.x * 64 + (t & 63);
  int cq = t >> 6;
  float hv[HDIM];
#pragma unroll 1
  for (int k = 0; k < HDIM; ++k) hv[k] = hT[(size_t)k * NROW + n];
#pragma unroll 1
  for (int ci = 0; ci < 4; ++ci) {
    int c = cq * 4 + ci;
    float acc = fc2b[c];
#pragma unroll
    for (int k = 0; k < HDIM; ++k) acc = fmaf(hv[k], fc2w[c * HDIM + k], acc);
    qT[(size_t)c * NROW + n] = acc;
  }
  const float qs = 0.17677669529663687f;  // 1/sqrt(32)
#pragma unroll 1
  for (int ai = 0; ai < 8; ++ai) {
    int a = cq * 8 + ai;
    float acc = wqb[a];
#pragma unroll
    for (int k = 0; k < HDIM; ++k) acc = fmaf(hv[k], wqw[a * HDIM + k], acc);
    queryT[(size_t)a * NROW + n] = acc * qs;
  }
  __shared__ float ssum[64], ssq[64];
#pragma unroll 1
  for (int ci = 0; ci < 16; ++ci) {
    int c = cq * 16 + ci;
    float acc = eb1[c];
#pragma unroll
    for (int k = 0; k < HDIM; ++k) acc = fmaf(hv[k], ew1[c * HDIM + k], acc);
    z1T[(size_t)c * NROW + n] = acc;
    float s1 = acc, s2 = acc * acc;
#pragma unroll
    for (int off = 32; off > 0; off >>= 1) {
      s1 += __shfl_down(s1, off, 64);
      s2 += __shfl_down(s2, off, 64);
    }
    if ((t & 63) == 0) { ssum[c] = s1; ssq[c] = s2; }
  }
  __syncthreads();
  if (t < 64) {
    part[(size_t)blockIdx.x * 128 + t] = ssum[t];
    part[(size_t)blockIdx.x * 128 + 64 + t] = ssq[t];
  }
}

// K4: finalize BN stats: stat[c]=bn_g*rstd, stat[64+c]=bn_b-mean*that
__global__ void k_bnstat(const float* __restrict__ part,
    const float* __restrict__ bng, const float* __restrict__ bnb,
    float* __restrict__ stat) {
  int c = threadIdx.x;  // 64 threads
  float s1 = 0.f, s2 = 0.f;
  for (int b = 0; b < 512; ++b) {
    s1 += part[(size_t)b * 128 + c];
    s2 += part[(size_t)b * 128 + 64 + c];
  }
  float mean = s1 * (1.f / NROW);
  float var = s2 * (1.f / NROW) - mean * mean;
  float rstd = rsqrtf(var + 1e-5f);
  float sc = bng[c] * rstd;
  stat[c] = sc;
  stat[64 + c] = bnb[c] - mean * sc;
}

// K5 (new): MFMA bf16 GEMM: latent pre-act = lrelu(BN(z1)) @ ew2^T, fused var/eps epilogue.
// Block: 128 rows (n) x 64 cols (c in 0..511), with both mu (o=c) and lv (o=512+c) accums.
// Grid: (NROW/128) x 8 = 2048 blocks. 256 threads (4 waves; wave w owns n-rows w*32..w*32+31).
__global__ __launch_bounds__(256) void k_emb_gemm(const float* __restrict__ z1T,
    const float* __restrict__ stat,
    const float* __restrict__ ew2, const float* __restrict__ eb2,
    const float* __restrict__ eps,
    float* __restrict__ latT) {
  __shared__ char smem[36864];
  const int t = threadIdx.x;
  const int nb = blockIdx.x >> 3;
  const int cb = blockIdx.x & 7;
  const int n0 = nb * 128;
  const int c0 = cb * 64;

  unsigned* aU = (unsigned*)smem;                 // A: [128][36] uints (= [128][72] bf16, 144B rows)
  unsigned* bmU = (unsigned*)(smem + 18432);      // Wmu: [64][36]
  unsigned* blU = (unsigned*)(smem + 27648);      // Wlv: [64][36]

  // Stage A = bf16(lrelu(stat*z1 + shift)), rows n0..n0+127, k=0..63 (pairs)
#pragma unroll 1
  for (int i = 0; i < 16; ++i) {
    int idx = t + 256 * i;          // 0..4095
    int nl = idx & 127;
    int kp = idx >> 7;              // 0..31 (k pair)
    float v0 = z1T[(size_t)(2 * kp) * NROW + n0 + nl];
    float v1 = z1T[(size_t)(2 * kp + 1) * NROW + n0 + nl];
    v0 = lrelu_(fmaf(stat[2 * kp], v0, stat[64 + 2 * kp]));
    v1 = lrelu_(fmaf(stat[2 * kp + 1], v1, stat[64 + 2 * kp + 1]));
    aU[nl * 36 + kp] = f2bf(v0) | (f2bf(v1) << 16);
  }
  // Stage W tiles (mu rows c0..c0+63, lv rows 512+c0..)
  const float2* ew2_2 = (const float2*)ew2;
#pragma unroll 1
  for (int i = 0; i < 8; ++i) {
    int idx = t + 256 * i;          // 0..2047
    int kp = idx & 31;
    int cl = idx >> 5;              // 0..63
    float2 m2 = ew2_2[(size_t)(c0 + cl) * 32 + kp];
    float2 l2 = ew2_2[(size_t)(512 + c0 + cl) * 32 + kp];
    bmU[cl * 36 + kp] = f2bf(m2.x) | (f2bf(m2.y) << 16);
    blU[cl * 36 + kp] = f2bf(l2.x) | (f2bf(l2.y) << 16);
  }
  __syncthreads();

  const int w = t >> 6, l = t & 63;
  const int m = l & 15, g = l >> 4;
  const short* sA = (const short*)smem;
  const short* sBm = (const short*)(smem + 18432);
  const short* sBl = (const short*)(smem + 27648);

  f32x4 accm[2][4], accl[2][4];
#pragma unroll
  for (int mt = 0; mt < 2; ++mt)
#pragma unroll
    for (int ct = 0; ct < 4; ++ct) {
      accm[mt][ct] = (f32x4){0.f, 0.f, 0.f, 0.f};
      accl[mt][ct] = (f32x4){0.f, 0.f, 0.f, 0.f};
    }
  bf16x8 af[2][2];
#pragma unroll
  for (int mt = 0; mt < 2; ++mt)
#pragma unroll
    for (int ks = 0; ks < 2; ++ks)
      af[mt][ks] = *(const bf16x8*)(sA + (w * 32 + mt * 16 + m) * 72 + ks * 32 + g * 8);
#pragma unroll
  for (int ct = 0; ct < 4; ++ct) {
#pragma unroll
    for (int ks = 0; ks < 2; ++ks) {
      bf16x8 bm = *(const bf16x8*)(sBm + (ct * 16 + m) * 72 + ks * 32 + g * 8);
      bf16x8 bl = *(const bf16x8*)(sBl + (ct * 16 + m) * 72 + ks * 32 + g * 8);
#pragma unroll
      for (int mt = 0; mt < 2; ++mt) {
        accm[mt][ct] = __builtin_amdgcn_mfma_f32_16x16x32_bf16(af[mt][ks], bm, accm[mt][ct], 0, 0, 0);
        accl[mt][ct] = __builtin_amdgcn_mfma_f32_16x16x32_bf16(af[mt][ks], bl, accl[mt][ct], 0, 0, 0);
      }
    }
  }

  // Epilogue: mu + sqrt(max(exp(lv),.002)) * eps   (lane holds c = c0+ct*16+m, n = n0+w*32+mt*16+g*4+reg)
  float lat[2][4][4];
#pragma unroll
  for (int mt = 0; mt < 2; ++mt) {
    int nl = w * 32 + mt * 16 + g * 4;
#pragma unroll
    for (int reg = 0; reg < 4; ++reg) {
      const float* ep = eps + (size_t)(n0 + nl + reg) * DH + c0;
#pragma unroll
      for (int ct = 0; ct < 4; ++ct) {
        int cl = ct * 16 + m;
        float mu = accm[mt][ct][reg] + eb2[c0 + cl];
        float lv = accl[mt][ct][reg] + eb2[DH + c0 + cl];
        lat[mt][ct][reg] = fmaf(sqrtf(fmaxf(__expf(lv), 0.002f)), ep[cl], mu);
      }
    }
  }
  __syncthreads();
  // Transpose through LDS so latT[c][n] stores are lane<->n coalesced
  float* outF = (float*)smem;     // [64][133]
#pragma unroll
  for (int mt = 0; mt < 2; ++mt)
#pragma unroll
    for (int ct = 0; ct < 4; ++ct)
#pragma unroll
      for (int reg = 0; reg < 4; ++reg)
        outF[(ct * 16 + m) * 133 + w * 32 + mt * 16 + g * 4 + reg] = lat[mt][ct][reg];
  __syncthreads();
#pragma unroll 1
  for (int i = 0; i < 32; ++i) {
    int idx = t + 256 * i;        // 8192
    int nl = idx & 127;
    int cl = idx >> 7;            // 0..63
    latT[(size_t)(c0 + cl) * NROW + n0 + nl] = outF[cl * 133 + nl];
  }
}

// K6: key = latent @ wk^T ; alpha = softmax_j(query . key) with diagonal mask
__global__ __launch_bounds__(256) void k_alpha(const float* __restrict__ latT,
    const float* __restrict__ queryT,
    const float* __restrict__ wkw, const float* __restrict__ wkb,
    float* __restrict__ alphaT) {
  int t = threadIdx.x;
  int r = t & 63;
  int jq = t >> 6;  // handles j in [jq*8, jq*8+8)
  int n = blockIdx.x * 64 + r;
  float qr[32];
#pragma unroll 1
  for (int a = 0; a < 32; ++a) qr[a] = queryT[(size_t)a * NROW + n];
  __shared__ float alBuf[64 * 33];
  int idiag = n & 31;
  float alj[8];
#pragma unroll 1
  for (int jj = 0; jj < 8; ++jj) {
    int j = jq * 8 + jj;
    float lat[16];
#pragma unroll
    for (int l = 0; l < 16; ++l) lat[l] = latT[(size_t)(j * 16 + l) * NROW + n];
    float aj = 0.f;
#pragma unroll
    for (int a = 0; a < 32; ++a) {
      float ka = wkb[a];
#pragma unroll
      for (int l = 0; l < 16; ++l) ka = fmaf(lat[l], wkw[a * 16 + l], ka);
      aj = fmaf(qr[a], ka, aj);
    }
    alj[jj] = (j == idiag) ? -1e9f : aj;
    alBuf[r * 33 + j] = alj[jj];
  }
  __syncthreads();
  float m = -1e30f;
#pragma unroll 1
  for (int j = 0; j < 32; ++j) m = fmaxf(m, alBuf[r * 33 + j]);
  float se = 0.f;
#pragma unroll 1
  for (int j = 0; j < 32; ++j) se += __expf(alBuf[r * 33 + j] - m);
  float inv = 1.f / se;
#pragma unroll 1
  for (int jj = 0; jj < 8; ++jj) {
    int j = jq * 8 + jj;
    alphaT[(size_t)j * NROW + n] = __expf(alj[jj] - m) * inv;
  }
}

// K7: per (b, j-half): hp = msg_w1[:, :64] @ h3 ; msg latent part ; w2 ; weighted agg ; + q
__global__ __launch_bounds__(256) void k_msg(const float* __restrict__ hT,
    const float* __restrict__ latT, const float* __restrict__ alphaT,
    const float* __restrict__ qT,
    const float* __restrict__ w1, const float* __restrict__ b1,
    const float* __restrict__ w2, const float* __restrict__ b2,
    float* __restrict__ out) {
  int t = threadIdx.x;
  int b = blockIdx.x >> 1;
  int jh = (blockIdx.x & 1) * 16;  // j base within [0,32)
  __shared__ float latL[32 * 273];   // i*273 + j'*17 + l
  __shared__ float h3L[16 * 65];     // j'*65 + k
  __shared__ float hpL[16 * 65];     // j'*65 + c
  __shared__ float alL[32 * 17];     // i*17 + j'
  __shared__ float aggL[16 * 16 * 16];  // (g*16+j')*16 + nn
  int base_n = b * 32;
  for (int idx = t; idx < 16 * 64; idx += 256) {
    int k = idx >> 4, jp = idx & 15;
    h3L[jp * 65 + k] = hT[(size_t)k * NROW + base_n + jh + jp];
  }
  for (int idx = t; idx < 8192; idx += 256) {
    int i = idx & 31, ol = idx >> 5;  // ol = j'*16 + l
    int jp = ol >> 4, l = ol & 15;
    latL[i * 273 + jp * 17 + l] = latT[(size_t)(jh * 16 + ol) * NROW + base_n + i];
  }
  for (int idx = t; idx < 512; idx += 256) {
    int i = idx & 31, jp = idx >> 5;
    alL[i * 17 + jp] = alphaT[(size_t)(jh + jp) * NROW + base_n + i];
  }
  __syncthreads();
  {
    int c = t & 63;
    int j0 = t >> 6;
#pragma unroll 1
    for (int jj = 0; jj < 4; ++jj) {
      int jp = j0 + jj * 4;
      float acc = b1[c];
#pragma unroll
      for (int k = 0; k < 64; ++k) acc = fmaf(h3L[jp * 65 + k], w1[c * 80 + k], acc);
      hpL[jp * 65 + c] = acc;
    }
  }
  __syncthreads();
  int jp = t & 15;
  int g = t >> 4;  // 0..15
  float aggp[16];
#pragma unroll
  for (int nn = 0; nn < 16; ++nn) aggp[nn] = 0.f;
#pragma unroll 1
  for (int ii = 0; ii < 2; ++ii) {
    int i = g + ii * 16;
    float lat[16];
#pragma unroll
    for (int l = 0; l < 16; ++l) lat[l] = latL[i * 273 + jp * 17 + l];
    float aw = alL[i * 17 + jp];
    float m1[64];
#pragma unroll 1
    for (int c = 0; c < 64; ++c) {
      float acc = hpL[jp * 65 + c];
#pragma unroll
      for (int l = 0; l < 16; ++l) acc = fmaf(lat[l], w1[c * 80 + 64 + l], acc);
      m1[c] = lrelu_(acc);
    }
#pragma unroll 1
    for (int nn = 0; nn < 16; ++nn) {
      float acc = b2[nn];
#pragma unroll
      for (int c = 0; c < 64; ++c) acc = fmaf(m1[c], w2[nn * 64 + c], acc);
      aggp[nn] = fmaf(aw, acc, aggp[nn]);
    }
  }
  float4* ag4 = (float4*)&aggL[t * 16];
#pragma unroll
  for (int n4 = 0; n4 < 4; ++n4)
    ag4[n4] = make_float4(aggp[4 * n4], aggp[4 * n4 + 1], aggp[4 * n4 + 2], aggp[4 * n4 + 3]);
  __syncthreads();
  // reduce over g groups; thread t -> (j' = t>>4, nn = t&15)
  float acc = qT[(size_t)(t & 15) * NROW + base_n + jh + (t >> 4)];
#pragma unroll 1
  for (int g2 = 0; g2 < 16; ++g2) acc += aggL[g2 * 256 + t];
  out[(size_t)b * 512 + jh * 16 + t] = acc;
}

}  // namespace

extern "C" void kernel_launch(void* const* d_in, const int* in_sizes, int n_in,
                              void* d_out, int out_size, void* d_ws, size_t ws_size,
                              hipStream_t stream) {
  (void)in_sizes; (void)n_in; (void)out_size; (void)ws_size;
  const float* inputs = (const float*)d_in[0];
  const float* hidden = (const float*)d_in[1];
  const float* eps    = (const float*)d_in[2];
  const float* fc1w   = (const float*)d_in[3];
  const float* fc1b   = (const float*)d_in[4];
  const float* wih    = (const float*)d_in[5];
  const float* whh    = (const float*)d_in[6];
  const float* bih    = (const float*)d_in[7];
  const float* bhh    = (const float*)d_in[8];
  const float* fc2w   = (const float*)d_in[9];
  const float* fc2b   = (const float*)d_in[10];
  const float* ew1    = (const float*)d_in[11];
  const float* eb1    = (const float*)d_in[12];
  const float* bng    = (const float*)d_in[13];
  const float* bnb    = (const float*)d_in[14];
  const float* ew2    = (const float*)d_in[15];
  const float* eb2    = (const float*)d_in[16];
  const float* w1     = (const float*)d_in[17];
  const float* b1     = (const float*)d_in[18];
  const float* w2     = (const float*)d_in[19];
  const float* b2     = (const float*)d_in[20];
  const float* wqw    = (const float*)d_in[21];
  const float* wqb    = (const float*)d_in[22];
  const float* wkw    = (const float*)d_in[23];
  const float* wkb    = (const float*)d_in[24];

  float* ws = (float*)d_ws;
  float* hT     = ws;                 // 2097152
  float* qT     = ws + 2097152;       // 524288
  float* queryT = ws + 2621440;       // 1048576
  float* z1T    = ws + 3670016;       // 2097152
  float* part   = ws + 5767168;       // 65536
  float* stat   = ws + 5832704;       // 128
  float* latT   = ws + 5832832;       // 16777216
  float* xT     = latT;               // aliased: xT dead before latT is written
  float* alphaT = ws + 22610048;      // 1048576

  float* out_q = (float*)d_out;             // 32768 x 16
  float* out_h = (float*)d_out + 524288;    // 32768 x 64

  hipLaunchKernelGGL(k_fc1, dim3(256), dim3(256), 0, stream, inputs, fc1w, fc1b, xT);
  hipLaunchKernelGGL(k_gru, dim3(512), dim3(256), 0, stream, xT, hidden, wih, whh, bih, bhh, hT, out_h);
  hipLaunchKernelGGL(k_heads, dim3(512), dim3(256), 0, stream, hT, fc2w, fc2b, wqw, wqb, ew1, eb1, qT, queryT, z1T, part);
  hipLaunchKernelGGL(k_bnstat, dim3(1), dim3(64), 0, stream, part, bng, bnb, stat);
  hipLaunchKernelGGL(k_emb_gemm, dim3(2048), dim3(256), 0, stream, z1T, stat, ew2, eb2, eps, latT);
  hipLaunchKernelGGL(k_alpha, dim3(512), dim3(256), 0, stream, latT, queryT, wkw, wkb, alphaT);
  hipLaunchKernelGGL(k_msg, dim3(2048), dim3(256), 0, stream, hT, latT, alphaT, qT, w1, b1, w2, b2, out_q);
}

// Round 3
// 804.875 us; speedup vs baseline: 2.0975x; 1.1459x over previous
//
#include <hip/hip_runtime.h>
#include <math.h>

namespace {

constexpr int NROW = 32768;   // BS*A rows
constexpr int IN_F = 96;
constexpr int HDIM = 64;
constexpr int DH   = 512;     // latent half-dim

typedef __attribute__((ext_vector_type(8))) short bf16x8;
typedef __attribute__((ext_vector_type(4))) float f32x4;

__device__ __forceinline__ float sigmoidf_(float x) { return 1.f / (1.f + __expf(-x)); }
__device__ __forceinline__ float lrelu_(float x) { return x > 0.f ? x : 0.01f * x; }
__device__ __forceinline__ unsigned f2bf(float x) {  // RNE float->bf16 (as low 16 bits)
  unsigned u = __float_as_uint(x);
  return (u + 0x7fffu + ((u >> 16) & 1u)) >> 16;
}

// K1: x = relu(inputs @ fc1_w^T + b) -> xT [64][N]
__global__ __launch_bounds__(256) void k_fc1(const float* __restrict__ in,
    const float* __restrict__ w, const float* __restrict__ bias,
    float* __restrict__ xT) {
  int t = threadIdx.x;
  int n = blockIdx.x * 128 + (t & 127);
  int half = t >> 7;
  float inr[IN_F];
  const float4* p4 = (const float4*)(in + (size_t)n * IN_F);
#pragma unroll
  for (int k4 = 0; k4 < IN_F / 4; ++k4) {
    float4 v = p4[k4];
    inr[4 * k4] = v.x; inr[4 * k4 + 1] = v.y; inr[4 * k4 + 2] = v.z; inr[4 * k4 + 3] = v.w;
  }
  int c0 = half * 32;
#pragma unroll 1
  for (int c = c0; c < c0 + 32; ++c) {
    float acc = bias[c];
#pragma unroll
    for (int k = 0; k < IN_F; ++k) acc = fmaf(inr[k], w[c * IN_F + k], acc);
    xT[(size_t)c * NROW + n] = fmaxf(acc, 0.f);
  }
}

// K2: GRU -> hT [64][N] (transposed) and h row-major to d_out
__global__ __launch_bounds__(256) void k_gru(const float* __restrict__ xT,
    const float* __restrict__ hprev,
    const float* __restrict__ wih, const float* __restrict__ whh,
    const float* __restrict__ bih, const float* __restrict__ bhh,
    float* __restrict__ hT, float* __restrict__ hout) {
  int t = threadIdx.x;
  int n = blockIdx.x * 64 + (t & 63);
  int cq = t >> 6;  // 0..3 -> c in [cq*16, cq*16+16)
  float xv[HDIM], hv[HDIM];
#pragma unroll 1
  for (int k = 0; k < HDIM; ++k) xv[k] = xT[(size_t)k * NROW + n];
  const float4* p4 = (const float4*)(hprev + (size_t)n * HDIM);
#pragma unroll
  for (int k4 = 0; k4 < HDIM / 4; ++k4) {
    float4 v = p4[k4];
    hv[4 * k4] = v.x; hv[4 * k4 + 1] = v.y; hv[4 * k4 + 2] = v.z; hv[4 * k4 + 3] = v.w;
  }
  float hb[16];
  int c0 = cq * 16;
#pragma unroll 1
  for (int ci = 0; ci < 16; ++ci) {
    int c = c0 + ci;
    float ir = bih[c], iz = bih[64 + c], in_ = bih[128 + c];
    float hr = bhh[c], hz = bhh[64 + c], hn = bhh[128 + c];
#pragma unroll
    for (int k = 0; k < HDIM; ++k) {
      float a = xv[k], b = hv[k];
      ir = fmaf(a, wih[c * HDIM + k], ir);
      iz = fmaf(a, wih[(64 + c) * HDIM + k], iz);
      in_ = fmaf(a, wih[(128 + c) * HDIM + k], in_);
      hr = fmaf(b, whh[c * HDIM + k], hr);
      hz = fmaf(b, whh[(64 + c) * HDIM + k], hz);
      hn = fmaf(b, whh[(128 + c) * HDIM + k], hn);
    }
    float r = sigmoidf_(ir + hr);
    float z = sigmoidf_(iz + hz);
    float nn_ = tanhf(in_ + r * hn);
    float hc = (1.f - z) * nn_ + z * hv[c];
    hT[(size_t)c * NROW + n] = hc;
    hb[ci] = hc;
  }
  float4* o4 = (float4*)(hout + (size_t)n * HDIM + c0);
#pragma unroll
  for (int i4 = 0; i4 < 4; ++i4)
    o4[i4] = make_float4(hb[4 * i4], hb[4 * i4 + 1], hb[4 * i4 + 2], hb[4 * i4 + 3]);
}

// K3: q, query(scaled), z1 heads + BN partial sums per block
__global__ __launch_bounds__(256) void k_heads(const float* __restrict__ hT,
    const float* __restrict__ fc2w, const float* __restrict__ fc2b,
    const float* __restrict__ wqw, const float* __restrict__ wqb,
    const float* __restrict__ ew1, const float* __restrict__ eb1,
    float* __restrict__ qT, float* __restrict__ queryT, float* __restrict__ z1T,
    float* __restrict__ part) {
  int t = threadIdx.x;
  int n = blockIdx.x * 64 + (t & 63);
  int cq = t >> 6;
  float hv[HDIM];
#pragma unroll 1
  for (int k = 0; k < HDIM; ++k) hv[k] = hT[(size_t)k * NROW + n];
#pragma unroll 1
  for (int ci = 0; ci < 4; ++ci) {
    int c = cq * 4 + ci;
    float acc = fc2b[c];
#pragma unroll
    for (int k = 0; k < HDIM; ++k) acc = fmaf(hv[k], fc2w[c * HDIM + k], acc);
    qT[(size_t)c * NROW + n] = acc;
  }
  const float qs = 0.17677669529663687f;  // 1/sqrt(32)
#pragma unroll 1
  for (int ai = 0; ai < 8; ++ai) {
    int a = cq * 8 + ai;
    float acc = wqb[a];
#pragma unroll
    for (int k = 0; k < HDIM; ++k) acc = fmaf(hv[k], wqw[a * HDIM + k], acc);
    queryT[(size_t)a * NROW + n] = acc * qs;
  }
  __shared__ float ssum[64], ssq[64];
#pragma unroll 1
  for (int ci = 0; ci < 16; ++ci) {
    int c = cq * 16 + ci;
    float acc = eb1[c];
#pragma unroll
    for (int k = 0; k < HDIM; ++k) acc = fmaf(hv[k], ew1[c * HDIM + k], acc);
    z1T[(size_t)c * NROW + n] = acc;
    float s1 = acc, s2 = acc * acc;
#pragma unroll
    for (int off = 32; off > 0; off >>= 1) {
      s1 += __shfl_down(s1, off, 64);
      s2 += __shfl_down(s2, off, 64);
    }
    if ((t & 63) == 0) { ssum[c] = s1; ssq[c] = s2; }
  }
  __syncthreads();
  if (t < 64) {
    part[(size_t)blockIdx.x * 128 + t] = ssum[t];
    part[(size_t)blockIdx.x * 128 + 64 + t] = ssq[t];
  }
}

// K4: finalize BN stats: stat[c]=bn_g*rstd, stat[64+c]=bn_b-mean*that
__global__ void k_bnstat(const float* __restrict__ part,
    const float* __restrict__ bng, const float* __restrict__ bnb,
    float* __restrict__ stat) {
  int c = threadIdx.x;  // 64 threads
  float s1 = 0.f, s2 = 0.f;
  for (int b = 0; b < 512; ++b) {
    s1 += part[(size_t)b * 128 + c];
    s2 += part[(size_t)b * 128 + 64 + c];
  }
  float mean = s1 * (1.f / NROW);
  float var = s2 * (1.f / NROW) - mean * mean;
  float rstd = rsqrtf(var + 1e-5f);
  float sc = bng[c] * rstd;
  stat[c] = sc;
  stat[64 + c] = bnb[c] - mean * sc;
}

// K5: MFMA bf16 GEMM: latent pre-act = lrelu(BN(z1)) @ ew2^T, fused var/eps epilogue.
__global__ __launch_bounds__(256) void k_emb_gemm(const float* __restrict__ z1T,
    const float* __restrict__ stat,
    const float* __restrict__ ew2, const float* __restrict__ eb2,
    const float* __restrict__ eps,
    float* __restrict__ latT) {
  __shared__ char smem[36864];
  const int t = threadIdx.x;
  const int nb = blockIdx.x >> 3;
  const int cb = blockIdx.x & 7;
  const int n0 = nb * 128;
  const int c0 = cb * 64;

  unsigned* aU = (unsigned*)smem;                 // A: [128][36] uints (= [128][72] bf16)
  unsigned* bmU = (unsigned*)(smem + 18432);      // Wmu: [64][36]
  unsigned* blU = (unsigned*)(smem + 27648);      // Wlv: [64][36]

#pragma unroll 1
  for (int i = 0; i < 16; ++i) {
    int idx = t + 256 * i;          // 0..4095
    int nl = idx & 127;
    int kp = idx >> 7;              // 0..31 (k pair)
    float v0 = z1T[(size_t)(2 * kp) * NROW + n0 + nl];
    float v1 = z1T[(size_t)(2 * kp + 1) * NROW + n0 + nl];
    v0 = lrelu_(fmaf(stat[2 * kp], v0, stat[64 + 2 * kp]));
    v1 = lrelu_(fmaf(stat[2 * kp + 1], v1, stat[64 + 2 * kp + 1]));
    aU[nl * 36 + kp] = f2bf(v0) | (f2bf(v1) << 16);
  }
  const float2* ew2_2 = (const float2*)ew2;
#pragma unroll 1
  for (int i = 0; i < 8; ++i) {
    int idx = t + 256 * i;          // 0..2047
    int kp = idx & 31;
    int cl = idx >> 5;              // 0..63
    float2 m2 = ew2_2[(size_t)(c0 + cl) * 32 + kp];
    float2 l2 = ew2_2[(size_t)(512 + c0 + cl) * 32 + kp];
    bmU[cl * 36 + kp] = f2bf(m2.x) | (f2bf(m2.y) << 16);
    blU[cl * 36 + kp] = f2bf(l2.x) | (f2bf(l2.y) << 16);
  }
  __syncthreads();

  const int w = t >> 6, l = t & 63;
  const int m = l & 15, g = l >> 4;
  const short* sA = (const short*)smem;
  const short* sBm = (const short*)(smem + 18432);
  const short* sBl = (const short*)(smem + 27648);

  f32x4 accm[2][4], accl[2][4];
#pragma unroll
  for (int mt = 0; mt < 2; ++mt)
#pragma unroll
    for (int ct = 0; ct < 4; ++ct) {
      accm[mt][ct] = (f32x4){0.f, 0.f, 0.f, 0.f};
      accl[mt][ct] = (f32x4){0.f, 0.f, 0.f, 0.f};
    }
  bf16x8 af[2][2];
#pragma unroll
  for (int mt = 0; mt < 2; ++mt)
#pragma unroll
    for (int ks = 0; ks < 2; ++ks)
      af[mt][ks] = *(const bf16x8*)(sA + (w * 32 + mt * 16 + m) * 72 + ks * 32 + g * 8);
#pragma unroll
  for (int ct = 0; ct < 4; ++ct) {
#pragma unroll
    for (int ks = 0; ks < 2; ++ks) {
      bf16x8 bm = *(const bf16x8*)(sBm + (ct * 16 + m) * 72 + ks * 32 + g * 8);
      bf16x8 bl = *(const bf16x8*)(sBl + (ct * 16 + m) * 72 + ks * 32 + g * 8);
#pragma unroll
      for (int mt = 0; mt < 2; ++mt) {
        accm[mt][ct] = __builtin_amdgcn_mfma_f32_16x16x32_bf16(af[mt][ks], bm, accm[mt][ct], 0, 0, 0);
        accl[mt][ct] = __builtin_amdgcn_mfma_f32_16x16x32_bf16(af[mt][ks], bl, accl[mt][ct], 0, 0, 0);
      }
    }
  }

  float lat[2][4][4];
#pragma unroll
  for (int mt = 0; mt < 2; ++mt) {
    int nl = w * 32 + mt * 16 + g * 4;
#pragma unroll
    for (int reg = 0; reg < 4; ++reg) {
      const float* ep = eps + (size_t)(n0 + nl + reg) * DH + c0;
#pragma unroll
      for (int ct = 0; ct < 4; ++ct) {
        int cl = ct * 16 + m;
        float mu = accm[mt][ct][reg] + eb2[c0 + cl];
        float lv = accl[mt][ct][reg] + eb2[DH + c0 + cl];
        lat[mt][ct][reg] = fmaf(sqrtf(fmaxf(__expf(lv), 0.002f)), ep[cl], mu);
      }
    }
  }
  __syncthreads();
  float* outF = (float*)smem;     // [64][133]
#pragma unroll
  for (int mt = 0; mt < 2; ++mt)
#pragma unroll
    for (int ct = 0; ct < 4; ++ct)
#pragma unroll
      for (int reg = 0; reg < 4; ++reg)
        outF[(ct * 16 + m) * 133 + w * 32 + mt * 16 + g * 4 + reg] = lat[mt][ct][reg];
  __syncthreads();
#pragma unroll 1
  for (int i = 0; i < 32; ++i) {
    int idx = t + 256 * i;        // 8192
    int nl = idx & 127;
    int cl = idx >> 7;            // 0..63
    latT[(size_t)(c0 + cl) * NROW + n0 + nl] = outF[cl * 133 + nl];
  }
}

// K6 (new): alpha via factorization: logit[n,j] = (Wk^T q)[n] . lat[n,j] + q[n].kb
// One thread per row; 16 FMA per j instead of 544. Memory-bound on latT (64 MB).
__global__ __launch_bounds__(128) void k_alpha(const float* __restrict__ latT,
    const float* __restrict__ queryT,
    const float* __restrict__ wkw, const float* __restrict__ wkb,
    float* __restrict__ alphaT) {
  int n = blockIdx.x * 128 + threadIdx.x;
  float qr[32];
#pragma unroll
  for (int a = 0; a < 32; ++a) qr[a] = queryT[(size_t)a * NROW + n];
  float qk[16];
#pragma unroll
  for (int l = 0; l < 16; ++l) qk[l] = 0.f;
  float qb = 0.f;
#pragma unroll
  for (int a = 0; a < 32; ++a) {
    qb = fmaf(qr[a], wkb[a], qb);
#pragma unroll
    for (int l = 0; l < 16; ++l) qk[l] = fmaf(qr[a], wkw[a * 16 + l], qk[l]);
  }
  int idiag = n & 31;
  float al[32];
#pragma unroll 4
  for (int j = 0; j < 32; ++j) {
    float acc = qb;
#pragma unroll
    for (int l = 0; l < 16; ++l)
      acc = fmaf(latT[(size_t)(j * 16 + l) * NROW + n], qk[l], acc);
    al[j] = (j == idiag) ? -1e9f : acc;
  }
  float m = -1e30f;
#pragma unroll
  for (int j = 0; j < 32; ++j) m = fmaxf(m, al[j]);
  float se = 0.f;
#pragma unroll
  for (int j = 0; j < 32; ++j) { al[j] = __expf(al[j] - m); se += al[j]; }
  float inv = 1.f / se;
#pragma unroll
  for (int j = 0; j < 32; ++j)
    alphaT[(size_t)j * NROW + n] = al[j] * inv;
}

// K7: per (b, j-half): hp = msg_w1[:, :64] @ h3 ; msg latent part ; w2 ; weighted agg ; + q
__global__ __launch_bounds__(256) void k_msg(const float* __restrict__ hT,
    const float* __restrict__ latT, const float* __restrict__ alphaT,
    const float* __restrict__ qT,
    const float* __restrict__ w1, const float* __restrict__ b1,
    const float* __restrict__ w2, const float* __restrict__ b2,
    float* __restrict__ out) {
  int t = threadIdx.x;
  int b = blockIdx.x >> 1;
  int jh = (blockIdx.x & 1) * 16;  // j base within [0,32)
  __shared__ float latL[32 * 273];   // i*273 + j'*17 + l
  __shared__ float h3L[16 * 65];     // j'*65 + k
  __shared__ float hpL[16 * 65];     // j'*65 + c
  __shared__ float alL[32 * 17];     // i*17 + j'
  __shared__ float aggL[16 * 16 * 16];  // (g*16+j')*16 + nn
  int base_n = b * 32;
  for (int idx = t; idx < 16 * 64; idx += 256) {
    int k = idx >> 4, jp = idx & 15;
    h3L[jp * 65 + k] = hT[(size_t)k * NROW + base_n + jh + jp];
  }
  for (int idx = t; idx < 8192; idx += 256) {
    int i = idx & 31, ol = idx >> 5;  // ol = j'*16 + l
    int jp = ol >> 4, l = ol & 15;
    latL[i * 273 + jp * 17 + l] = latT[(size_t)(jh * 16 + ol) * NROW + base_n + i];
  }
  for (int idx = t; idx < 512; idx += 256) {
    int i = idx & 31, jp = idx >> 5;
    alL[i * 17 + jp] = alphaT[(size_t)(jh + jp) * NROW + base_n + i];
  }
  __syncthreads();
  {
    int c = t & 63;
    int j0 = t >> 6;
#pragma unroll 1
    for (int jj = 0; jj < 4; ++jj) {
      int jp = j0 + jj * 4;
      float acc = b1[c];
#pragma unroll
      for (int k = 0; k < 64; ++k) acc = fmaf(h3L[jp * 65 + k], w1[c * 80 + k], acc);
      hpL[jp * 65 + c] = acc;
    }
  }
  __syncthreads();
  int jp = t & 15;
  int g = t >> 4;  // 0..15
  float aggp[16];
#pragma unroll
  for (int nn = 0; nn < 16; ++nn) aggp[nn] = 0.f;
#pragma unroll 1
  for (int ii = 0; ii < 2; ++ii) {
    int i = g + ii * 16;
    float lat[16];
#pragma unroll
    for (int l = 0; l < 16; ++l) lat[l] = latL[i * 273 + jp * 17 + l];
    float aw = alL[i * 17 + jp];
    float m1[64];
#pragma unroll 1
    for (int c = 0; c < 64; ++c) {
      float acc = hpL[jp * 65 + c];
#pragma unroll
      for (int l = 0; l < 16; ++l) acc = fmaf(lat[l], w1[c * 80 + 64 + l], acc);
      m1[c] = lrelu_(acc);
    }
#pragma unroll 1
    for (int nn = 0; nn < 16; ++nn) {
      float acc = b2[nn];
#pragma unroll
      for (int c = 0; c < 64; ++c) acc = fmaf(m1[c], w2[nn * 64 + c], acc);
      aggp[nn] = fmaf(aw, acc, aggp[nn]);
    }
  }
  float4* ag4 = (float4*)&aggL[t * 16];
#pragma unroll
  for (int n4 = 0; n4 < 4; ++n4)
    ag4[n4] = make_float4(aggp[4 * n4], aggp[4 * n4 + 1], aggp[4 * n4 + 2], aggp[4 * n4 + 3]);
  __syncthreads();
  // reduce over g groups; thread t -> (j' = t>>4, nn = t&15)
  float acc = qT[(size_t)(t & 15) * NROW + base_n + jh + (t >> 4)];
#pragma unroll 1
  for (int g2 = 0; g2 < 16; ++g2) acc += aggL[g2 * 256 + t];
  out[(size_t)b * 512 + jh * 16 + t] = acc;
}

}  // namespace

extern "C" void kernel_launch(void* const* d_in, const int* in_sizes, int n_in,
                              void* d_out, int out_size, void* d_ws, size_t ws_size,
                              hipStream_t stream) {
  (void)in_sizes; (void)n_in; (void)out_size; (void)ws_size;
  const float* inputs = (const float*)d_in[0];
  const float* hidden = (const float*)d_in[1];
  const float* eps    = (const float*)d_in[2];
  const float* fc1w   = (const float*)d_in[3];
  const float* fc1b   = (const float*)d_in[4];
  const float* wih    = (const float*)d_in[5];
  const float* whh    = (const float*)d_in[6];
  const float* bih    = (const float*)d_in[7];
  const float* bhh    = (const float*)d_in[8];
  const float* fc2w   = (const float*)d_in[9];
  const float* fc2b   = (const float*)d_in[10];
  const float* ew1    = (const float*)d_in[11];
  const float* eb1    = (const float*)d_in[12];
  const float* bng    = (const float*)d_in[13];
  const float* bnb    = (const float*)d_in[14];
  const float* ew2    = (const float*)d_in[15];
  const float* eb2    = (const float*)d_in[16];
  const float* w1     = (const float*)d_in[17];
  const float* b1     = (const float*)d_in[18];
  const float* w2     = (const float*)d_in[19];
  const float* b2     = (const float*)d_in[20];
  const float* wqw    = (const float*)d_in[21];
  const float* wqb    = (const float*)d_in[22];
  const float* wkw    = (const float*)d_in[23];
  const float* wkb    = (const float*)d_in[24];

  float* ws = (float*)d_ws;
  float* hT     = ws;                 // 2097152
  float* qT     = ws + 2097152;       // 524288
  float* queryT = ws + 2621440;       // 1048576
  float* z1T    = ws + 3670016;       // 2097152
  float* part   = ws + 5767168;       // 65536
  float* stat   = ws + 5832704;       // 128
  float* latT   = ws + 5832832;       // 16777216
  float* xT     = latT;               // aliased: xT dead before latT is written
  float* alphaT = ws + 22610048;      // 1048576

  float* out_q = (float*)d_out;             // 32768 x 16
  float* out_h = (float*)d_out + 524288;    // 32768 x 64

  hipLaunchKernelGGL(k_fc1, dim3(256), dim3(256), 0, stream, inputs, fc1w, fc1b, xT);
  hipLaunchKernelGGL(k_gru, dim3(512), dim3(256), 0, stream, xT, hidden, wih, whh, bih, bhh, hT, out_h);
  hipLaunchKernelGGL(k_heads, dim3(512), dim3(256), 0, stream, hT, fc2w, fc2b, wqw, wqb, ew1, eb1, qT, queryT, z1T, part);
  hipLaunchKernelGGL(k_bnstat, dim3(1), dim3(64), 0, stream, part, bng, bnb, stat);
  hipLaunchKernelGGL(k_emb_gemm, dim3(2048), dim3(256), 0, stream, z1T, stat, ew2, eb2, eps, latT);
  hipLaunchKernelGGL(k_alpha, dim3(256), dim3(128), 0, stream, latT, queryT, wkw, wkb, alphaT);
  hipLaunchKernelGGL(k_msg, dim3(2048), dim3(256), 0, stream, hT, latT, alphaT, qT, w1, b1, w2, b2, out_q);
}

// Round 4
// 575.324 us; speedup vs baseline: 2.9344x; 1.3990x over previous
//
#include <hip/hip_runtime.h>
#include <math.h>

namespace {

constexpr int NROW = 32768;   // BS*A rows
constexpr int HDIM = 64;
constexpr int DH   = 512;     // latent half-dim

typedef __attribute__((ext_vector_type(8))) short bf16x8;
typedef __attribute__((ext_vector_type(4))) float f32x4;

__device__ __forceinline__ float sigmoidf_(float x) { return 1.f / (1.f + __expf(-x)); }
__device__ __forceinline__ float lrelu_(float x) { return x > 0.f ? x : 0.01f * x; }
__device__ __forceinline__ unsigned f2bf(float x) {  // RNE float->bf16 (as low 16 bits)
  unsigned u = __float_as_uint(x);
  return (u + 0x7fffu + ((u >> 16) & 1u)) >> 16;
}

// K1+K2 fused: x = relu(inputs @ fc1_w^T + b); GRU via 6 MFMA gate GEMMs.
// Per block: 128 rows. LDS-staged bf16 A/B tiles, fp32 accum, fp32 h_in in epilogue.
__global__ __launch_bounds__(256, 1) void k_fgru(
    const float* __restrict__ in,      // [N][96]
    const float* __restrict__ hprev,   // [N][64]
    const float* __restrict__ fc1w, const float* __restrict__ fc1b,
    const float* __restrict__ wih, const float* __restrict__ whh,
    const float* __restrict__ bih, const float* __restrict__ bhh,
    float* __restrict__ hT, float* __restrict__ hout) {
  __shared__ char smem[132096];
  const int t = threadIdx.x;
  const int n0 = blockIdx.x * 128;
  unsigned* inU  = (unsigned*)smem;                    // [128][52] (96 bf16/row + pad)
  unsigned* f1U  = (unsigned*)(smem + 26624);          // [64][52]
  unsigned* xU   = (unsigned*)(smem + 39936);          // [128][36] (64 bf16/row + pad)
  unsigned* hU   = (unsigned*)(smem + 58368);          // [128][36]
  unsigned* gU   = (unsigned*)(smem + 76800);          // [6][64][36] gates: ir,iz,in,hr,hz,hn
  float*    trF  = (float*)smem;                       // [64][133] overlaps inU/f1U (dead then)

  const float2* in2 = (const float2*)in;
#pragma unroll 1
  for (int i = 0; i < 24; ++i) {
    int idx = t + 256 * i;               // 128*48
    int nl = idx / 48, kp = idx - nl * 48;
    float2 v = in2[(size_t)(n0 + nl) * 48 + kp];
    inU[nl * 52 + kp] = f2bf(v.x) | (f2bf(v.y) << 16);
  }
  const float2* f1w2 = (const float2*)fc1w;
#pragma unroll 1
  for (int i = 0; i < 12; ++i) {
    int idx = t + 256 * i;               // 64*48
    int cl = idx / 48, kp = idx - cl * 48;
    float2 v = f1w2[cl * 48 + kp];
    f1U[cl * 52 + kp] = f2bf(v.x) | (f2bf(v.y) << 16);
  }
  const float2* h2 = (const float2*)hprev;
#pragma unroll 1
  for (int i = 0; i < 16; ++i) {
    int idx = t + 256 * i;               // 128*32
    int nl = idx >> 5, kp = idx & 31;
    float2 v = h2[(size_t)(n0 + nl) * 32 + kp];
    hU[nl * 36 + kp] = f2bf(v.x) | (f2bf(v.y) << 16);
  }
  const float2* wih2 = (const float2*)wih;
  const float2* whh2 = (const float2*)whh;
#pragma unroll 1
  for (int i = 0; i < 24; ++i) {
    int idx = t + 256 * i;               // 192*32
    int row = idx >> 5, kp = idx & 31;
    float2 v = wih2[row * 32 + kp];
    int gate = row >> 6, cl = row & 63;
    gU[(gate * 64 + cl) * 36 + kp] = f2bf(v.x) | (f2bf(v.y) << 16);
  }
#pragma unroll 1
  for (int i = 0; i < 24; ++i) {
    int idx = t + 256 * i;
    int row = idx >> 5, kp = idx & 31;
    float2 v = whh2[row * 32 + kp];
    int gate = row >> 6, cl = row & 63;
    gU[((gate + 3) * 64 + cl) * 36 + kp] = f2bf(v.x) | (f2bf(v.y) << 16);
  }
  __syncthreads();

  const int w = t >> 6, l = t & 63;
  const int m = l & 15, g = l >> 4;
  const short* inS = (const short*)inU;   // row stride 104 shorts
  const short* f1S = (const short*)f1U;
  short*       xS  = (short*)xU;          // row stride 72 shorts
  const short* hS  = (const short*)hU;
  const short* gS  = (const short*)gU;

  // ---- fc1 phase ----
  {
    f32x4 accx[2][4];
#pragma unroll
    for (int mt = 0; mt < 2; ++mt)
#pragma unroll
      for (int ct = 0; ct < 4; ++ct) accx[mt][ct] = (f32x4){0.f, 0.f, 0.f, 0.f};
    bf16x8 af[2][3];
#pragma unroll
    for (int mt = 0; mt < 2; ++mt)
#pragma unroll
      for (int ks = 0; ks < 3; ++ks)
        af[mt][ks] = *(const bf16x8*)(inS + (w * 32 + mt * 16 + m) * 104 + ks * 32 + g * 8);
#pragma unroll
    for (int ct = 0; ct < 4; ++ct)
#pragma unroll
      for (int ks = 0; ks < 3; ++ks) {
        bf16x8 bw = *(const bf16x8*)(f1S + (ct * 16 + m) * 104 + ks * 32 + g * 8);
#pragma unroll
        for (int mt = 0; mt < 2; ++mt)
          accx[mt][ct] = __builtin_amdgcn_mfma_f32_16x16x32_bf16(af[mt][ks], bw, accx[mt][ct], 0, 0, 0);
      }
#pragma unroll
    for (int mt = 0; mt < 2; ++mt)
#pragma unroll
      for (int ct = 0; ct < 4; ++ct) {
        int c = ct * 16 + m;
        float bc = fc1b[c];
#pragma unroll
        for (int reg = 0; reg < 4; ++reg) {
          int nl = w * 32 + mt * 16 + g * 4 + reg;
          float v = fmaxf(accx[mt][ct][reg] + bc, 0.f);
          xS[nl * 72 + c] = (short)f2bf(v);
        }
      }
  }
  __syncthreads();

  // ---- GRU phase ----
  bf16x8 ax[2][2], ah[2][2];
#pragma unroll
  for (int mt = 0; mt < 2; ++mt)
#pragma unroll
    for (int ks = 0; ks < 2; ++ks) {
      ax[mt][ks] = *(const bf16x8*)((const short*)xU + (w * 32 + mt * 16 + m) * 72 + ks * 32 + g * 8);
      ah[mt][ks] = *(const bf16x8*)(hS + (w * 32 + mt * 16 + m) * 72 + ks * 32 + g * 8);
    }
#pragma unroll 1
  for (int ct = 0; ct < 4; ++ct) {
    f32x4 a_ir[2], a_iz[2], a_in[2], a_hr[2], a_hz[2], a_hn[2];
#pragma unroll
    for (int mt = 0; mt < 2; ++mt) {
      a_ir[mt] = (f32x4){0.f, 0.f, 0.f, 0.f}; a_iz[mt] = (f32x4){0.f, 0.f, 0.f, 0.f};
      a_in[mt] = (f32x4){0.f, 0.f, 0.f, 0.f}; a_hr[mt] = (f32x4){0.f, 0.f, 0.f, 0.f};
      a_hz[mt] = (f32x4){0.f, 0.f, 0.f, 0.f}; a_hn[mt] = (f32x4){0.f, 0.f, 0.f, 0.f};
    }
    int crow = ct * 16 + m;
#pragma unroll
    for (int ks = 0; ks < 2; ++ks) {
      bf16x8 b0 = *(const bf16x8*)(gS + (0 * 64 + crow) * 72 + ks * 32 + g * 8);
      bf16x8 b1 = *(const bf16x8*)(gS + (1 * 64 + crow) * 72 + ks * 32 + g * 8);
      bf16x8 b2 = *(const bf16x8*)(gS + (2 * 64 + crow) * 72 + ks * 32 + g * 8);
      bf16x8 b3 = *(const bf16x8*)(gS + (3 * 64 + crow) * 72 + ks * 32 + g * 8);
      bf16x8 b4 = *(const bf16x8*)(gS + (4 * 64 + crow) * 72 + ks * 32 + g * 8);
      bf16x8 b5 = *(const bf16x8*)(gS + (5 * 64 + crow) * 72 + ks * 32 + g * 8);
#pragma unroll
      for (int mt = 0; mt < 2; ++mt) {
        a_ir[mt] = __builtin_amdgcn_mfma_f32_16x16x32_bf16(ax[mt][ks], b0, a_ir[mt], 0, 0, 0);
        a_iz[mt] = __builtin_amdgcn_mfma_f32_16x16x32_bf16(ax[mt][ks], b1, a_iz[mt], 0, 0, 0);
        a_in[mt] = __builtin_amdgcn_mfma_f32_16x16x32_bf16(ax[mt][ks], b2, a_in[mt], 0, 0, 0);
        a_hr[mt] = __builtin_amdgcn_mfma_f32_16x16x32_bf16(ah[mt][ks], b3, a_hr[mt], 0, 0, 0);
        a_hz[mt] = __builtin_amdgcn_mfma_f32_16x16x32_bf16(ah[mt][ks], b4, a_hz[mt], 0, 0, 0);
        a_hn[mt] = __builtin_amdgcn_mfma_f32_16x16x32_bf16(ah[mt][ks], b5, a_hn[mt], 0, 0, 0);
      }
    }
    int c = crow;
    float bir = bih[c], biz = bih[64 + c], bin = bih[128 + c];
    float bhr = bhh[c], bhz = bhh[64 + c], bhn = bhh[128 + c];
#pragma unroll
    for (int mt = 0; mt < 2; ++mt)
#pragma unroll
      for (int reg = 0; reg < 4; ++reg) {
        int nl = w * 32 + mt * 16 + g * 4 + reg;
        float hv = hprev[(size_t)(n0 + nl) * 64 + c];
        float r  = sigmoidf_(a_ir[mt][reg] + bir + a_hr[mt][reg] + bhr);
        float z  = sigmoidf_(a_iz[mt][reg] + biz + a_hz[mt][reg] + bhz);
        float nn = tanhf(a_in[mt][reg] + bin + r * (a_hn[mt][reg] + bhn));
        float hc = (1.f - z) * nn + z * hv;
        trF[c * 133 + nl] = hc;
      }
  }
  __syncthreads();
#pragma unroll 1
  for (int i = 0; i < 32; ++i) {
    int idx = t + 256 * i;
    int nl = idx & 127, cl = idx >> 7;
    hT[(size_t)cl * NROW + n0 + nl] = trF[cl * 133 + nl];
  }
#pragma unroll 1
  for (int i = 0; i < 32; ++i) {
    int idx = t + 256 * i;
    int c = idx & 63, nl = idx >> 6;
    hout[(size_t)(n0 + nl) * 64 + c] = trF[c * 133 + nl];
  }
}

// K3: q, query(scaled), z1 heads + BN partial sums per block
__global__ __launch_bounds__(256) void k_heads(const float* __restrict__ hT,
    const float* __restrict__ fc2w, const float* __restrict__ fc2b,
    const float* __restrict__ wqw, const float* __restrict__ wqb,
    const float* __restrict__ ew1, const float* __restrict__ eb1,
    float* __restrict__ qT, float* __restrict__ queryT, float* __restrict__ z1T,
    float* __restrict__ part) {
  int t = threadIdx.x;
  int n = blockIdx.x * 64 + (t & 63);
  int cq = t >> 6;
  float hv[HDIM];
#pragma unroll 1
  for (int k = 0; k < HDIM; ++k) hv[k] = hT[(size_t)k * NROW + n];
#pragma unroll 1
  for (int ci = 0; ci < 4; ++ci) {
    int c = cq * 4 + ci;
    float acc = fc2b[c];
#pragma unroll
    for (int k = 0; k < HDIM; ++k) acc = fmaf(hv[k], fc2w[c * HDIM + k], acc);
    qT[(size_t)c * NROW + n] = acc;
  }
  const float qs = 0.17677669529663687f;  // 1/sqrt(32)
#pragma unroll 1
  for (int ai = 0; ai < 8; ++ai) {
    int a = cq * 8 + ai;
    float acc = wqb[a];
#pragma unroll
    for (int k = 0; k < HDIM; ++k) acc = fmaf(hv[k], wqw[a * HDIM + k], acc);
    queryT[(size_t)a * NROW + n] = acc * qs;
  }
  __shared__ float ssum[64], ssq[64];
#pragma unroll 1
  for (int ci = 0; ci < 16; ++ci) {
    int c = cq * 16 + ci;
    float acc = eb1[c];
#pragma unroll
    for (int k = 0; k < HDIM; ++k) acc = fmaf(hv[k], ew1[c * HDIM + k], acc);
    z1T[(size_t)c * NROW + n] = acc;
    float s1 = acc, s2 = acc * acc;
#pragma unroll
    for (int off = 32; off > 0; off >>= 1) {
      s1 += __shfl_down(s1, off, 64);
      s2 += __shfl_down(s2, off, 64);
    }
    if ((t & 63) == 0) { ssum[c] = s1; ssq[c] = s2; }
  }
  __syncthreads();
  if (t < 64) {
    part[(size_t)blockIdx.x * 128 + t] = ssum[t];
    part[(size_t)blockIdx.x * 128 + 64 + t] = ssq[t];
  }
}

// K4: finalize BN stats
__global__ void k_bnstat(const float* __restrict__ part,
    const float* __restrict__ bng, const float* __restrict__ bnb,
    float* __restrict__ stat) {
  int c = threadIdx.x;  // 64 threads
  float s1 = 0.f, s2 = 0.f;
  for (int b = 0; b < 512; ++b) {
    s1 += part[(size_t)b * 128 + c];
    s2 += part[(size_t)b * 128 + 64 + c];
  }
  float mean = s1 * (1.f / NROW);
  float var = s2 * (1.f / NROW) - mean * mean;
  float rstd = rsqrtf(var + 1e-5f);
  float sc = bng[c] * rstd;
  stat[c] = sc;
  stat[64 + c] = bnb[c] - mean * sc;
}

// K5: MFMA bf16 GEMM: latent pre-act = lrelu(BN(z1)) @ ew2^T, fused var/eps epilogue.
__global__ __launch_bounds__(256) void k_emb_gemm(const float* __restrict__ z1T,
    const float* __restrict__ stat,
    const float* __restrict__ ew2, const float* __restrict__ eb2,
    const float* __restrict__ eps,
    float* __restrict__ latT) {
  __shared__ char smem[36864];
  const int t = threadIdx.x;
  const int nb = blockIdx.x >> 3;
  const int cb = blockIdx.x & 7;
  const int n0 = nb * 128;
  const int c0 = cb * 64;

  unsigned* aU = (unsigned*)smem;                 // A: [128][36]
  unsigned* bmU = (unsigned*)(smem + 18432);      // Wmu: [64][36]
  unsigned* blU = (unsigned*)(smem + 27648);      // Wlv: [64][36]

#pragma unroll 1
  for (int i = 0; i < 16; ++i) {
    int idx = t + 256 * i;
    int nl = idx & 127;
    int kp = idx >> 7;
    float v0 = z1T[(size_t)(2 * kp) * NROW + n0 + nl];
    float v1 = z1T[(size_t)(2 * kp + 1) * NROW + n0 + nl];
    v0 = lrelu_(fmaf(stat[2 * kp], v0, stat[64 + 2 * kp]));
    v1 = lrelu_(fmaf(stat[2 * kp + 1], v1, stat[64 + 2 * kp + 1]));
    aU[nl * 36 + kp] = f2bf(v0) | (f2bf(v1) << 16);
  }
  const float2* ew2_2 = (const float2*)ew2;
#pragma unroll 1
  for (int i = 0; i < 8; ++i) {
    int idx = t + 256 * i;
    int kp = idx & 31;
    int cl = idx >> 5;
    float2 m2 = ew2_2[(size_t)(c0 + cl) * 32 + kp];
    float2 l2 = ew2_2[(size_t)(512 + c0 + cl) * 32 + kp];
    bmU[cl * 36 + kp] = f2bf(m2.x) | (f2bf(m2.y) << 16);
    blU[cl * 36 + kp] = f2bf(l2.x) | (f2bf(l2.y) << 16);
  }
  __syncthreads();

  const int w = t >> 6, l = t & 63;
  const int m = l & 15, g = l >> 4;
  const short* sA = (const short*)smem;
  const short* sBm = (const short*)(smem + 18432);
  const short* sBl = (const short*)(smem + 27648);

  f32x4 accm[2][4], accl[2][4];
#pragma unroll
  for (int mt = 0; mt < 2; ++mt)
#pragma unroll
    for (int ct = 0; ct < 4; ++ct) {
      accm[mt][ct] = (f32x4){0.f, 0.f, 0.f, 0.f};
      accl[mt][ct] = (f32x4){0.f, 0.f, 0.f, 0.f};
    }
  bf16x8 af[2][2];
#pragma unroll
  for (int mt = 0; mt < 2; ++mt)
#pragma unroll
    for (int ks = 0; ks < 2; ++ks)
      af[mt][ks] = *(const bf16x8*)(sA + (w * 32 + mt * 16 + m) * 72 + ks * 32 + g * 8);
#pragma unroll
  for (int ct = 0; ct < 4; ++ct) {
#pragma unroll
    for (int ks = 0; ks < 2; ++ks) {
      bf16x8 bm = *(const bf16x8*)(sBm + (ct * 16 + m) * 72 + ks * 32 + g * 8);
      bf16x8 bl = *(const bf16x8*)(sBl + (ct * 16 + m) * 72 + ks * 32 + g * 8);
#pragma unroll
      for (int mt = 0; mt < 2; ++mt) {
        accm[mt][ct] = __builtin_amdgcn_mfma_f32_16x16x32_bf16(af[mt][ks], bm, accm[mt][ct], 0, 0, 0);
        accl[mt][ct] = __builtin_amdgcn_mfma_f32_16x16x32_bf16(af[mt][ks], bl, accl[mt][ct], 0, 0, 0);
      }
    }
  }

  float lat[2][4][4];
#pragma unroll
  for (int mt = 0; mt < 2; ++mt) {
    int nl = w * 32 + mt * 16 + g * 4;
#pragma unroll
    for (int reg = 0; reg < 4; ++reg) {
      const float* ep = eps + (size_t)(n0 + nl + reg) * DH + c0;
#pragma unroll
      for (int ct = 0; ct < 4; ++ct) {
        int cl = ct * 16 + m;
        float mu = accm[mt][ct][reg] + eb2[c0 + cl];
        float lv = accl[mt][ct][reg] + eb2[DH + c0 + cl];
        lat[mt][ct][reg] = fmaf(sqrtf(fmaxf(__expf(lv), 0.002f)), ep[cl], mu);
      }
    }
  }
  __syncthreads();
  float* outF = (float*)smem;     // [64][133]
#pragma unroll
  for (int mt = 0; mt < 2; ++mt)
#pragma unroll
    for (int ct = 0; ct < 4; ++ct)
#pragma unroll
      for (int reg = 0; reg < 4; ++reg)
        outF[(ct * 16 + m) * 133 + w * 32 + mt * 16 + g * 4 + reg] = lat[mt][ct][reg];
  __syncthreads();
#pragma unroll 1
  for (int i = 0; i < 32; ++i) {
    int idx = t + 256 * i;
    int nl = idx & 127;
    int cl = idx >> 7;
    latT[(size_t)(c0 + cl) * NROW + n0 + nl] = outF[cl * 133 + nl];
  }
}

// K6: alpha via factorization: logit[n,j] = (Wk^T q)[n] . lat[n,j] + q[n].kb
__global__ __launch_bounds__(128) void k_alpha(const float* __restrict__ latT,
    const float* __restrict__ queryT,
    const float* __restrict__ wkw, const float* __restrict__ wkb,
    float* __restrict__ alphaT) {
  int n = blockIdx.x * 128 + threadIdx.x;
  float qr[32];
#pragma unroll
  for (int a = 0; a < 32; ++a) qr[a] = queryT[(size_t)a * NROW + n];
  float qk[16];
#pragma unroll
  for (int l = 0; l < 16; ++l) qk[l] = 0.f;
  float qb = 0.f;
#pragma unroll
  for (int a = 0; a < 32; ++a) {
    qb = fmaf(qr[a], wkb[a], qb);
#pragma unroll
    for (int l = 0; l < 16; ++l) qk[l] = fmaf(qr[a], wkw[a * 16 + l], qk[l]);
  }
  int idiag = n & 31;
  float al[32];
#pragma unroll 4
  for (int j = 0; j < 32; ++j) {
    float acc = qb;
#pragma unroll
    for (int l = 0; l < 16; ++l)
      acc = fmaf(latT[(size_t)(j * 16 + l) * NROW + n], qk[l], acc);
    al[j] = (j == idiag) ? -1e9f : acc;
  }
  float m = -1e30f;
#pragma unroll
  for (int j = 0; j < 32; ++j) m = fmaxf(m, al[j]);
  float se = 0.f;
#pragma unroll
  for (int j = 0; j < 32; ++j) { al[j] = __expf(al[j] - m); se += al[j]; }
  float inv = 1.f / se;
#pragma unroll
  for (int j = 0; j < 32; ++j)
    alphaT[(size_t)j * NROW + n] = al[j] * inv;
}

// K7: per (b, j-half): hp = msg_w1[:, :64] @ h3 ; msg latent part ; w2 ; weighted agg ; + q
__global__ __launch_bounds__(256) void k_msg(const float* __restrict__ hT,
    const float* __restrict__ latT, const float* __restrict__ alphaT,
    const float* __restrict__ qT,
    const float* __restrict__ w1, const float* __restrict__ b1,
    const float* __restrict__ w2, const float* __restrict__ b2,
    float* __restrict__ out) {
  int t = threadIdx.x;
  int b = blockIdx.x >> 1;
  int jh = (blockIdx.x & 1) * 16;  // j base within [0,32)
  __shared__ float latL[32 * 273];   // i*273 + j'*17 + l
  __shared__ float h3L[16 * 65];     // j'*65 + k
  __shared__ float hpL[16 * 65];     // j'*65 + c
  __shared__ float alL[32 * 17];     // i*17 + j'
  __shared__ float aggL[16 * 16 * 16];  // (g*16+j')*16 + nn
  int base_n = b * 32;
  for (int idx = t; idx < 16 * 64; idx += 256) {
    int k = idx >> 4, jp = idx & 15;
    h3L[jp * 65 + k] = hT[(size_t)k * NROW + base_n + jh + jp];
  }
  for (int idx = t; idx < 8192; idx += 256) {
    int i = idx & 31, ol = idx >> 5;
    int jp = ol >> 4, l = ol & 15;
    latL[i * 273 + jp * 17 + l] = latT[(size_t)(jh * 16 + ol) * NROW + base_n + i];
  }
  for (int idx = t; idx < 512; idx += 256) {
    int i = idx & 31, jp = idx >> 5;
    alL[i * 17 + jp] = alphaT[(size_t)(jh + jp) * NROW + base_n + i];
  }
  __syncthreads();
  {
    int c = t & 63;
    int j0 = t >> 6;
#pragma unroll 1
    for (int jj = 0; jj < 4; ++jj) {
      int jp = j0 + jj * 4;
      float acc = b1[c];
#pragma unroll
      for (int k = 0; k < 64; ++k) acc = fmaf(h3L[jp * 65 + k], w1[c * 80 + k], acc);
      hpL[jp * 65 + c] = acc;
    }
  }
  __syncthreads();
  int jp = t & 15;
  int g = t >> 4;
  float aggp[16];
#pragma unroll
  for (int nn = 0; nn < 16; ++nn) aggp[nn] = 0.f;
#pragma unroll 1
  for (int ii = 0; ii < 2; ++ii) {
    int i = g + ii * 16;
    float lat[16];
#pragma unroll
    for (int l = 0; l < 16; ++l) lat[l] = latL[i * 273 + jp * 17 + l];
    float aw = alL[i * 17 + jp];
    float m1[64];
#pragma unroll 1
    for (int c = 0; c < 64; ++c) {
      float acc = hpL[jp * 65 + c];
#pragma unroll
      for (int l = 0; l < 16; ++l) acc = fmaf(lat[l], w1[c * 80 + 64 + l], acc);
      m1[c] = lrelu_(acc);
    }
#pragma unroll 1
    for (int nn = 0; nn < 16; ++nn) {
      float acc = b2[nn];
#pragma unroll
      for (int c = 0; c < 64; ++c) acc = fmaf(m1[c], w2[nn * 64 + c], acc);
      aggp[nn] = fmaf(aw, acc, aggp[nn]);
    }
  }
  float4* ag4 = (float4*)&aggL[t * 16];
#pragma unroll
  for (int n4 = 0; n4 < 4; ++n4)
    ag4[n4] = make_float4(aggp[4 * n4], aggp[4 * n4 + 1], aggp[4 * n4 + 2], aggp[4 * n4 + 3]);
  __syncthreads();
  float acc = qT[(size_t)(t & 15) * NROW + base_n + jh + (t >> 4)];
#pragma unroll 1
  for (int g2 = 0; g2 < 16; ++g2) acc += aggL[g2 * 256 + t];
  out[(size_t)b * 512 + jh * 16 + t] = acc;
}

}  // namespace

extern "C" void kernel_launch(void* const* d_in, const int* in_sizes, int n_in,
                              void* d_out, int out_size, void* d_ws, size_t ws_size,
                              hipStream_t stream) {
  (void)in_sizes; (void)n_in; (void)out_size; (void)ws_size;
  const float* inputs = (const float*)d_in[0];
  const float* hidden = (const float*)d_in[1];
  const float* eps    = (const float*)d_in[2];
  const float* fc1w   = (const float*)d_in[3];
  const float* fc1b   = (const float*)d_in[4];
  const float* wih    = (const float*)d_in[5];
  const float* whh    = (const float*)d_in[6];
  const float* bih    = (const float*)d_in[7];
  const float* bhh    = (const float*)d_in[8];
  const float* fc2w   = (const float*)d_in[9];
  const float* fc2b   = (const float*)d_in[10];
  const float* ew1    = (const float*)d_in[11];
  const float* eb1    = (const float*)d_in[12];
  const float* bng    = (const float*)d_in[13];
  const float* bnb    = (const float*)d_in[14];
  const float* ew2    = (const float*)d_in[15];
  const float* eb2    = (const float*)d_in[16];
  const float* w1     = (const float*)d_in[17];
  const float* b1     = (const float*)d_in[18];
  const float* w2     = (const float*)d_in[19];
  const float* b2     = (const float*)d_in[20];
  const float* wqw    = (const float*)d_in[21];
  const float* wqb    = (const float*)d_in[22];
  const float* wkw    = (const float*)d_in[23];
  const float* wkb    = (const float*)d_in[24];

  float* ws = (float*)d_ws;
  float* hT     = ws;                 // 2097152
  float* qT     = ws + 2097152;       // 524288
  float* queryT = ws + 2621440;       // 1048576
  float* z1T    = ws + 3670016;       // 2097152
  float* part   = ws + 5767168;       // 65536
  float* stat   = ws + 5832704;       // 128
  float* latT   = ws + 5832832;       // 16777216
  float* alphaT = ws + 22610048;      // 1048576

  float* out_q = (float*)d_out;             // 32768 x 16
  float* out_h = (float*)d_out + 524288;    // 32768 x 64

  hipLaunchKernelGGL(k_fgru, dim3(256), dim3(256), 0, stream,
                     inputs, hidden, fc1w, fc1b, wih, whh, bih, bhh, hT, out_h);
  hipLaunchKernelGGL(k_heads, dim3(512), dim3(256), 0, stream, hT, fc2w, fc2b, wqw, wqb, ew1, eb1, qT, queryT, z1T, part);
  hipLaunchKernelGGL(k_bnstat, dim3(1), dim3(64), 0, stream, part, bng, bnb, stat);
  hipLaunchKernelGGL(k_emb_gemm, dim3(2048), dim3(256), 0, stream, z1T, stat, ew2, eb2, eps, latT);
  hipLaunchKernelGGL(k_alpha, dim3(256), dim3(128), 0, stream, latT, queryT, wkw, wkb, alphaT);
  hipLaunchKernelGGL(k_msg, dim3(2048), dim3(256), 0, stream, hT, latT, alphaT, qT, w1, b1, w2, b2, out_q);
}

// Round 5
// 543.020 us; speedup vs baseline: 3.1090x; 1.0595x over previous
//
#include <hip/hip_runtime.h>
#include <math.h>

namespace {

constexpr int NROW = 32768;   // BS*A rows
constexpr int HDIM = 64;
constexpr int DH   = 512;     // latent half-dim

typedef __attribute__((ext_vector_type(8))) short bf16x8;
typedef __attribute__((ext_vector_type(4))) float f32x4;

__device__ __forceinline__ float sigmoidf_(float x) { return 1.f / (1.f + __expf(-x)); }
__device__ __forceinline__ float lrelu_(float x) { return x > 0.f ? x : 0.01f * x; }
__device__ __forceinline__ unsigned f2bf(float x) {  // RNE float->bf16 (as low 16 bits)
  unsigned u = __float_as_uint(x);
  return (u + 0x7fffu + ((u >> 16) & 1u)) >> 16;
}

// K1+K2 fused: x = relu(inputs @ fc1_w^T + b); GRU via 6 MFMA gate GEMMs.
__global__ __launch_bounds__(256, 1) void k_fgru(
    const float* __restrict__ in,      // [N][96]
    const float* __restrict__ hprev,   // [N][64]
    const float* __restrict__ fc1w, const float* __restrict__ fc1b,
    const float* __restrict__ wih, const float* __restrict__ whh,
    const float* __restrict__ bih, const float* __restrict__ bhh,
    float* __restrict__ hT, float* __restrict__ hout) {
  __shared__ char smem[132096];
  const int t = threadIdx.x;
  const int n0 = blockIdx.x * 128;
  unsigned* inU  = (unsigned*)smem;                    // [128][52]
  unsigned* f1U  = (unsigned*)(smem + 26624);          // [64][52]
  unsigned* xU   = (unsigned*)(smem + 39936);          // [128][36]
  unsigned* hU   = (unsigned*)(smem + 58368);          // [128][36]
  unsigned* gU   = (unsigned*)(smem + 76800);          // [6][64][36]
  float*    trF  = (float*)smem;                       // [64][133] overlaps inU/f1U

  const float2* in2 = (const float2*)in;
#pragma unroll 1
  for (int i = 0; i < 24; ++i) {
    int idx = t + 256 * i;
    int nl = idx / 48, kp = idx - nl * 48;
    float2 v = in2[(size_t)(n0 + nl) * 48 + kp];
    inU[nl * 52 + kp] = f2bf(v.x) | (f2bf(v.y) << 16);
  }
  const float2* f1w2 = (const float2*)fc1w;
#pragma unroll 1
  for (int i = 0; i < 12; ++i) {
    int idx = t + 256 * i;
    int cl = idx / 48, kp = idx - cl * 48;
    float2 v = f1w2[cl * 48 + kp];
    f1U[cl * 52 + kp] = f2bf(v.x) | (f2bf(v.y) << 16);
  }
  const float2* h2 = (const float2*)hprev;
#pragma unroll 1
  for (int i = 0; i < 16; ++i) {
    int idx = t + 256 * i;
    int nl = idx >> 5, kp = idx & 31;
    float2 v = h2[(size_t)(n0 + nl) * 32 + kp];
    hU[nl * 36 + kp] = f2bf(v.x) | (f2bf(v.y) << 16);
  }
  const float2* wih2 = (const float2*)wih;
  const float2* whh2 = (const float2*)whh;
#pragma unroll 1
  for (int i = 0; i < 24; ++i) {
    int idx = t + 256 * i;
    int row = idx >> 5, kp = idx & 31;
    float2 v = wih2[row * 32 + kp];
    int gate = row >> 6, cl = row & 63;
    gU[(gate * 64 + cl) * 36 + kp] = f2bf(v.x) | (f2bf(v.y) << 16);
  }
#pragma unroll 1
  for (int i = 0; i < 24; ++i) {
    int idx = t + 256 * i;
    int row = idx >> 5, kp = idx & 31;
    float2 v = whh2[row * 32 + kp];
    int gate = row >> 6, cl = row & 63;
    gU[((gate + 3) * 64 + cl) * 36 + kp] = f2bf(v.x) | (f2bf(v.y) << 16);
  }
  __syncthreads();

  const int w = t >> 6, l = t & 63;
  const int m = l & 15, g = l >> 4;
  const short* inS = (const short*)inU;
  const short* f1S = (const short*)f1U;
  short*       xS  = (short*)xU;
  const short* hS  = (const short*)hU;
  const short* gS  = (const short*)gU;

  // ---- fc1 phase ----
  {
    f32x4 accx[2][4];
#pragma unroll
    for (int mt = 0; mt < 2; ++mt)
#pragma unroll
      for (int ct = 0; ct < 4; ++ct) accx[mt][ct] = (f32x4){0.f, 0.f, 0.f, 0.f};
    bf16x8 af[2][3];
#pragma unroll
    for (int mt = 0; mt < 2; ++mt)
#pragma unroll
      for (int ks = 0; ks < 3; ++ks)
        af[mt][ks] = *(const bf16x8*)(inS + (w * 32 + mt * 16 + m) * 104 + ks * 32 + g * 8);
#pragma unroll
    for (int ct = 0; ct < 4; ++ct)
#pragma unroll
      for (int ks = 0; ks < 3; ++ks) {
        bf16x8 bw = *(const bf16x8*)(f1S + (ct * 16 + m) * 104 + ks * 32 + g * 8);
#pragma unroll
        for (int mt = 0; mt < 2; ++mt)
          accx[mt][ct] = __builtin_amdgcn_mfma_f32_16x16x32_bf16(af[mt][ks], bw, accx[mt][ct], 0, 0, 0);
      }
#pragma unroll
    for (int mt = 0; mt < 2; ++mt)
#pragma unroll
      for (int ct = 0; ct < 4; ++ct) {
        int c = ct * 16 + m;
        float bc = fc1b[c];
#pragma unroll
        for (int reg = 0; reg < 4; ++reg) {
          int nl = w * 32 + mt * 16 + g * 4 + reg;
          float v = fmaxf(accx[mt][ct][reg] + bc, 0.f);
          xS[nl * 72 + c] = (short)f2bf(v);
        }
      }
  }
  __syncthreads();

  // ---- GRU phase ----
  bf16x8 ax[2][2], ah[2][2];
#pragma unroll
  for (int mt = 0; mt < 2; ++mt)
#pragma unroll
    for (int ks = 0; ks < 2; ++ks) {
      ax[mt][ks] = *(const bf16x8*)((const short*)xU + (w * 32 + mt * 16 + m) * 72 + ks * 32 + g * 8);
      ah[mt][ks] = *(const bf16x8*)(hS + (w * 32 + mt * 16 + m) * 72 + ks * 32 + g * 8);
    }
#pragma unroll 1
  for (int ct = 0; ct < 4; ++ct) {
    f32x4 a_ir[2], a_iz[2], a_in[2], a_hr[2], a_hz[2], a_hn[2];
#pragma unroll
    for (int mt = 0; mt < 2; ++mt) {
      a_ir[mt] = (f32x4){0.f, 0.f, 0.f, 0.f}; a_iz[mt] = (f32x4){0.f, 0.f, 0.f, 0.f};
      a_in[mt] = (f32x4){0.f, 0.f, 0.f, 0.f}; a_hr[mt] = (f32x4){0.f, 0.f, 0.f, 0.f};
      a_hz[mt] = (f32x4){0.f, 0.f, 0.f, 0.f}; a_hn[mt] = (f32x4){0.f, 0.f, 0.f, 0.f};
    }
    int crow = ct * 16 + m;
#pragma unroll
    for (int ks = 0; ks < 2; ++ks) {
      bf16x8 b0 = *(const bf16x8*)(gS + (0 * 64 + crow) * 72 + ks * 32 + g * 8);
      bf16x8 b1 = *(const bf16x8*)(gS + (1 * 64 + crow) * 72 + ks * 32 + g * 8);
      bf16x8 b2 = *(const bf16x8*)(gS + (2 * 64 + crow) * 72 + ks * 32 + g * 8);
      bf16x8 b3 = *(const bf16x8*)(gS + (3 * 64 + crow) * 72 + ks * 32 + g * 8);
      bf16x8 b4 = *(const bf16x8*)(gS + (4 * 64 + crow) * 72 + ks * 32 + g * 8);
      bf16x8 b5 = *(const bf16x8*)(gS + (5 * 64 + crow) * 72 + ks * 32 + g * 8);
#pragma unroll
      for (int mt = 0; mt < 2; ++mt) {
        a_ir[mt] = __builtin_amdgcn_mfma_f32_16x16x32_bf16(ax[mt][ks], b0, a_ir[mt], 0, 0, 0);
        a_iz[mt] = __builtin_amdgcn_mfma_f32_16x16x32_bf16(ax[mt][ks], b1, a_iz[mt], 0, 0, 0);
        a_in[mt] = __builtin_amdgcn_mfma_f32_16x16x32_bf16(ax[mt][ks], b2, a_in[mt], 0, 0, 0);
        a_hr[mt] = __builtin_amdgcn_mfma_f32_16x16x32_bf16(ah[mt][ks], b3, a_hr[mt], 0, 0, 0);
        a_hz[mt] = __builtin_amdgcn_mfma_f32_16x16x32_bf16(ah[mt][ks], b4, a_hz[mt], 0, 0, 0);
        a_hn[mt] = __builtin_amdgcn_mfma_f32_16x16x32_bf16(ah[mt][ks], b5, a_hn[mt], 0, 0, 0);
      }
    }
    int c = crow;
    float bir = bih[c], biz = bih[64 + c], bin = bih[128 + c];
    float bhr = bhh[c], bhz = bhh[64 + c], bhn = bhh[128 + c];
#pragma unroll
    for (int mt = 0; mt < 2; ++mt)
#pragma unroll
      for (int reg = 0; reg < 4; ++reg) {
        int nl = w * 32 + mt * 16 + g * 4 + reg;
        float hv = hprev[(size_t)(n0 + nl) * 64 + c];
        float r  = sigmoidf_(a_ir[mt][reg] + bir + a_hr[mt][reg] + bhr);
        float z  = sigmoidf_(a_iz[mt][reg] + biz + a_hz[mt][reg] + bhz);
        float nn = tanhf(a_in[mt][reg] + bin + r * (a_hn[mt][reg] + bhn));
        float hc = (1.f - z) * nn + z * hv;
        trF[c * 133 + nl] = hc;
      }
  }
  __syncthreads();
#pragma unroll 1
  for (int i = 0; i < 32; ++i) {
    int idx = t + 256 * i;
    int nl = idx & 127, cl = idx >> 7;
    hT[(size_t)cl * NROW + n0 + nl] = trF[cl * 133 + nl];
  }
#pragma unroll 1
  for (int i = 0; i < 32; ++i) {
    int idx = t + 256 * i;
    int c = idx & 63, nl = idx >> 6;
    hout[(size_t)(n0 + nl) * 64 + c] = trF[c * 133 + nl];
  }
}

// K3: q, query(scaled), z1 heads + BN partial sums per block
__global__ __launch_bounds__(256) void k_heads(const float* __restrict__ hT,
    const float* __restrict__ fc2w, const float* __restrict__ fc2b,
    const float* __restrict__ wqw, const float* __restrict__ wqb,
    const float* __restrict__ ew1, const float* __restrict__ eb1,
    float* __restrict__ qT, float* __restrict__ queryT, float* __restrict__ z1T,
    float* __restrict__ part) {
  int t = threadIdx.x;
  int n = blockIdx.x * 64 + (t & 63);
  int cq = t >> 6;
  float hv[HDIM];
#pragma unroll 1
  for (int k = 0; k < HDIM; ++k) hv[k] = hT[(size_t)k * NROW + n];
#pragma unroll 1
  for (int ci = 0; ci < 4; ++ci) {
    int c = cq * 4 + ci;
    float acc = fc2b[c];
#pragma unroll
    for (int k = 0; k < HDIM; ++k) acc = fmaf(hv[k], fc2w[c * HDIM + k], acc);
    qT[(size_t)c * NROW + n] = acc;
  }
  const float qs = 0.17677669529663687f;  // 1/sqrt(32)
#pragma unroll 1
  for (int ai = 0; ai < 8; ++ai) {
    int a = cq * 8 + ai;
    float acc = wqb[a];
#pragma unroll
    for (int k = 0; k < HDIM; ++k) acc = fmaf(hv[k], wqw[a * HDIM + k], acc);
    queryT[(size_t)a * NROW + n] = acc * qs;
  }
  __shared__ float ssum[64], ssq[64];
#pragma unroll 1
  for (int ci = 0; ci < 16; ++ci) {
    int c = cq * 16 + ci;
    float acc = eb1[c];
#pragma unroll
    for (int k = 0; k < HDIM; ++k) acc = fmaf(hv[k], ew1[c * HDIM + k], acc);
    z1T[(size_t)c * NROW + n] = acc;
    float s1 = acc, s2 = acc * acc;
#pragma unroll
    for (int off = 32; off > 0; off >>= 1) {
      s1 += __shfl_down(s1, off, 64);
      s2 += __shfl_down(s2, off, 64);
    }
    if ((t & 63) == 0) { ssum[c] = s1; ssq[c] = s2; }
  }
  __syncthreads();
  if (t < 64) {
    part[(size_t)blockIdx.x * 128 + t] = ssum[t];
    part[(size_t)blockIdx.x * 128 + 64 + t] = ssq[t];
  }
}

// K4: finalize BN stats
__global__ void k_bnstat(const float* __restrict__ part,
    const float* __restrict__ bng, const float* __restrict__ bnb,
    float* __restrict__ stat) {
  int c = threadIdx.x;  // 64 threads
  float s1 = 0.f, s2 = 0.f;
  for (int b = 0; b < 512; ++b) {
    s1 += part[(size_t)b * 128 + c];
    s2 += part[(size_t)b * 128 + 64 + c];
  }
  float mean = s1 * (1.f / NROW);
  float var = s2 * (1.f / NROW) - mean * mean;
  float rstd = rsqrtf(var + 1e-5f);
  float sc = bng[c] * rstd;
  stat[c] = sc;
  stat[64 + c] = bnb[c] - mean * sc;
}

// K5: MFMA bf16 GEMM: latent pre-act = lrelu(BN(z1)) @ ew2^T, fused var/eps epilogue.
__global__ __launch_bounds__(256) void k_emb_gemm(const float* __restrict__ z1T,
    const float* __restrict__ stat,
    const float* __restrict__ ew2, const float* __restrict__ eb2,
    const float* __restrict__ eps,
    float* __restrict__ latT) {
  __shared__ char smem[36864];
  const int t = threadIdx.x;
  const int nb = blockIdx.x >> 3;
  const int cb = blockIdx.x & 7;
  const int n0 = nb * 128;
  const int c0 = cb * 64;

  unsigned* aU = (unsigned*)smem;                 // A: [128][36]
  unsigned* bmU = (unsigned*)(smem + 18432);      // Wmu: [64][36]
  unsigned* blU = (unsigned*)(smem + 27648);      // Wlv: [64][36]

#pragma unroll 1
  for (int i = 0; i < 16; ++i) {
    int idx = t + 256 * i;
    int nl = idx & 127;
    int kp = idx >> 7;
    float v0 = z1T[(size_t)(2 * kp) * NROW + n0 + nl];
    float v1 = z1T[(size_t)(2 * kp + 1) * NROW + n0 + nl];
    v0 = lrelu_(fmaf(stat[2 * kp], v0, stat[64 + 2 * kp]));
    v1 = lrelu_(fmaf(stat[2 * kp + 1], v1, stat[64 + 2 * kp + 1]));
    aU[nl * 36 + kp] = f2bf(v0) | (f2bf(v1) << 16);
  }
  const float2* ew2_2 = (const float2*)ew2;
#pragma unroll 1
  for (int i = 0; i < 8; ++i) {
    int idx = t + 256 * i;
    int kp = idx & 31;
    int cl = idx >> 5;
    float2 m2 = ew2_2[(size_t)(c0 + cl) * 32 + kp];
    float2 l2 = ew2_2[(size_t)(512 + c0 + cl) * 32 + kp];
    bmU[cl * 36 + kp] = f2bf(m2.x) | (f2bf(m2.y) << 16);
    blU[cl * 36 + kp] = f2bf(l2.x) | (f2bf(l2.y) << 16);
  }
  __syncthreads();

  const int w = t >> 6, l = t & 63;
  const int m = l & 15, g = l >> 4;
  const short* sA = (const short*)smem;
  const short* sBm = (const short*)(smem + 18432);
  const short* sBl = (const short*)(smem + 27648);

  f32x4 accm[2][4], accl[2][4];
#pragma unroll
  for (int mt = 0; mt < 2; ++mt)
#pragma unroll
    for (int ct = 0; ct < 4; ++ct) {
      accm[mt][ct] = (f32x4){0.f, 0.f, 0.f, 0.f};
      accl[mt][ct] = (f32x4){0.f, 0.f, 0.f, 0.f};
    }
  bf16x8 af[2][2];
#pragma unroll
  for (int mt = 0; mt < 2; ++mt)
#pragma unroll
    for (int ks = 0; ks < 2; ++ks)
      af[mt][ks] = *(const bf16x8*)(sA + (w * 32 + mt * 16 + m) * 72 + ks * 32 + g * 8);
#pragma unroll
  for (int ct = 0; ct < 4; ++ct) {
#pragma unroll
    for (int ks = 0; ks < 2; ++ks) {
      bf16x8 bm = *(const bf16x8*)(sBm + (ct * 16 + m) * 72 + ks * 32 + g * 8);
      bf16x8 bl = *(const bf16x8*)(sBl + (ct * 16 + m) * 72 + ks * 32 + g * 8);
#pragma unroll
      for (int mt = 0; mt < 2; ++mt) {
        accm[mt][ct] = __builtin_amdgcn_mfma_f32_16x16x32_bf16(af[mt][ks], bm, accm[mt][ct], 0, 0, 0);
        accl[mt][ct] = __builtin_amdgcn_mfma_f32_16x16x32_bf16(af[mt][ks], bl, accl[mt][ct], 0, 0, 0);
      }
    }
  }

  float lat[2][4][4];
#pragma unroll
  for (int mt = 0; mt < 2; ++mt) {
    int nl = w * 32 + mt * 16 + g * 4;
#pragma unroll
    for (int reg = 0; reg < 4; ++reg) {
      const float* ep = eps + (size_t)(n0 + nl + reg) * DH + c0;
#pragma unroll
      for (int ct = 0; ct < 4; ++ct) {
        int cl = ct * 16 + m;
        float mu = accm[mt][ct][reg] + eb2[c0 + cl];
        float lv = accl[mt][ct][reg] + eb2[DH + c0 + cl];
        lat[mt][ct][reg] = fmaf(sqrtf(fmaxf(__expf(lv), 0.002f)), ep[cl], mu);
      }
    }
  }
  __syncthreads();
  float* outF = (float*)smem;     // [64][133]
#pragma unroll
  for (int mt = 0; mt < 2; ++mt)
#pragma unroll
    for (int ct = 0; ct < 4; ++ct)
#pragma unroll
      for (int reg = 0; reg < 4; ++reg)
        outF[(ct * 16 + m) * 133 + w * 32 + mt * 16 + g * 4 + reg] = lat[mt][ct][reg];
  __syncthreads();
#pragma unroll 1
  for (int i = 0; i < 32; ++i) {
    int idx = t + 256 * i;
    int nl = idx & 127;
    int cl = idx >> 7;
    latT[(size_t)(c0 + cl) * NROW + n0 + nl] = outF[cl * 133 + nl];
  }
}

// K6: alpha via factorization: logit[n,j] = (Wk^T q)[n] . lat[n,j] + q[n].kb
__global__ __launch_bounds__(128) void k_alpha(const float* __restrict__ latT,
    const float* __restrict__ queryT,
    const float* __restrict__ wkw, const float* __restrict__ wkb,
    float* __restrict__ alphaT) {
  int n = blockIdx.x * 128 + threadIdx.x;
  float qr[32];
#pragma unroll
  for (int a = 0; a < 32; ++a) qr[a] = queryT[(size_t)a * NROW + n];
  float qk[16];
#pragma unroll
  for (int l = 0; l < 16; ++l) qk[l] = 0.f;
  float qb = 0.f;
#pragma unroll
  for (int a = 0; a < 32; ++a) {
    qb = fmaf(qr[a], wkb[a], qb);
#pragma unroll
    for (int l = 0; l < 16; ++l) qk[l] = fmaf(qr[a], wkw[a * 16 + l], qk[l]);
  }
  int idiag = n & 31;
  float al[32];
#pragma unroll 4
  for (int j = 0; j < 32; ++j) {
    float acc = qb;
#pragma unroll
    for (int l = 0; l < 16; ++l)
      acc = fmaf(latT[(size_t)(j * 16 + l) * NROW + n], qk[l], acc);
    al[j] = (j == idiag) ? -1e9f : acc;
  }
  float m = -1e30f;
#pragma unroll
  for (int j = 0; j < 32; ++j) m = fmaxf(m, al[j]);
  float se = 0.f;
#pragma unroll
  for (int j = 0; j < 32; ++j) { al[j] = __expf(al[j] - m); se += al[j]; }
  float inv = 1.f / se;
#pragma unroll
  for (int j = 0; j < 32; ++j)
    alphaT[(size_t)j * NROW + n] = al[j] * inv;
}

// K7: per (b, j-half). Spill-free: fused c-loop (no m1[64] array); w1-latent and
// w2^T staged in LDS (parked in aggL region, dead until epilogue).
__global__ __launch_bounds__(256) void k_msg(const float* __restrict__ hT,
    const float* __restrict__ latT, const float* __restrict__ alphaT,
    const float* __restrict__ qT,
    const float* __restrict__ w1, const float* __restrict__ b1,
    const float* __restrict__ w2, const float* __restrict__ b2,
    float* __restrict__ out) {
  int t = threadIdx.x;
  int b = blockIdx.x >> 1;
  int jh = (blockIdx.x & 1) * 16;  // j base within [0,32)
  __shared__ float latL[32 * 273];   // i*273 + j'*17 + l
  __shared__ float h3L[16 * 65];     // j'*65 + k
  __shared__ float hpL[16 * 65];     // j'*65 + c
  __shared__ float alL[32 * 17];     // i*17 + j'
  __shared__ float aggL[16 * 16 * 16];  // epilogue; hosts w1L/w2tL during main loop
  float* w1L  = aggL;          // [64][20]: w1[c][64+l]
  float* w2tL = aggL + 1280;   // [64][20]: w2[nn][c] transposed
  int base_n = b * 32;
  for (int idx = t; idx < 16 * 64; idx += 256) {
    int k = idx >> 4, jp = idx & 15;
    h3L[jp * 65 + k] = hT[(size_t)k * NROW + base_n + jh + jp];
  }
  for (int idx = t; idx < 8192; idx += 256) {
    int i = idx & 31, ol = idx >> 5;
    int jp = ol >> 4, l = ol & 15;
    latL[i * 273 + jp * 17 + l] = latT[(size_t)(jh * 16 + ol) * NROW + base_n + i];
  }
  for (int idx = t; idx < 512; idx += 256) {
    int i = idx & 31, jp = idx >> 5;
    alL[i * 17 + jp] = alphaT[(size_t)(jh + jp) * NROW + base_n + i];
  }
  for (int idx = t; idx < 1024; idx += 256) {
    int c = idx >> 4, l = idx & 15;
    w1L[c * 20 + l] = w1[c * 80 + 64 + l];
  }
  for (int idx = t; idx < 1024; idx += 256) {
    int nn = idx >> 6, c = idx & 63;
    w2tL[c * 20 + nn] = w2[nn * 64 + c];
  }
  __syncthreads();
  {
    int c = t & 63;
    int j0 = t >> 6;
#pragma unroll 1
    for (int jj = 0; jj < 4; ++jj) {
      int jp = j0 + jj * 4;
      float acc = b1[c];
#pragma unroll
      for (int k = 0; k < 64; ++k) acc = fmaf(h3L[jp * 65 + k], w1[c * 80 + k], acc);
      hpL[jp * 65 + c] = acc;
    }
  }
  __syncthreads();
  int jp = t & 15;
  int g = t >> 4;
  float aggp[16];
#pragma unroll
  for (int nn = 0; nn < 16; ++nn) aggp[nn] = 0.f;
#pragma unroll 1
  for (int ii = 0; ii < 2; ++ii) {
    int i = g + ii * 16;
    float lat[16];
#pragma unroll
    for (int l = 0; l < 16; ++l) lat[l] = latL[i * 273 + jp * 17 + l];
    float aw = alL[i * 17 + jp];
    float tmp[16];
#pragma unroll
    for (int nn = 0; nn < 16; ++nn) tmp[nn] = 0.f;
#pragma unroll 2
    for (int c = 0; c < 64; ++c) {
      const float4* wv1 = (const float4*)(w1L + c * 20);
      float4 a0 = wv1[0], a1 = wv1[1], a2 = wv1[2], a3 = wv1[3];
      float acc = hpL[jp * 65 + c];
      acc = fmaf(lat[0], a0.x, acc);  acc = fmaf(lat[1], a0.y, acc);
      acc = fmaf(lat[2], a0.z, acc);  acc = fmaf(lat[3], a0.w, acc);
      acc = fmaf(lat[4], a1.x, acc);  acc = fmaf(lat[5], a1.y, acc);
      acc = fmaf(lat[6], a1.z, acc);  acc = fmaf(lat[7], a1.w, acc);
      acc = fmaf(lat[8], a2.x, acc);  acc = fmaf(lat[9], a2.y, acc);
      acc = fmaf(lat[10], a2.z, acc); acc = fmaf(lat[11], a2.w, acc);
      acc = fmaf(lat[12], a3.x, acc); acc = fmaf(lat[13], a3.y, acc);
      acc = fmaf(lat[14], a3.z, acc); acc = fmaf(lat[15], a3.w, acc);
      float mm = lrelu_(acc);
      const float4* wv2 = (const float4*)(w2tL + c * 20);
      float4 b0 = wv2[0], b1v = wv2[1], b2v = wv2[2], b3v = wv2[3];
      tmp[0]  = fmaf(mm, b0.x, tmp[0]);   tmp[1]  = fmaf(mm, b0.y, tmp[1]);
      tmp[2]  = fmaf(mm, b0.z, tmp[2]);   tmp[3]  = fmaf(mm, b0.w, tmp[3]);
      tmp[4]  = fmaf(mm, b1v.x, tmp[4]);  tmp[5]  = fmaf(mm, b1v.y, tmp[5]);
      tmp[6]  = fmaf(mm, b1v.z, tmp[6]);  tmp[7]  = fmaf(mm, b1v.w, tmp[7]);
      tmp[8]  = fmaf(mm, b2v.x, tmp[8]);  tmp[9]  = fmaf(mm, b2v.y, tmp[9]);
      tmp[10] = fmaf(mm, b2v.z, tmp[10]); tmp[11] = fmaf(mm, b2v.w, tmp[11]);
      tmp[12] = fmaf(mm, b3v.x, tmp[12]); tmp[13] = fmaf(mm, b3v.y, tmp[13]);
      tmp[14] = fmaf(mm, b3v.z, tmp[14]); tmp[15] = fmaf(mm, b3v.w, tmp[15]);
    }
#pragma unroll
    for (int nn = 0; nn < 16; ++nn) aggp[nn] = fmaf(aw, tmp[nn] + b2[nn], aggp[nn]);
  }
  __syncthreads();   // all waves done reading w1L/w2tL before aggL overwrite
  float4* ag4 = (float4*)&aggL[t * 16];
#pragma unroll
  for (int n4 = 0; n4 < 4; ++n4)
    ag4[n4] = make_float4(aggp[4 * n4], aggp[4 * n4 + 1], aggp[4 * n4 + 2], aggp[4 * n4 + 3]);
  __syncthreads();
  float acc = qT[(size_t)(t & 15) * NROW + base_n + jh + (t >> 4)];
#pragma unroll 1
  for (int g2 = 0; g2 < 16; ++g2) acc += aggL[g2 * 256 + t];
  out[(size_t)b * 512 + jh * 16 + t] = acc;
}

}  // namespace

extern "C" void kernel_launch(void* const* d_in, const int* in_sizes, int n_in,
                              void* d_out, int out_size, void* d_ws, size_t ws_size,
                              hipStream_t stream) {
  (void)in_sizes; (void)n_in; (void)out_size; (void)ws_size;
  const float* inputs = (const float*)d_in[0];
  const float* hidden = (const float*)d_in[1];
  const float* eps    = (const float*)d_in[2];
  const float* fc1w   = (const float*)d_in[3];
  const float* fc1b   = (const float*)d_in[4];
  const float* wih    = (const float*)d_in[5];
  const float* whh    = (const float*)d_in[6];
  const float* bih    = (const float*)d_in[7];
  const float* bhh    = (const float*)d_in[8];
  const float* fc2w   = (const float*)d_in[9];
  const float* fc2b   = (const float*)d_in[10];
  const float* ew1    = (const float*)d_in[11];
  const float* eb1    = (const float*)d_in[12];
  const float* bng    = (const float*)d_in[13];
  const float* bnb    = (const float*)d_in[14];
  const float* ew2    = (const float*)d_in[15];
  const float* eb2    = (const float*)d_in[16];
  const float* w1     = (const float*)d_in[17];
  const float* b1     = (const float*)d_in[18];
  const float* w2     = (const float*)d_in[19];
  const float* b2     = (const float*)d_in[20];
  const float* wqw    = (const float*)d_in[21];
  const float* wqb    = (const float*)d_in[22];
  const float* wkw    = (const float*)d_in[23];
  const float* wkb    = (const float*)d_in[24];

  float* ws = (float*)d_ws;
  float* hT     = ws;                 // 2097152
  float* qT     = ws + 2097152;       // 524288
  float* queryT = ws + 2621440;       // 1048576
  float* z1T    = ws + 3670016;       // 2097152
  float* part   = ws + 5767168;       // 65536
  float* stat   = ws + 5832704;       // 128
  float* latT   = ws + 5832832;       // 16777216
  float* alphaT = ws + 22610048;      // 1048576

  float* out_q = (float*)d_out;             // 32768 x 16
  float* out_h = (float*)d_out + 524288;    // 32768 x 64

  hipLaunchKernelGGL(k_fgru, dim3(256), dim3(256), 0, stream,
                     inputs, hidden, fc1w, fc1b, wih, whh, bih, bhh, hT, out_h);
  hipLaunchKernelGGL(k_heads, dim3(512), dim3(256), 0, stream, hT, fc2w, fc2b, wqw, wqb, ew1, eb1, qT, queryT, z1T, part);
  hipLaunchKernelGGL(k_bnstat, dim3(1), dim3(64), 0, stream, part, bng, bnb, stat);
  hipLaunchKernelGGL(k_emb_gemm, dim3(2048), dim3(256), 0, stream, z1T, stat, ew2, eb2, eps, latT);
  hipLaunchKernelGGL(k_alpha, dim3(256), dim3(128), 0, stream, latT, queryT, wkw, wkb, alphaT);
  hipLaunchKernelGGL(k_msg, dim3(2048), dim3(256), 0, stream, hT, latT, alphaT, qT, w1, b1, w2, b2, out_q);
}

// Round 6
// 461.733 us; speedup vs baseline: 3.6563x; 1.1760x over previous
//
#include <hip/hip_runtime.h>
#include <math.h>

namespace {

constexpr int NROW = 32768;   // BS*A rows
constexpr int HDIM = 64;
constexpr int DH   = 512;     // latent half-dim

typedef __attribute__((ext_vector_type(8))) short bf16x8;
typedef __attribute__((ext_vector_type(4))) float f32x4;
typedef __attribute__((ext_vector_type(4))) unsigned uint4e;
typedef __attribute__((ext_vector_type(2))) unsigned uint2e;

__device__ __forceinline__ float sigmoidf_(float x) { return 1.f / (1.f + __expf(-x)); }
__device__ __forceinline__ float lrelu_(float x) { return x > 0.f ? x : 0.01f * x; }
__device__ __forceinline__ unsigned f2bf(float x) {  // RNE float->bf16 (as low 16 bits)
  unsigned u = __float_as_uint(x);
  return (u + 0x7fffu + ((u >> 16) & 1u)) >> 16;
}
// fast pack: round-half-up bf16 pair (a -> low16, b -> high16), 3 VALU
__device__ __forceinline__ unsigned pkbf(float a, float b) {
  unsigned ua = __float_as_uint(a) + 0x8000u;
  unsigned ub = __float_as_uint(b) + 0x8000u;
  return __builtin_amdgcn_perm(ub, ua, 0x07060302);
}

// K1+K2 fused: x = relu(inputs @ fc1_w^T + b); GRU via 6 MFMA gate GEMMs.
__global__ __launch_bounds__(256, 1) void k_fgru(
    const float* __restrict__ in,      // [N][96]
    const float* __restrict__ hprev,   // [N][64]
    const float* __restrict__ fc1w, const float* __restrict__ fc1b,
    const float* __restrict__ wih, const float* __restrict__ whh,
    const float* __restrict__ bih, const float* __restrict__ bhh,
    float* __restrict__ hT, float* __restrict__ hout) {
  __shared__ char smem[132096];
  const int t = threadIdx.x;
  const int n0 = blockIdx.x * 128;
  unsigned* inU  = (unsigned*)smem;                    // [128][52]
  unsigned* f1U  = (unsigned*)(smem + 26624);          // [64][52]
  unsigned* xU   = (unsigned*)(smem + 39936);          // [128][36]
  unsigned* hU   = (unsigned*)(smem + 58368);          // [128][36]
  unsigned* gU   = (unsigned*)(smem + 76800);          // [6][64][36]
  float*    trF  = (float*)smem;                       // [64][133] overlaps inU/f1U

  const float2* in2 = (const float2*)in;
#pragma unroll 1
  for (int i = 0; i < 24; ++i) {
    int idx = t + 256 * i;
    int nl = idx / 48, kp = idx - nl * 48;
    float2 v = in2[(size_t)(n0 + nl) * 48 + kp];
    inU[nl * 52 + kp] = f2bf(v.x) | (f2bf(v.y) << 16);
  }
  const float2* f1w2 = (const float2*)fc1w;
#pragma unroll 1
  for (int i = 0; i < 12; ++i) {
    int idx = t + 256 * i;
    int cl = idx / 48, kp = idx - cl * 48;
    float2 v = f1w2[cl * 48 + kp];
    f1U[cl * 52 + kp] = f2bf(v.x) | (f2bf(v.y) << 16);
  }
  const float2* h2 = (const float2*)hprev;
#pragma unroll 1
  for (int i = 0; i < 16; ++i) {
    int idx = t + 256 * i;
    int nl = idx >> 5, kp = idx & 31;
    float2 v = h2[(size_t)(n0 + nl) * 32 + kp];
    hU[nl * 36 + kp] = f2bf(v.x) | (f2bf(v.y) << 16);
  }
  const float2* wih2 = (const float2*)wih;
  const float2* whh2 = (const float2*)whh;
#pragma unroll 1
  for (int i = 0; i < 24; ++i) {
    int idx = t + 256 * i;
    int row = idx >> 5, kp = idx & 31;
    float2 v = wih2[row * 32 + kp];
    int gate = row >> 6, cl = row & 63;
    gU[(gate * 64 + cl) * 36 + kp] = f2bf(v.x) | (f2bf(v.y) << 16);
  }
#pragma unroll 1
  for (int i = 0; i < 24; ++i) {
    int idx = t + 256 * i;
    int row = idx >> 5, kp = idx & 31;
    float2 v = whh2[row * 32 + kp];
    int gate = row >> 6, cl = row & 63;
    gU[((gate + 3) * 64 + cl) * 36 + kp] = f2bf(v.x) | (f2bf(v.y) << 16);
  }
  __syncthreads();

  const int w = t >> 6, l = t & 63;
  const int m = l & 15, g = l >> 4;
  const short* inS = (const short*)inU;
  const short* f1S = (const short*)f1U;
  short*       xS  = (short*)xU;
  const short* hS  = (const short*)hU;
  const short* gS  = (const short*)gU;

  // ---- fc1 phase ----
  {
    f32x4 accx[2][4];
#pragma unroll
    for (int mt = 0; mt < 2; ++mt)
#pragma unroll
      for (int ct = 0; ct < 4; ++ct) accx[mt][ct] = (f32x4){0.f, 0.f, 0.f, 0.f};
    bf16x8 af[2][3];
#pragma unroll
    for (int mt = 0; mt < 2; ++mt)
#pragma unroll
      for (int ks = 0; ks < 3; ++ks)
        af[mt][ks] = *(const bf16x8*)(inS + (w * 32 + mt * 16 + m) * 104 + ks * 32 + g * 8);
#pragma unroll
    for (int ct = 0; ct < 4; ++ct)
#pragma unroll
      for (int ks = 0; ks < 3; ++ks) {
        bf16x8 bw = *(const bf16x8*)(f1S + (ct * 16 + m) * 104 + ks * 32 + g * 8);
#pragma unroll
        for (int mt = 0; mt < 2; ++mt)
          accx[mt][ct] = __builtin_amdgcn_mfma_f32_16x16x32_bf16(af[mt][ks], bw, accx[mt][ct], 0, 0, 0);
      }
#pragma unroll
    for (int mt = 0; mt < 2; ++mt)
#pragma unroll
      for (int ct = 0; ct < 4; ++ct) {
        int c = ct * 16 + m;
        float bc = fc1b[c];
#pragma unroll
        for (int reg = 0; reg < 4; ++reg) {
          int nl = w * 32 + mt * 16 + g * 4 + reg;
          float v = fmaxf(accx[mt][ct][reg] + bc, 0.f);
          xS[nl * 72 + c] = (short)f2bf(v);
        }
      }
  }
  __syncthreads();

  // ---- GRU phase ----
  bf16x8 ax[2][2], ah[2][2];
#pragma unroll
  for (int mt = 0; mt < 2; ++mt)
#pragma unroll
    for (int ks = 0; ks < 2; ++ks) {
      ax[mt][ks] = *(const bf16x8*)((const short*)xU + (w * 32 + mt * 16 + m) * 72 + ks * 32 + g * 8);
      ah[mt][ks] = *(const bf16x8*)(hS + (w * 32 + mt * 16 + m) * 72 + ks * 32 + g * 8);
    }
#pragma unroll 1
  for (int ct = 0; ct < 4; ++ct) {
    f32x4 a_ir[2], a_iz[2], a_in[2], a_hr[2], a_hz[2], a_hn[2];
#pragma unroll
    for (int mt = 0; mt < 2; ++mt) {
      a_ir[mt] = (f32x4){0.f, 0.f, 0.f, 0.f}; a_iz[mt] = (f32x4){0.f, 0.f, 0.f, 0.f};
      a_in[mt] = (f32x4){0.f, 0.f, 0.f, 0.f}; a_hr[mt] = (f32x4){0.f, 0.f, 0.f, 0.f};
      a_hz[mt] = (f32x4){0.f, 0.f, 0.f, 0.f}; a_hn[mt] = (f32x4){0.f, 0.f, 0.f, 0.f};
    }
    int crow = ct * 16 + m;
#pragma unroll
    for (int ks = 0; ks < 2; ++ks) {
      bf16x8 b0 = *(const bf16x8*)(gS + (0 * 64 + crow) * 72 + ks * 32 + g * 8);
      bf16x8 b1 = *(const bf16x8*)(gS + (1 * 64 + crow) * 72 + ks * 32 + g * 8);
      bf16x8 b2 = *(const bf16x8*)(gS + (2 * 64 + crow) * 72 + ks * 32 + g * 8);
      bf16x8 b3 = *(const bf16x8*)(gS + (3 * 64 + crow) * 72 + ks * 32 + g * 8);
      bf16x8 b4 = *(const bf16x8*)(gS + (4 * 64 + crow) * 72 + ks * 32 + g * 8);
      bf16x8 b5 = *(const bf16x8*)(gS + (5 * 64 + crow) * 72 + ks * 32 + g * 8);
#pragma unroll
      for (int mt = 0; mt < 2; ++mt) {
        a_ir[mt] = __builtin_amdgcn_mfma_f32_16x16x32_bf16(ax[mt][ks], b0, a_ir[mt], 0, 0, 0);
        a_iz[mt] = __builtin_amdgcn_mfma_f32_16x16x32_bf16(ax[mt][ks], b1, a_iz[mt], 0, 0, 0);
        a_in[mt] = __builtin_amdgcn_mfma_f32_16x16x32_bf16(ax[mt][ks], b2, a_in[mt], 0, 0, 0);
        a_hr[mt] = __builtin_amdgcn_mfma_f32_16x16x32_bf16(ah[mt][ks], b3, a_hr[mt], 0, 0, 0);
        a_hz[mt] = __builtin_amdgcn_mfma_f32_16x16x32_bf16(ah[mt][ks], b4, a_hz[mt], 0, 0, 0);
        a_hn[mt] = __builtin_amdgcn_mfma_f32_16x16x32_bf16(ah[mt][ks], b5, a_hn[mt], 0, 0, 0);
      }
    }
    int c = crow;
    float bir = bih[c], biz = bih[64 + c], bin = bih[128 + c];
    float bhr = bhh[c], bhz = bhh[64 + c], bhn = bhh[128 + c];
#pragma unroll
    for (int mt = 0; mt < 2; ++mt)
#pragma unroll
      for (int reg = 0; reg < 4; ++reg) {
        int nl = w * 32 + mt * 16 + g * 4 + reg;
        float hv = hprev[(size_t)(n0 + nl) * 64 + c];
        float r  = sigmoidf_(a_ir[mt][reg] + bir + a_hr[mt][reg] + bhr);
        float z  = sigmoidf_(a_iz[mt][reg] + biz + a_hz[mt][reg] + bhz);
        float nn = tanhf(a_in[mt][reg] + bin + r * (a_hn[mt][reg] + bhn));
        float hc = (1.f - z) * nn + z * hv;
        trF[c * 133 + nl] = hc;
      }
  }
  __syncthreads();
#pragma unroll 1
  for (int i = 0; i < 32; ++i) {
    int idx = t + 256 * i;
    int nl = idx & 127, cl = idx >> 7;
    hT[(size_t)cl * NROW + n0 + nl] = trF[cl * 133 + nl];
  }
#pragma unroll 1
  for (int i = 0; i < 32; ++i) {
    int idx = t + 256 * i;
    int c = idx & 63, nl = idx >> 6;
    hout[(size_t)(n0 + nl) * 64 + c] = trF[c * 133 + nl];
  }
}

// K3: q, query(scaled), z1 heads + BN partial sums per block
__global__ __launch_bounds__(256) void k_heads(const float* __restrict__ hT,
    const float* __restrict__ fc2w, const float* __restrict__ fc2b,
    const float* __restrict__ wqw, const float* __restrict__ wqb,
    const float* __restrict__ ew1, const float* __restrict__ eb1,
    float* __restrict__ qT, float* __restrict__ queryT, float* __restrict__ z1T,
    float* __restrict__ part) {
  int t = threadIdx.x;
  int n = blockIdx.x * 64 + (t & 63);
  int cq = t >> 6;
  float hv[HDIM];
#pragma unroll 1
  for (int k = 0; k < HDIM; ++k) hv[k] = hT[(size_t)k * NROW + n];
#pragma unroll 1
  for (int ci = 0; ci < 4; ++ci) {
    int c = cq * 4 + ci;
    float acc = fc2b[c];
#pragma unroll
    for (int k = 0; k < HDIM; ++k) acc = fmaf(hv[k], fc2w[c * HDIM + k], acc);
    qT[(size_t)c * NROW + n] = acc;
  }
  const float qs = 0.17677669529663687f;  // 1/sqrt(32)
#pragma unroll 1
  for (int ai = 0; ai < 8; ++ai) {
    int a = cq * 8 + ai;
    float acc = wqb[a];
#pragma unroll
    for (int k = 0; k < HDIM; ++k) acc = fmaf(hv[k], wqw[a * HDIM + k], acc);
    queryT[(size_t)a * NROW + n] = acc * qs;
  }
  __shared__ float ssum[64], ssq[64];
#pragma unroll 1
  for (int ci = 0; ci < 16; ++ci) {
    int c = cq * 16 + ci;
    float acc = eb1[c];
#pragma unroll
    for (int k = 0; k < HDIM; ++k) acc = fmaf(hv[k], ew1[c * HDIM + k], acc);
    z1T[(size_t)c * NROW + n] = acc;
    float s1 = acc, s2 = acc * acc;
#pragma unroll
    for (int off = 32; off > 0; off >>= 1) {
      s1 += __shfl_down(s1, off, 64);
      s2 += __shfl_down(s2, off, 64);
    }
    if ((t & 63) == 0) { ssum[c] = s1; ssq[c] = s2; }
  }
  __syncthreads();
  if (t < 64) {
    part[(size_t)blockIdx.x * 128 + t] = ssum[t];
    part[(size_t)blockIdx.x * 128 + 64 + t] = ssq[t];
  }
}

// K4: finalize BN stats
__global__ void k_bnstat(const float* __restrict__ part,
    const float* __restrict__ bng, const float* __restrict__ bnb,
    float* __restrict__ stat) {
  int c = threadIdx.x;  // 64 threads
  float s1 = 0.f, s2 = 0.f;
  for (int b = 0; b < 512; ++b) {
    s1 += part[(size_t)b * 128 + c];
    s2 += part[(size_t)b * 128 + 64 + c];
  }
  float mean = s1 * (1.f / NROW);
  float var = s2 * (1.f / NROW) - mean * mean;
  float rstd = rsqrtf(var + 1e-5f);
  float sc = bng[c] * rstd;
  stat[c] = sc;
  stat[64 + c] = bnb[c] - mean * sc;
}

// K5: MFMA bf16 GEMM: latent pre-act = lrelu(BN(z1)) @ ew2^T, fused var/eps epilogue.
__global__ __launch_bounds__(256) void k_emb_gemm(const float* __restrict__ z1T,
    const float* __restrict__ stat,
    const float* __restrict__ ew2, const float* __restrict__ eb2,
    const float* __restrict__ eps,
    float* __restrict__ latT) {
  __shared__ char smem[36864];
  const int t = threadIdx.x;
  const int nb = blockIdx.x >> 3;
  const int cb = blockIdx.x & 7;
  const int n0 = nb * 128;
  const int c0 = cb * 64;

  unsigned* aU = (unsigned*)smem;                 // A: [128][36]
  unsigned* bmU = (unsigned*)(smem + 18432);      // Wmu: [64][36]
  unsigned* blU = (unsigned*)(smem + 27648);      // Wlv: [64][36]

#pragma unroll 1
  for (int i = 0; i < 16; ++i) {
    int idx = t + 256 * i;
    int nl = idx & 127;
    int kp = idx >> 7;
    float v0 = z1T[(size_t)(2 * kp) * NROW + n0 + nl];
    float v1 = z1T[(size_t)(2 * kp + 1) * NROW + n0 + nl];
    v0 = lrelu_(fmaf(stat[2 * kp], v0, stat[64 + 2 * kp]));
    v1 = lrelu_(fmaf(stat[2 * kp + 1], v1, stat[64 + 2 * kp + 1]));
    aU[nl * 36 + kp] = f2bf(v0) | (f2bf(v1) << 16);
  }
  const float2* ew2_2 = (const float2*)ew2;
#pragma unroll 1
  for (int i = 0; i < 8; ++i) {
    int idx = t + 256 * i;
    int kp = idx & 31;
    int cl = idx >> 5;
    float2 m2 = ew2_2[(size_t)(c0 + cl) * 32 + kp];
    float2 l2 = ew2_2[(size_t)(512 + c0 + cl) * 32 + kp];
    bmU[cl * 36 + kp] = f2bf(m2.x) | (f2bf(m2.y) << 16);
    blU[cl * 36 + kp] = f2bf(l2.x) | (f2bf(l2.y) << 16);
  }
  __syncthreads();

  const int w = t >> 6, l = t & 63;
  const int m = l & 15, g = l >> 4;
  const short* sA = (const short*)smem;
  const short* sBm = (const short*)(smem + 18432);
  const short* sBl = (const short*)(smem + 27648);

  f32x4 accm[2][4], accl[2][4];
#pragma unroll
  for (int mt = 0; mt < 2; ++mt)
#pragma unroll
    for (int ct = 0; ct < 4; ++ct) {
      accm[mt][ct] = (f32x4){0.f, 0.f, 0.f, 0.f};
      accl[mt][ct] = (f32x4){0.f, 0.f, 0.f, 0.f};
    }
  bf16x8 af[2][2];
#pragma unroll
  for (int mt = 0; mt < 2; ++mt)
#pragma unroll
    for (int ks = 0; ks < 2; ++ks)
      af[mt][ks] = *(const bf16x8*)(sA + (w * 32 + mt * 16 + m) * 72 + ks * 32 + g * 8);
#pragma unroll
  for (int ct = 0; ct < 4; ++ct) {
#pragma unroll
    for (int ks = 0; ks < 2; ++ks) {
      bf16x8 bm = *(const bf16x8*)(sBm + (ct * 16 + m) * 72 + ks * 32 + g * 8);
      bf16x8 bl = *(const bf16x8*)(sBl + (ct * 16 + m) * 72 + ks * 32 + g * 8);
#pragma unroll
      for (int mt = 0; mt < 2; ++mt) {
        accm[mt][ct] = __builtin_amdgcn_mfma_f32_16x16x32_bf16(af[mt][ks], bm, accm[mt][ct], 0, 0, 0);
        accl[mt][ct] = __builtin_amdgcn_mfma_f32_16x16x32_bf16(af[mt][ks], bl, accl[mt][ct], 0, 0, 0);
      }
    }
  }

  float lat[2][4][4];
#pragma unroll
  for (int mt = 0; mt < 2; ++mt) {
    int nl = w * 32 + mt * 16 + g * 4;
#pragma unroll
    for (int reg = 0; reg < 4; ++reg) {
      const float* ep = eps + (size_t)(n0 + nl + reg) * DH + c0;
#pragma unroll
      for (int ct = 0; ct < 4; ++ct) {
        int cl = ct * 16 + m;
        float mu = accm[mt][ct][reg] + eb2[c0 + cl];
        float lv = accl[mt][ct][reg] + eb2[DH + c0 + cl];
        lat[mt][ct][reg] = fmaf(sqrtf(fmaxf(__expf(lv), 0.002f)), ep[cl], mu);
      }
    }
  }
  __syncthreads();
  float* outF = (float*)smem;     // [64][133]
#pragma unroll
  for (int mt = 0; mt < 2; ++mt)
#pragma unroll
    for (int ct = 0; ct < 4; ++ct)
#pragma unroll
      for (int reg = 0; reg < 4; ++reg)
        outF[(ct * 16 + m) * 133 + w * 32 + mt * 16 + g * 4 + reg] = lat[mt][ct][reg];
  __syncthreads();
#pragma unroll 1
  for (int i = 0; i < 32; ++i) {
    int idx = t + 256 * i;
    int nl = idx & 127;
    int cl = idx >> 7;
    latT[(size_t)(c0 + cl) * NROW + n0 + nl] = outF[cl * 133 + nl];
  }
}

// K6: alpha via factorization: logit[n,j] = (Wk^T q)[n] . lat[n,j] + q[n].kb
__global__ __launch_bounds__(128) void k_alpha(const float* __restrict__ latT,
    const float* __restrict__ queryT,
    const float* __restrict__ wkw, const float* __restrict__ wkb,
    float* __restrict__ alphaT) {
  int n = blockIdx.x * 128 + threadIdx.x;
  float qr[32];
#pragma unroll
  for (int a = 0; a < 32; ++a) qr[a] = queryT[(size_t)a * NROW + n];
  float qk[16];
#pragma unroll
  for (int l = 0; l < 16; ++l) qk[l] = 0.f;
  float qb = 0.f;
#pragma unroll
  for (int a = 0; a < 32; ++a) {
    qb = fmaf(qr[a], wkb[a], qb);
#pragma unroll
    for (int l = 0; l < 16; ++l) qk[l] = fmaf(qr[a], wkw[a * 16 + l], qk[l]);
  }
  int idiag = n & 31;
  float al[32];
#pragma unroll 4
  for (int j = 0; j < 32; ++j) {
    float acc = qb;
#pragma unroll
    for (int l = 0; l < 16; ++l)
      acc = fmaf(latT[(size_t)(j * 16 + l) * NROW + n], qk[l], acc);
    al[j] = (j == idiag) ? -1e9f : acc;
  }
  float m = -1e30f;
#pragma unroll
  for (int j = 0; j < 32; ++j) m = fmaxf(m, al[j]);
  float se = 0.f;
#pragma unroll
  for (int j = 0; j < 32; ++j) { al[j] = __expf(al[j] - m); se += al[j]; }
  float inv = 1.f / se;
#pragma unroll
  for (int j = 0; j < 32; ++j)
    alphaT[(size_t)j * NROW + n] = al[j] * inv;
}

// K7 (MFMA rewrite): one block per b. Three chained MFMA phases, all tiles
// co-designed so C-layout (col=lane&15, row=quad*4+reg) flows phase to phase.
//   phase1: hp[c][j]  = w1h . h           (regs, per wave: its jh half)
//   per i : pre[c][j] = w1lat . lat(i)    (K=16 in 16x16x32, quads 2,3 zero)
//           m = lrelu(pre+hp) -> bf16 -> per-wave LDS buffer (c-permutation pi)
//           msg[nn][j] = w2P . mT         (w2 staged with same pi)
//           agg[nn][j] += alpha(i,j) * (msg + b2)
// LDS layouts byte offsets (74112 total -> 2 blocks/CU):
constexpr int LATB_OFF = 0;        // [1024][20] bf16, 40B rows (r = i*32+j)
constexpr int H3B_OFF  = 40960;    // [32][72] bf16, 144B rows
constexpr int W1H_OFF  = 45568;    // [64][72] bf16
constexpr int W1L_OFF  = 54784;    // [64][20] bf16
constexpr int W2P_OFF  = 57344;    // [16][72] bf16 (pi-permuted c)
constexpr int ALL_OFF  = 59648;    // [32][33] f32
constexpr int MT_OFF   = 63872;    // 4 waves x 2560B private transpose buf
__global__ __launch_bounds__(256, 1) void k_msg(
    const float* __restrict__ latT, const float* __restrict__ alphaT,
    const float* __restrict__ qT, const float* __restrict__ hrow,
    const float* __restrict__ w1, const float* __restrict__ b1,
    const float* __restrict__ w2, const float* __restrict__ b2,
    float* __restrict__ out) {
  __shared__ char smem[74112];
  const int t = threadIdx.x;
  const int b = blockIdx.x;
  const int b32 = b * 32;
  unsigned* latB_dw = (unsigned*)(smem + LATB_OFF);

  // ---- staging ----
  {  // latB: lat[i][j][l] bf16, rows r=i*32+j (20 bf16 = 10 dw)
    int j5 = t >> 3, lp = t & 7;
    const float4* lat4 = (const float4*)latT;
#pragma unroll 1
    for (int i0 = 0; i0 < 32; i0 += 4) {
      float4 v0 = lat4[((size_t)(j5 * 16 + 2 * lp) * NROW + b32 + i0) >> 2];
      float4 v1 = lat4[((size_t)(j5 * 16 + 2 * lp + 1) * NROW + b32 + i0) >> 2];
      latB_dw[((i0 + 0) * 32 + j5) * 10 + lp] = f2bf(v0.x) | (f2bf(v1.x) << 16);
      latB_dw[((i0 + 1) * 32 + j5) * 10 + lp] = f2bf(v0.y) | (f2bf(v1.y) << 16);
      latB_dw[((i0 + 2) * 32 + j5) * 10 + lp] = f2bf(v0.z) | (f2bf(v1.z) << 16);
      latB_dw[((i0 + 3) * 32 + j5) * 10 + lp] = f2bf(v0.w) | (f2bf(v1.w) << 16);
    }
  }
  {  // h3B[j][k] bf16 from row-major h (d_out region)
    int cp = t & 31, jj = t >> 5;
    const float2* h2 = (const float2*)hrow;
    unsigned* dst = (unsigned*)(smem + H3B_OFF);
#pragma unroll 1
    for (int it = 0; it < 4; ++it) {
      int j = jj + 8 * it;
      float2 hv = h2[((size_t)(b32 + j) * 64 + 2 * cp) >> 1];
      dst[j * 36 + cp] = f2bf(hv.x) | (f2bf(hv.y) << 16);
    }
  }
  {  // w1hL[c][k] (k<64)
    int kp = t & 31, cc = t >> 5;
    const float2* w12 = (const float2*)w1;
    unsigned* dst = (unsigned*)(smem + W1H_OFF);
#pragma unroll 1
    for (int it = 0; it < 8; ++it) {
      int c = cc + 8 * it;
      float2 wv = w12[(c * 80 + 2 * kp) >> 1];
      dst[c * 36 + kp] = f2bf(wv.x) | (f2bf(wv.y) << 16);
    }
  }
  {  // w1latL[c][l]
    int lp = t & 7, cc = t >> 3;
    const float2* w12 = (const float2*)w1;
    unsigned* dst = (unsigned*)(smem + W1L_OFF);
#pragma unroll 1
    for (int it = 0; it < 2; ++it) {
      int c = cc + 32 * it;
      float2 wv = w12[(c * 80 + 64 + 2 * lp) >> 1];
      dst[c * 10 + lp] = f2bf(wv.x) | (f2bf(wv.y) << 16);
    }
  }
  {  // w2P[nn][p] = w2[nn][c(p)], c(p) = ((p>>2)&3)*16 + (p>>4)*4 + (p&3)
    int pp = t & 31, nn = t >> 5;
    const float2* w22 = (const float2*)w2;
    unsigned* dst = (unsigned*)(smem + W2P_OFF);
#pragma unroll 1
    for (int it = 0; it < 2; ++it) {
      int n2 = nn + 8 * it;
      int p = 2 * pp;
      int c = ((p >> 2) & 3) * 16 + (p >> 4) * 4 + (p & 3);
      float2 wv = w22[(n2 * 64 + c) >> 1];
      dst[n2 * 36 + pp] = f2bf(wv.x) | (f2bf(wv.y) << 16);
    }
  }
  {  // alL[i][j]
    int i = t & 31, jj = t >> 5;
    float* alL = (float*)(smem + ALL_OFF);
#pragma unroll 1
    for (int it = 0; it < 4; ++it) {
      int j = jj + 8 * it;
      alL[i * 33 + j] = alphaT[(size_t)j * NROW + b32 + i];
    }
  }
  __syncthreads();

  const int w = t >> 6, l = t & 63;
  const int n15 = l & 15, q = l >> 4;
  const int jh = w & 1, ibase = (w >> 1) * 16;
  const bool kact = (q < 2);

  // ---- phase 1: hp[ct][reg] for (c = ct*16+q*4+reg, j = jh*16+n15) ----
  f32x4 hp[4];
#pragma unroll
  for (int ct = 0; ct < 4; ++ct) hp[ct] = (f32x4){0.f, 0.f, 0.f, 0.f};
#pragma unroll
  for (int ct = 0; ct < 4; ++ct)
#pragma unroll
    for (int ks = 0; ks < 2; ++ks) {
      bf16x8 aF = *(const bf16x8*)(smem + W1H_OFF + (ct * 16 + n15) * 144 + ks * 64 + q * 16);
      bf16x8 bF = *(const bf16x8*)(smem + H3B_OFF + (jh * 16 + n15) * 144 + ks * 64 + q * 16);
      hp[ct] = __builtin_amdgcn_mfma_f32_16x16x32_bf16(aF, bF, hp[ct], 0, 0, 0);
    }
#pragma unroll
  for (int ct = 0; ct < 4; ++ct)
#pragma unroll
    for (int reg = 0; reg < 4; ++reg)
      hp[ct][reg] += b1[ct * 16 + q * 4 + reg];

  // hoisted fragments
  bf16x8 aL[4];
#pragma unroll
  for (int ct = 0; ct < 4; ++ct) {
    union { unsigned u[4]; bf16x8 h; } tmp;
    tmp.u[0] = tmp.u[1] = tmp.u[2] = tmp.u[3] = 0u;
    if (kact) {
      const unsigned* p = (const unsigned*)(smem + W1L_OFF) + (ct * 16 + n15) * 10 + q * 4;
      uint2e d0 = *(const uint2e*)p;
      uint2e d1 = *(const uint2e*)(p + 2);
      tmp.u[0] = d0.x; tmp.u[1] = d0.y; tmp.u[2] = d1.x; tmp.u[3] = d1.y;
    }
    aL[ct] = tmp.h;
  }
  bf16x8 w2F[2];
#pragma unroll
  for (int ks = 0; ks < 2; ++ks)
    w2F[ks] = *(const bf16x8*)(smem + W2P_OFF + n15 * 144 + ks * 64 + q * 16);
  float b2v[4];
#pragma unroll
  for (int reg = 0; reg < 4; ++reg) b2v[reg] = b2[q * 4 + reg];

  // ---- main i loop ----
  float agg[4] = {0.f, 0.f, 0.f, 0.f};
  char* wb = smem + MT_OFF + w * 2560;
  const float* alLf = (const float*)(smem + ALL_OFF);
#pragma unroll 1
  for (int it = 0; it < 16; ++it) {
    int ii = ibase + it;
    int r = ii * 32 + jh * 16 + n15;
    union { unsigned u[4]; bf16x8 h; } latF;
    latF.u[0] = latF.u[1] = latF.u[2] = latF.u[3] = 0u;
    if (kact) {
      const unsigned* p = latB_dw + r * 10 + q * 4;
      uint2e d0 = *(const uint2e*)p;
      uint2e d1 = *(const uint2e*)(p + 2);
      latF.u[0] = d0.x; latF.u[1] = d0.y; latF.u[2] = d1.x; latF.u[3] = d1.y;
    }
    f32x4 acc[4];
#pragma unroll
    for (int ct = 0; ct < 4; ++ct) {
      acc[ct] = (f32x4){0.f, 0.f, 0.f, 0.f};
      acc[ct] = __builtin_amdgcn_mfma_f32_16x16x32_bf16(aL[ct], latF.h, acc[ct], 0, 0, 0);
    }
    // lrelu + pack + pi-transpose write (per-wave private buffer, no barrier)
#pragma unroll
    for (int h = 0; h < 2; ++h) {
      float m0[4], m1[4];
#pragma unroll
      for (int reg = 0; reg < 4; ++reg) {
        float v0 = acc[2 * h][reg] + hp[2 * h][reg];
        float v1 = acc[2 * h + 1][reg] + hp[2 * h + 1][reg];
        m0[reg] = fmaxf(v0, 0.01f * v0);
        m1[reg] = fmaxf(v1, 0.01f * v1);
      }
      uint4e pk4;
      pk4.x = pkbf(m0[0], m0[1]); pk4.y = pkbf(m0[2], m0[3]);
      pk4.z = pkbf(m1[0], m1[1]); pk4.w = pkbf(m1[2], m1[3]);
      int qp = (2 * q + h) & 3;
      *(uint4e*)(wb + (q >> 1) * 1280 + n15 * 80 + qp * 16) = pk4;
    }
    // phase 3
    f32x4 msg = (f32x4){0.f, 0.f, 0.f, 0.f};
#pragma unroll
    for (int ks = 0; ks < 2; ++ks) {
      bf16x8 mF = *(const bf16x8*)(wb + ks * 1280 + n15 * 80 + q * 16);
      msg = __builtin_amdgcn_mfma_f32_16x16x32_bf16(w2F[ks], mF, msg, 0, 0, 0);
    }
    float aw = alLf[ii * 33 + jh * 16 + n15];
#pragma unroll
    for (int reg = 0; reg < 4; ++reg)
      agg[reg] = fmaf(aw, msg[reg] + b2v[reg], agg[reg]);
  }
  // park agg in own wave buffer: float at n15*80 + (q*4+reg)*4
  {
    f32x4 av; av[0] = agg[0]; av[1] = agg[1]; av[2] = agg[2]; av[3] = agg[3];
    *(f32x4*)(wb + n15 * 80 + q * 16) = av;
  }
  __syncthreads();
  // combine wave pairs (i-low + i-high) and add q head
#pragma unroll
  for (int tt = 0; tt < 2; ++tt) {
    int idx = t + 256 * tt;
    int jg = idx >> 4, nn = idx & 15;
    int jh2 = jg >> 4, jl = jg & 15;
    float a0 = *(const float*)(smem + MT_OFF + jh2 * 2560 + jl * 80 + nn * 4);
    float a1 = *(const float*)(smem + MT_OFF + (jh2 + 2) * 2560 + jl * 80 + nn * 4);
    out[(size_t)b * 512 + idx] = a0 + a1 + qT[(size_t)nn * NROW + b32 + jg];
  }
}

}  // namespace

extern "C" void kernel_launch(void* const* d_in, const int* in_sizes, int n_in,
                              void* d_out, int out_size, void* d_ws, size_t ws_size,
                              hipStream_t stream) {
  (void)in_sizes; (void)n_in; (void)out_size; (void)ws_size;
  const float* inputs = (const float*)d_in[0];
  const float* hidden = (const float*)d_in[1];
  const float* eps    = (const float*)d_in[2];
  const float* fc1w   = (const float*)d_in[3];
  const float* fc1b   = (const float*)d_in[4];
  const float* wih    = (const float*)d_in[5];
  const float* whh    = (const float*)d_in[6];
  const float* bih    = (const float*)d_in[7];
  const float* bhh    = (const float*)d_in[8];
  const float* fc2w   = (const float*)d_in[9];
  const float* fc2b   = (const float*)d_in[10];
  const float* ew1    = (const float*)d_in[11];
  const float* eb1    = (const float*)d_in[12];
  const float* bng    = (const float*)d_in[13];
  const float* bnb    = (const float*)d_in[14];
  const float* ew2    = (const float*)d_in[15];
  const float* eb2    = (const float*)d_in[16];
  const float* w1     = (const float*)d_in[17];
  const float* b1     = (const float*)d_in[18];
  const float* w2     = (const float*)d_in[19];
  const float* b2     = (const float*)d_in[20];
  const float* wqw    = (const float*)d_in[21];
  const float* wqb    = (const float*)d_in[22];
  const float* wkw    = (const float*)d_in[23];
  const float* wkb    = (const float*)d_in[24];

  float* ws = (float*)d_ws;
  float* hT     = ws;                 // 2097152
  float* qT     = ws + 2097152;       // 524288
  float* queryT = ws + 2621440;       // 1048576
  float* z1T    = ws + 3670016;       // 2097152
  float* part   = ws + 5767168;       // 65536
  float* stat   = ws + 5832704;       // 128
  float* latT   = ws + 5832832;       // 16777216
  float* alphaT = ws + 22610048;      // 1048576

  float* out_q = (float*)d_out;             // 32768 x 16
  float* out_h = (float*)d_out + 524288;    // 32768 x 64

  hipLaunchKernelGGL(k_fgru, dim3(256), dim3(256), 0, stream,
                     inputs, hidden, fc1w, fc1b, wih, whh, bih, bhh, hT, out_h);
  hipLaunchKernelGGL(k_heads, dim3(512), dim3(256), 0, stream, hT, fc2w, fc2b, wqw, wqb, ew1, eb1, qT, queryT, z1T, part);
  hipLaunchKernelGGL(k_bnstat, dim3(1), dim3(64), 0, stream, part, bng, bnb, stat);
  hipLaunchKernelGGL(k_emb_gemm, dim3(2048), dim3(256), 0, stream, z1T, stat, ew2, eb2, eps, latT);
  hipLaunchKernelGGL(k_alpha, dim3(256), dim3(128), 0, stream, latT, queryT, wkw, wkb, alphaT);
  hipLaunchKernelGGL(k_msg, dim3(1024), dim3(256), 0, stream,
                     latT, alphaT, qT, out_h, w1, b1, w2, b2, out_q);
}

// Round 7
// 346.737 us; speedup vs baseline: 4.8689x; 1.3317x over previous
//
#include <hip/hip_runtime.h>
#include <math.h>

namespace {

constexpr int NROW = 32768;   // BS*A rows
constexpr int HDIM = 64;
constexpr int DH   = 512;     // latent half-dim

typedef __attribute__((ext_vector_type(8))) short bf16x8;
typedef __attribute__((ext_vector_type(4))) float f32x4;
typedef __attribute__((ext_vector_type(4))) unsigned uint4e;
typedef __attribute__((ext_vector_type(2))) unsigned uint2e;

__device__ __forceinline__ float sigmoidf_(float x) { return 1.f / (1.f + __expf(-x)); }
__device__ __forceinline__ float lrelu_(float x) { return x > 0.f ? x : 0.01f * x; }
__device__ __forceinline__ unsigned f2bf(float x) {  // RNE float->bf16 (as low 16 bits)
  unsigned u = __float_as_uint(x);
  return (u + 0x7fffu + ((u >> 16) & 1u)) >> 16;
}
// fast pack: round-half-up bf16 pair (a -> low16, b -> high16), 3 VALU
__device__ __forceinline__ unsigned pkbf(float a, float b) {
  unsigned ua = __float_as_uint(a) + 0x8000u;
  unsigned ub = __float_as_uint(b) + 0x8000u;
  return __builtin_amdgcn_perm(ub, ua, 0x07060302);
}

// K1+K2 fused: x = relu(inputs @ fc1_w^T + b); GRU via 6 MFMA gate GEMMs.
__global__ __launch_bounds__(256, 1) void k_fgru(
    const float* __restrict__ in,      // [N][96]
    const float* __restrict__ hprev,   // [N][64]
    const float* __restrict__ fc1w, const float* __restrict__ fc1b,
    const float* __restrict__ wih, const float* __restrict__ whh,
    const float* __restrict__ bih, const float* __restrict__ bhh,
    float* __restrict__ hT, float* __restrict__ hout) {
  __shared__ char smem[132096];
  const int t = threadIdx.x;
  const int n0 = blockIdx.x * 128;
  unsigned* inU  = (unsigned*)smem;                    // [128][52]
  unsigned* f1U  = (unsigned*)(smem + 26624);          // [64][52]
  unsigned* xU   = (unsigned*)(smem + 39936);          // [128][36]
  unsigned* hU   = (unsigned*)(smem + 58368);          // [128][36]
  unsigned* gU   = (unsigned*)(smem + 76800);          // [6][64][36]
  float*    trF  = (float*)smem;                       // [64][133] overlaps inU/f1U

  const float2* in2 = (const float2*)in;
#pragma unroll 1
  for (int i = 0; i < 24; ++i) {
    int idx = t + 256 * i;
    int nl = idx / 48, kp = idx - nl * 48;
    float2 v = in2[(size_t)(n0 + nl) * 48 + kp];
    inU[nl * 52 + kp] = f2bf(v.x) | (f2bf(v.y) << 16);
  }
  const float2* f1w2 = (const float2*)fc1w;
#pragma unroll 1
  for (int i = 0; i < 12; ++i) {
    int idx = t + 256 * i;
    int cl = idx / 48, kp = idx - cl * 48;
    float2 v = f1w2[cl * 48 + kp];
    f1U[cl * 52 + kp] = f2bf(v.x) | (f2bf(v.y) << 16);
  }
  const float2* h2 = (const float2*)hprev;
#pragma unroll 1
  for (int i = 0; i < 16; ++i) {
    int idx = t + 256 * i;
    int nl = idx >> 5, kp = idx & 31;
    float2 v = h2[(size_t)(n0 + nl) * 32 + kp];
    hU[nl * 36 + kp] = f2bf(v.x) | (f2bf(v.y) << 16);
  }
  const float2* wih2 = (const float2*)wih;
  const float2* whh2 = (const float2*)whh;
#pragma unroll 1
  for (int i = 0; i < 24; ++i) {
    int idx = t + 256 * i;
    int row = idx >> 5, kp = idx & 31;
    float2 v = wih2[row * 32 + kp];
    int gate = row >> 6, cl = row & 63;
    gU[(gate * 64 + cl) * 36 + kp] = f2bf(v.x) | (f2bf(v.y) << 16);
  }
#pragma unroll 1
  for (int i = 0; i < 24; ++i) {
    int idx = t + 256 * i;
    int row = idx >> 5, kp = idx & 31;
    float2 v = whh2[row * 32 + kp];
    int gate = row >> 6, cl = row & 63;
    gU[((gate + 3) * 64 + cl) * 36 + kp] = f2bf(v.x) | (f2bf(v.y) << 16);
  }
  __syncthreads();

  const int w = t >> 6, l = t & 63;
  const int m = l & 15, g = l >> 4;
  const short* inS = (const short*)inU;
  const short* f1S = (const short*)f1U;
  short*       xS  = (short*)xU;
  const short* hS  = (const short*)hU;
  const short* gS  = (const short*)gU;

  // ---- fc1 phase ----
  {
    f32x4 accx[2][4];
#pragma unroll
    for (int mt = 0; mt < 2; ++mt)
#pragma unroll
      for (int ct = 0; ct < 4; ++ct) accx[mt][ct] = (f32x4){0.f, 0.f, 0.f, 0.f};
    bf16x8 af[2][3];
#pragma unroll
    for (int mt = 0; mt < 2; ++mt)
#pragma unroll
      for (int ks = 0; ks < 3; ++ks)
        af[mt][ks] = *(const bf16x8*)(inS + (w * 32 + mt * 16 + m) * 104 + ks * 32 + g * 8);
#pragma unroll
    for (int ct = 0; ct < 4; ++ct)
#pragma unroll
      for (int ks = 0; ks < 3; ++ks) {
        bf16x8 bw = *(const bf16x8*)(f1S + (ct * 16 + m) * 104 + ks * 32 + g * 8);
#pragma unroll
        for (int mt = 0; mt < 2; ++mt)
          accx[mt][ct] = __builtin_amdgcn_mfma_f32_16x16x32_bf16(af[mt][ks], bw, accx[mt][ct], 0, 0, 0);
      }
#pragma unroll
    for (int mt = 0; mt < 2; ++mt)
#pragma unroll
      for (int ct = 0; ct < 4; ++ct) {
        int c = ct * 16 + m;
        float bc = fc1b[c];
#pragma unroll
        for (int reg = 0; reg < 4; ++reg) {
          int nl = w * 32 + mt * 16 + g * 4 + reg;
          float v = fmaxf(accx[mt][ct][reg] + bc, 0.f);
          xS[nl * 72 + c] = (short)f2bf(v);
        }
      }
  }
  __syncthreads();

  // ---- GRU phase ----
  bf16x8 ax[2][2], ah[2][2];
#pragma unroll
  for (int mt = 0; mt < 2; ++mt)
#pragma unroll
    for (int ks = 0; ks < 2; ++ks) {
      ax[mt][ks] = *(const bf16x8*)((const short*)xU + (w * 32 + mt * 16 + m) * 72 + ks * 32 + g * 8);
      ah[mt][ks] = *(const bf16x8*)(hS + (w * 32 + mt * 16 + m) * 72 + ks * 32 + g * 8);
    }
#pragma unroll 1
  for (int ct = 0; ct < 4; ++ct) {
    f32x4 a_ir[2], a_iz[2], a_in[2], a_hr[2], a_hz[2], a_hn[2];
#pragma unroll
    for (int mt = 0; mt < 2; ++mt) {
      a_ir[mt] = (f32x4){0.f, 0.f, 0.f, 0.f}; a_iz[mt] = (f32x4){0.f, 0.f, 0.f, 0.f};
      a_in[mt] = (f32x4){0.f, 0.f, 0.f, 0.f}; a_hr[mt] = (f32x4){0.f, 0.f, 0.f, 0.f};
      a_hz[mt] = (f32x4){0.f, 0.f, 0.f, 0.f}; a_hn[mt] = (f32x4){0.f, 0.f, 0.f, 0.f};
    }
    int crow = ct * 16 + m;
#pragma unroll
    for (int ks = 0; ks < 2; ++ks) {
      bf16x8 b0 = *(const bf16x8*)(gS + (0 * 64 + crow) * 72 + ks * 32 + g * 8);
      bf16x8 b1 = *(const bf16x8*)(gS + (1 * 64 + crow) * 72 + ks * 32 + g * 8);
      bf16x8 b2 = *(const bf16x8*)(gS + (2 * 64 + crow) * 72 + ks * 32 + g * 8);
      bf16x8 b3 = *(const bf16x8*)(gS + (3 * 64 + crow) * 72 + ks * 32 + g * 8);
      bf16x8 b4 = *(const bf16x8*)(gS + (4 * 64 + crow) * 72 + ks * 32 + g * 8);
      bf16x8 b5 = *(const bf16x8*)(gS + (5 * 64 + crow) * 72 + ks * 32 + g * 8);
#pragma unroll
      for (int mt = 0; mt < 2; ++mt) {
        a_ir[mt] = __builtin_amdgcn_mfma_f32_16x16x32_bf16(ax[mt][ks], b0, a_ir[mt], 0, 0, 0);
        a_iz[mt] = __builtin_amdgcn_mfma_f32_16x16x32_bf16(ax[mt][ks], b1, a_iz[mt], 0, 0, 0);
        a_in[mt] = __builtin_amdgcn_mfma_f32_16x16x32_bf16(ax[mt][ks], b2, a_in[mt], 0, 0, 0);
        a_hr[mt] = __builtin_amdgcn_mfma_f32_16x16x32_bf16(ah[mt][ks], b3, a_hr[mt], 0, 0, 0);
        a_hz[mt] = __builtin_amdgcn_mfma_f32_16x16x32_bf16(ah[mt][ks], b4, a_hz[mt], 0, 0, 0);
        a_hn[mt] = __builtin_amdgcn_mfma_f32_16x16x32_bf16(ah[mt][ks], b5, a_hn[mt], 0, 0, 0);
      }
    }
    int c = crow;
    float bir = bih[c], biz = bih[64 + c], bin = bih[128 + c];
    float bhr = bhh[c], bhz = bhh[64 + c], bhn = bhh[128 + c];
#pragma unroll
    for (int mt = 0; mt < 2; ++mt)
#pragma unroll
      for (int reg = 0; reg < 4; ++reg) {
        int nl = w * 32 + mt * 16 + g * 4 + reg;
        float hv = hprev[(size_t)(n0 + nl) * 64 + c];
        float r  = sigmoidf_(a_ir[mt][reg] + bir + a_hr[mt][reg] + bhr);
        float z  = sigmoidf_(a_iz[mt][reg] + biz + a_hz[mt][reg] + bhz);
        float nn = tanhf(a_in[mt][reg] + bin + r * (a_hn[mt][reg] + bhn));
        float hc = (1.f - z) * nn + z * hv;
        trF[c * 133 + nl] = hc;
      }
  }
  __syncthreads();
#pragma unroll 1
  for (int i = 0; i < 32; ++i) {
    int idx = t + 256 * i;
    int nl = idx & 127, cl = idx >> 7;
    hT[(size_t)cl * NROW + n0 + nl] = trF[cl * 133 + nl];
  }
#pragma unroll 1
  for (int i = 0; i < 32; ++i) {
    int idx = t + 256 * i;
    int c = idx & 63, nl = idx >> 6;
    hout[(size_t)(n0 + nl) * 64 + c] = trF[c * 133 + nl];
  }
}

// K3: q, query(scaled), z1 heads + BN partial sums per block
__global__ __launch_bounds__(256) void k_heads(const float* __restrict__ hT,
    const float* __restrict__ fc2w, const float* __restrict__ fc2b,
    const float* __restrict__ wqw, const float* __restrict__ wqb,
    const float* __restrict__ ew1, const float* __restrict__ eb1,
    float* __restrict__ qT, float* __restrict__ queryT, float* __restrict__ z1T,
    float* __restrict__ part) {
  int t = threadIdx.x;
  int n = blockIdx.x * 64 + (t & 63);
  int cq = t >> 6;
  float hv[HDIM];
#pragma unroll 1
  for (int k = 0; k < HDIM; ++k) hv[k] = hT[(size_t)k * NROW + n];
#pragma unroll 1
  for (int ci = 0; ci < 4; ++ci) {
    int c = cq * 4 + ci;
    float acc = fc2b[c];
#pragma unroll
    for (int k = 0; k < HDIM; ++k) acc = fmaf(hv[k], fc2w[c * HDIM + k], acc);
    qT[(size_t)c * NROW + n] = acc;
  }
  const float qs = 0.17677669529663687f;  // 1/sqrt(32)
#pragma unroll 1
  for (int ai = 0; ai < 8; ++ai) {
    int a = cq * 8 + ai;
    float acc = wqb[a];
#pragma unroll
    for (int k = 0; k < HDIM; ++k) acc = fmaf(hv[k], wqw[a * HDIM + k], acc);
    queryT[(size_t)a * NROW + n] = acc * qs;
  }
  __shared__ float ssum[64], ssq[64];
#pragma unroll 1
  for (int ci = 0; ci < 16; ++ci) {
    int c = cq * 16 + ci;
    float acc = eb1[c];
#pragma unroll
    for (int k = 0; k < HDIM; ++k) acc = fmaf(hv[k], ew1[c * HDIM + k], acc);
    z1T[(size_t)c * NROW + n] = acc;
    float s1 = acc, s2 = acc * acc;
#pragma unroll
    for (int off = 32; off > 0; off >>= 1) {
      s1 += __shfl_down(s1, off, 64);
      s2 += __shfl_down(s2, off, 64);
    }
    if ((t & 63) == 0) { ssum[c] = s1; ssq[c] = s2; }
  }
  __syncthreads();
  if (t < 64) {
    part[(size_t)blockIdx.x * 128 + t] = ssum[t];
    part[(size_t)blockIdx.x * 128 + 64 + t] = ssq[t];
  }
}

// K4: finalize BN stats
__global__ void k_bnstat(const float* __restrict__ part,
    const float* __restrict__ bng, const float* __restrict__ bnb,
    float* __restrict__ stat) {
  int c = threadIdx.x;  // 64 threads
  float s1 = 0.f, s2 = 0.f;
  for (int b = 0; b < 512; ++b) {
    s1 += part[(size_t)b * 128 + c];
    s2 += part[(size_t)b * 128 + 64 + c];
  }
  float mean = s1 * (1.f / NROW);
  float var = s2 * (1.f / NROW) - mean * mean;
  float rstd = rsqrtf(var + 1e-5f);
  float sc = bng[c] * rstd;
  stat[c] = sc;
  stat[64 + c] = bnb[c] - mean * sc;
}

// K5: MFMA bf16 GEMM -> latR row-major [N][512]
__global__ __launch_bounds__(256) void k_emb_gemm(const float* __restrict__ z1T,
    const float* __restrict__ stat,
    const float* __restrict__ ew2, const float* __restrict__ eb2,
    const float* __restrict__ eps,
    float* __restrict__ latR) {
  __shared__ char smem[36864];
  const int t = threadIdx.x;
  const int nb = blockIdx.x >> 3;
  const int cb = blockIdx.x & 7;
  const int n0 = nb * 128;
  const int c0 = cb * 64;

  unsigned* aU = (unsigned*)smem;                 // A: [128][36]
  unsigned* bmU = (unsigned*)(smem + 18432);      // Wmu: [64][36]
  unsigned* blU = (unsigned*)(smem + 27648);      // Wlv: [64][36]

#pragma unroll 1
  for (int i = 0; i < 16; ++i) {
    int idx = t + 256 * i;
    int nl = idx & 127;
    int kp = idx >> 7;
    float v0 = z1T[(size_t)(2 * kp) * NROW + n0 + nl];
    float v1 = z1T[(size_t)(2 * kp + 1) * NROW + n0 + nl];
    v0 = lrelu_(fmaf(stat[2 * kp], v0, stat[64 + 2 * kp]));
    v1 = lrelu_(fmaf(stat[2 * kp + 1], v1, stat[64 + 2 * kp + 1]));
    aU[nl * 36 + kp] = f2bf(v0) | (f2bf(v1) << 16);
  }
  const float2* ew2_2 = (const float2*)ew2;
#pragma unroll 1
  for (int i = 0; i < 8; ++i) {
    int idx = t + 256 * i;
    int kp = idx & 31;
    int cl = idx >> 5;
    float2 m2 = ew2_2[(size_t)(c0 + cl) * 32 + kp];
    float2 l2 = ew2_2[(size_t)(512 + c0 + cl) * 32 + kp];
    bmU[cl * 36 + kp] = f2bf(m2.x) | (f2bf(m2.y) << 16);
    blU[cl * 36 + kp] = f2bf(l2.x) | (f2bf(l2.y) << 16);
  }
  __syncthreads();

  const int w = t >> 6, l = t & 63;
  const int m = l & 15, g = l >> 4;
  const short* sA = (const short*)smem;
  const short* sBm = (const short*)(smem + 18432);
  const short* sBl = (const short*)(smem + 27648);

  f32x4 accm[2][4], accl[2][4];
#pragma unroll
  for (int mt = 0; mt < 2; ++mt)
#pragma unroll
    for (int ct = 0; ct < 4; ++ct) {
      accm[mt][ct] = (f32x4){0.f, 0.f, 0.f, 0.f};
      accl[mt][ct] = (f32x4){0.f, 0.f, 0.f, 0.f};
    }
  bf16x8 af[2][2];
#pragma unroll
  for (int mt = 0; mt < 2; ++mt)
#pragma unroll
    for (int ks = 0; ks < 2; ++ks)
      af[mt][ks] = *(const bf16x8*)(sA + (w * 32 + mt * 16 + m) * 72 + ks * 32 + g * 8);
#pragma unroll
  for (int ct = 0; ct < 4; ++ct) {
#pragma unroll
    for (int ks = 0; ks < 2; ++ks) {
      bf16x8 bm = *(const bf16x8*)(sBm + (ct * 16 + m) * 72 + ks * 32 + g * 8);
      bf16x8 bl = *(const bf16x8*)(sBl + (ct * 16 + m) * 72 + ks * 32 + g * 8);
#pragma unroll
      for (int mt = 0; mt < 2; ++mt) {
        accm[mt][ct] = __builtin_amdgcn_mfma_f32_16x16x32_bf16(af[mt][ks], bm, accm[mt][ct], 0, 0, 0);
        accl[mt][ct] = __builtin_amdgcn_mfma_f32_16x16x32_bf16(af[mt][ks], bl, accl[mt][ct], 0, 0, 0);
      }
    }
  }

  float lat[2][4][4];
#pragma unroll
  for (int mt = 0; mt < 2; ++mt) {
    int nl = w * 32 + mt * 16 + g * 4;
#pragma unroll
    for (int reg = 0; reg < 4; ++reg) {
      const float* ep = eps + (size_t)(n0 + nl + reg) * DH + c0;
#pragma unroll
      for (int ct = 0; ct < 4; ++ct) {
        int cl = ct * 16 + m;
        float mu = accm[mt][ct][reg] + eb2[c0 + cl];
        float lv = accl[mt][ct][reg] + eb2[DH + c0 + cl];
        lat[mt][ct][reg] = fmaf(sqrtf(fmaxf(__expf(lv), 0.002f)), ep[cl], mu);
      }
    }
  }
  __syncthreads();
  float* outF = (float*)smem;     // [64][133]
#pragma unroll
  for (int mt = 0; mt < 2; ++mt)
#pragma unroll
    for (int ct = 0; ct < 4; ++ct)
#pragma unroll
      for (int reg = 0; reg < 4; ++reg)
        outF[(ct * 16 + m) * 133 + w * 32 + mt * 16 + g * 4 + reg] = lat[mt][ct][reg];
  __syncthreads();
  // row-major store: 64 consecutive c per row, coalesced 256B per wave
#pragma unroll 1
  for (int i = 0; i < 32; ++i) {
    int idx = t + 256 * i;
    int cl = idx & 63;
    int nl = idx >> 6;
    latR[(size_t)(n0 + nl) * 512 + c0 + cl] = outF[cl * 133 + nl];
  }
}

// K6 v2: one thread per (row, j). Massive TLP; coalesced latR reads; shfl softmax.
__global__ __launch_bounds__(256) void k_alpha(const float* __restrict__ latR,
    const float* __restrict__ queryT,
    const float* __restrict__ wkw, const float* __restrict__ wkb,
    float* __restrict__ alphaR) {
  int t = threadIdx.x;
  int n = blockIdx.x * 8 + (t >> 5);
  int j = t & 31;
  float qk[16];
#pragma unroll
  for (int l = 0; l < 16; ++l) qk[l] = 0.f;
  float qb = 0.f;
#pragma unroll
  for (int a = 0; a < 32; ++a) {
    float q = queryT[(size_t)a * NROW + n];
    qb = fmaf(q, wkb[a], qb);
#pragma unroll
    for (int l = 0; l < 16; ++l) qk[l] = fmaf(q, wkw[a * 16 + l], qk[l]);
  }
  const float4* lp = (const float4*)(latR + (size_t)n * 512 + j * 16);
  float4 v0 = lp[0], v1 = lp[1], v2 = lp[2], v3 = lp[3];
  float acc = qb;
  acc = fmaf(v0.x, qk[0], acc);  acc = fmaf(v0.y, qk[1], acc);
  acc = fmaf(v0.z, qk[2], acc);  acc = fmaf(v0.w, qk[3], acc);
  acc = fmaf(v1.x, qk[4], acc);  acc = fmaf(v1.y, qk[5], acc);
  acc = fmaf(v1.z, qk[6], acc);  acc = fmaf(v1.w, qk[7], acc);
  acc = fmaf(v2.x, qk[8], acc);  acc = fmaf(v2.y, qk[9], acc);
  acc = fmaf(v2.z, qk[10], acc); acc = fmaf(v2.w, qk[11], acc);
  acc = fmaf(v3.x, qk[12], acc); acc = fmaf(v3.y, qk[13], acc);
  acc = fmaf(v3.z, qk[14], acc); acc = fmaf(v3.w, qk[15], acc);
  if (j == (n & 31)) acc = -1e9f;
  float m = acc;
#pragma unroll
  for (int mask = 16; mask > 0; mask >>= 1) m = fmaxf(m, __shfl_xor(m, mask, 64));
  float e = __expf(acc - m);
  float s = e;
#pragma unroll
  for (int mask = 16; mask > 0; mask >>= 1) s += __shfl_xor(s, mask, 64);
  alphaR[(size_t)n * 32 + j] = e / s;
}

// K7 (MFMA): one block per b. See round-6 notes; staging now reads latR/alphaR.
constexpr int LATB_OFF = 0;        // [1024][20] bf16, 40B rows (r = i*32+j)
constexpr int H3B_OFF  = 40960;    // [32][72] bf16, 144B rows
constexpr int W1H_OFF  = 45568;    // [64][72] bf16
constexpr int W1L_OFF  = 54784;    // [64][20] bf16
constexpr int W2P_OFF  = 57344;    // [16][72] bf16 (pi-permuted c)
constexpr int ALL_OFF  = 59648;    // [32][33] f32
constexpr int MT_OFF   = 63872;    // 4 waves x 2560B private transpose buf
__global__ __launch_bounds__(256, 1) void k_msg(
    const float* __restrict__ latR, const float* __restrict__ alphaR,
    const float* __restrict__ qT, const float* __restrict__ hrow,
    const float* __restrict__ w1, const float* __restrict__ b1,
    const float* __restrict__ w2, const float* __restrict__ b2,
    float* __restrict__ out) {
  __shared__ char smem[74112];
  const int t = threadIdx.x;
  const int b = blockIdx.x;
  const int b32 = b * 32;
  unsigned* latB_dw = (unsigned*)(smem + LATB_OFF);

  // ---- staging ----
  {  // latB from latR: contiguous sweep, 2 rows x 128 float4 per iter
    int ih = t >> 7;            // 0..1
    int j5 = (t >> 2) & 31;     // 0..31
    int lp4 = t & 3;            // 0..3
    const float4* latR4 = (const float4*)latR;
#pragma unroll 1
    for (int i0 = 0; i0 < 32; i0 += 2) {
      int i = i0 + ih;
      float4 v = latR4[((size_t)(b32 + i) * 512 + j5 * 16 + 4 * lp4) >> 2];
      int base = (i * 32 + j5) * 10 + 2 * lp4;
      latB_dw[base]     = f2bf(v.x) | (f2bf(v.y) << 16);
      latB_dw[base + 1] = f2bf(v.z) | (f2bf(v.w) << 16);
    }
  }
  {  // h3B[j][k] bf16 from row-major h (d_out region)
    int cp = t & 31, jj = t >> 5;
    const float2* h2 = (const float2*)hrow;
    unsigned* dst = (unsigned*)(smem + H3B_OFF);
#pragma unroll 1
    for (int it = 0; it < 4; ++it) {
      int j = jj + 8 * it;
      float2 hv = h2[((size_t)(b32 + j) * 64 + 2 * cp) >> 1];
      dst[j * 36 + cp] = f2bf(hv.x) | (f2bf(hv.y) << 16);
    }
  }
  {  // w1hL[c][k] (k<64)
    int kp = t & 31, cc = t >> 5;
    const float2* w12 = (const float2*)w1;
    unsigned* dst = (unsigned*)(smem + W1H_OFF);
#pragma unroll 1
    for (int it = 0; it < 8; ++it) {
      int c = cc + 8 * it;
      float2 wv = w12[(c * 80 + 2 * kp) >> 1];
      dst[c * 36 + kp] = f2bf(wv.x) | (f2bf(wv.y) << 16);
    }
  }
  {  // w1latL[c][l]
    int lp = t & 7, cc = t >> 3;
    const float2* w12 = (const float2*)w1;
    unsigned* dst = (unsigned*)(smem + W1L_OFF);
#pragma unroll 1
    for (int it = 0; it < 2; ++it) {
      int c = cc + 32 * it;
      float2 wv = w12[(c * 80 + 64 + 2 * lp) >> 1];
      dst[c * 10 + lp] = f2bf(wv.x) | (f2bf(wv.y) << 16);
    }
  }
  {  // w2P[nn][p] = w2[nn][c(p)], c(p) = ((p>>2)&3)*16 + (p>>4)*4 + (p&3)
    int pp = t & 31, nn = t >> 5;
    const float2* w22 = (const float2*)w2;
    unsigned* dst = (unsigned*)(smem + W2P_OFF);
#pragma unroll 1
    for (int it = 0; it < 2; ++it) {
      int n2 = nn + 8 * it;
      int p = 2 * pp;
      int c = ((p >> 2) & 3) * 16 + (p >> 4) * 4 + (p & 3);
      float2 wv = w22[(n2 * 64 + c) >> 1];
      dst[n2 * 36 + pp] = f2bf(wv.x) | (f2bf(wv.y) << 16);
    }
  }
  {  // alL[i][j] from alphaR (contiguous)
    int j = t & 31, i8 = t >> 5;
    float* alL = (float*)(smem + ALL_OFF);
#pragma unroll 1
    for (int it = 0; it < 4; ++it) {
      int i = i8 + 8 * it;
      alL[i * 33 + j] = alphaR[(size_t)(b32 + i) * 32 + j];
    }
  }
  __syncthreads();

  const int w = t >> 6, l = t & 63;
  const int n15 = l & 15, q = l >> 4;
  const int jh = w & 1, ibase = (w >> 1) * 16;
  const bool kact = (q < 2);

  // ---- phase 1: hp[ct][reg] for (c = ct*16+q*4+reg, j = jh*16+n15) ----
  f32x4 hp[4];
#pragma unroll
  for (int ct = 0; ct < 4; ++ct) hp[ct] = (f32x4){0.f, 0.f, 0.f, 0.f};
#pragma unroll
  for (int ct = 0; ct < 4; ++ct)
#pragma unroll
    for (int ks = 0; ks < 2; ++ks) {
      bf16x8 aF = *(const bf16x8*)(smem + W1H_OFF + (ct * 16 + n15) * 144 + ks * 64 + q * 16);
      bf16x8 bF = *(const bf16x8*)(smem + H3B_OFF + (jh * 16 + n15) * 144 + ks * 64 + q * 16);
      hp[ct] = __builtin_amdgcn_mfma_f32_16x16x32_bf16(aF, bF, hp[ct], 0, 0, 0);
    }
#pragma unroll
  for (int ct = 0; ct < 4; ++ct)
#pragma unroll
    for (int reg = 0; reg < 4; ++reg)
      hp[ct][reg] += b1[ct * 16 + q * 4 + reg];

  // hoisted fragments
  bf16x8 aL[4];
#pragma unroll
  for (int ct = 0; ct < 4; ++ct) {
    union { unsigned u[4]; bf16x8 h; } tmp;
    tmp.u[0] = tmp.u[1] = tmp.u[2] = tmp.u[3] = 0u;
    if (kact) {
      const unsigned* p = (const unsigned*)(smem + W1L_OFF) + (ct * 16 + n15) * 10 + q * 4;
      uint2e d0 = *(const uint2e*)p;
      uint2e d1 = *(const uint2e*)(p + 2);
      tmp.u[0] = d0.x; tmp.u[1] = d0.y; tmp.u[2] = d1.x; tmp.u[3] = d1.y;
    }
    aL[ct] = tmp.h;
  }
  bf16x8 w2F[2];
#pragma unroll
  for (int ks = 0; ks < 2; ++ks)
    w2F[ks] = *(const bf16x8*)(smem + W2P_OFF + n15 * 144 + ks * 64 + q * 16);
  float b2v[4];
#pragma unroll
  for (int reg = 0; reg < 4; ++reg) b2v[reg] = b2[q * 4 + reg];

  // ---- main i loop ----
  float agg[4] = {0.f, 0.f, 0.f, 0.f};
  char* wb = smem + MT_OFF + w * 2560;
  const float* alLf = (const float*)(smem + ALL_OFF);
#pragma unroll 1
  for (int it = 0; it < 16; ++it) {
    int ii = ibase + it;
    int r = ii * 32 + jh * 16 + n15;
    union { unsigned u[4]; bf16x8 h; } latF;
    latF.u[0] = latF.u[1] = latF.u[2] = latF.u[3] = 0u;
    if (kact) {
      const unsigned* p = latB_dw + r * 10 + q * 4;
      uint2e d0 = *(const uint2e*)p;
      uint2e d1 = *(const uint2e*)(p + 2);
      latF.u[0] = d0.x; latF.u[1] = d0.y; latF.u[2] = d1.x; latF.u[3] = d1.y;
    }
    f32x4 acc[4];
#pragma unroll
    for (int ct = 0; ct < 4; ++ct) {
      acc[ct] = (f32x4){0.f, 0.f, 0.f, 0.f};
      acc[ct] = __builtin_amdgcn_mfma_f32_16x16x32_bf16(aL[ct], latF.h, acc[ct], 0, 0, 0);
    }
    // lrelu + pack + pi-transpose write (per-wave private buffer, no barrier)
#pragma unroll
    for (int h = 0; h < 2; ++h) {
      float m0[4], m1[4];
#pragma unroll
      for (int reg = 0; reg < 4; ++reg) {
        float v0 = acc[2 * h][reg] + hp[2 * h][reg];
        float v1 = acc[2 * h + 1][reg] + hp[2 * h + 1][reg];
        m0[reg] = fmaxf(v0, 0.01f * v0);
        m1[reg] = fmaxf(v1, 0.01f * v1);
      }
      uint4e pk4;
      pk4.x = pkbf(m0[0], m0[1]); pk4.y = pkbf(m0[2], m0[3]);
      pk4.z = pkbf(m1[0], m1[1]); pk4.w = pkbf(m1[2], m1[3]);
      int qp = (2 * q + h) & 3;
      *(uint4e*)(wb + (q >> 1) * 1280 + n15 * 80 + qp * 16) = pk4;
    }
    // phase 3
    f32x4 msg = (f32x4){0.f, 0.f, 0.f, 0.f};
#pragma unroll
    for (int ks = 0; ks < 2; ++ks) {
      bf16x8 mF = *(const bf16x8*)(wb + ks * 1280 + n15 * 80 + q * 16);
      msg = __builtin_amdgcn_mfma_f32_16x16x32_bf16(w2F[ks], mF, msg, 0, 0, 0);
    }
    float aw = alLf[ii * 33 + jh * 16 + n15];
#pragma unroll
    for (int reg = 0; reg < 4; ++reg)
      agg[reg] = fmaf(aw, msg[reg] + b2v[reg], agg[reg]);
  }
  // park agg in own wave buffer
  {
    f32x4 av; av[0] = agg[0]; av[1] = agg[1]; av[2] = agg[2]; av[3] = agg[3];
    *(f32x4*)(wb + n15 * 80 + q * 16) = av;
  }
  __syncthreads();
  // combine wave pairs (i-low + i-high) and add q head
#pragma unroll
  for (int tt = 0; tt < 2; ++tt) {
    int idx = t + 256 * tt;
    int jg = idx >> 4, nn = idx & 15;
    int jh2 = jg >> 4, jl = jg & 15;
    float a0 = *(const float*)(smem + MT_OFF + jh2 * 2560 + jl * 80 + nn * 4);
    float a1 = *(const float*)(smem + MT_OFF + (jh2 + 2) * 2560 + jl * 80 + nn * 4);
    out[(size_t)b * 512 + idx] = a0 + a1 + qT[(size_t)nn * NROW + b32 + jg];
  }
}

}  // namespace

extern "C" void kernel_launch(void* const* d_in, const int* in_sizes, int n_in,
                              void* d_out, int out_size, void* d_ws, size_t ws_size,
                              hipStream_t stream) {
  (void)in_sizes; (void)n_in; (void)out_size; (void)ws_size;
  const float* inputs = (const float*)d_in[0];
  const float* hidden = (const float*)d_in[1];
  const float* eps    = (const float*)d_in[2];
  const float* fc1w   = (const float*)d_in[3];
  const float* fc1b   = (const float*)d_in[4];
  const float* wih    = (const float*)d_in[5];
  const float* whh    = (const float*)d_in[6];
  const float* bih    = (const float*)d_in[7];
  const float* bhh    = (const float*)d_in[8];
  const float* fc2w   = (const float*)d_in[9];
  const float* fc2b   = (const float*)d_in[10];
  const float* ew1    = (const float*)d_in[11];
  const float* eb1    = (const float*)d_in[12];
  const float* bng    = (const float*)d_in[13];
  const float* bnb    = (const float*)d_in[14];
  const float* ew2    = (const float*)d_in[15];
  const float* eb2    = (const float*)d_in[16];
  const float* w1     = (const float*)d_in[17];
  const float* b1     = (const float*)d_in[18];
  const float* w2     = (const float*)d_in[19];
  const float* b2     = (const float*)d_in[20];
  const float* wqw    = (const float*)d_in[21];
  const float* wqb    = (const float*)d_in[22];
  const float* wkw    = (const float*)d_in[23];
  const float* wkb    = (const float*)d_in[24];

  float* ws = (float*)d_ws;
  float* hT     = ws;                 // 2097152
  float* qT     = ws + 2097152;       // 524288
  float* queryT = ws + 2621440;       // 1048576
  float* z1T    = ws + 3670016;       // 2097152
  float* part   = ws + 5767168;       // 65536
  float* stat   = ws + 5832704;       // 128
  float* latR   = ws + 5832832;       // 16777216  (row-major [N][512])
  float* alphaR = ws + 22610048;      // 1048576   (row-major [N][32])

  float* out_q = (float*)d_out;             // 32768 x 16
  float* out_h = (float*)d_out + 524288;    // 32768 x 64

  hipLaunchKernelGGL(k_fgru, dim3(256), dim3(256), 0, stream,
                     inputs, hidden, fc1w, fc1b, wih, whh, bih, bhh, hT, out_h);
  hipLaunchKernelGGL(k_heads, dim3(512), dim3(256), 0, stream, hT, fc2w, fc2b, wqw, wqb, ew1, eb1, qT, queryT, z1T, part);
  hipLaunchKernelGGL(k_bnstat, dim3(1), dim3(64), 0, stream, part, bng, bnb, stat);
  hipLaunchKernelGGL(k_emb_gemm, dim3(2048), dim3(256), 0, stream, z1T, stat, ew2, eb2, eps, latR);
  hipLaunchKernelGGL(k_alpha, dim3(4096), dim3(256), 0, stream, latR, queryT, wkw, wkb, alphaR);
  hipLaunchKernelGGL(k_msg, dim3(1024), dim3(256), 0, stream,
                     latR, alphaR, qT, out_h, w1, b1, w2, b2, out_q);
}

// Round 8
// 297.304 us; speedup vs baseline: 5.6785x; 1.1663x over previous
//
#include <hip/hip_runtime.h>
#include <math.h>

namespace {

constexpr int NROW = 32768;   // BS*A rows
constexpr int HDIM = 64;
constexpr int DH   = 512;     // latent half-dim

typedef __attribute__((ext_vector_type(8))) short bf16x8;
typedef __attribute__((ext_vector_type(4))) float f32x4;
typedef __attribute__((ext_vector_type(4))) unsigned uint4e;
typedef __attribute__((ext_vector_type(2))) unsigned uint2e;

__device__ __forceinline__ float sigmoidf_(float x) { return 1.f / (1.f + __expf(-x)); }
__device__ __forceinline__ float lrelu_(float x) { return x > 0.f ? x : 0.01f * x; }
__device__ __forceinline__ unsigned f2bf(float x) {  // RNE float->bf16 (as low 16 bits)
  unsigned u = __float_as_uint(x);
  return (u + 0x7fffu + ((u >> 16) & 1u)) >> 16;
}
// fast pack: round-half-up bf16 pair (a -> low16, b -> high16), 3 VALU
__device__ __forceinline__ unsigned pkbf(float a, float b) {
  unsigned ua = __float_as_uint(a) + 0x8000u;
  unsigned ub = __float_as_uint(b) + 0x8000u;
  return __builtin_amdgcn_perm(ub, ua, 0x07060302);
}

// K1+K2 fused: x = relu(inputs @ fc1_w^T + b); GRU via 6 MFMA gate GEMMs.
__global__ __launch_bounds__(256, 1) void k_fgru(
    const float* __restrict__ in,      // [N][96]
    const float* __restrict__ hprev,   // [N][64]
    const float* __restrict__ fc1w, const float* __restrict__ fc1b,
    const float* __restrict__ wih, const float* __restrict__ whh,
    const float* __restrict__ bih, const float* __restrict__ bhh,
    float* __restrict__ hT, float* __restrict__ hout) {
  __shared__ char smem[132096];
  const int t = threadIdx.x;
  const int n0 = blockIdx.x * 128;
  unsigned* inU  = (unsigned*)smem;                    // [128][52]
  unsigned* f1U  = (unsigned*)(smem + 26624);          // [64][52]
  unsigned* xU   = (unsigned*)(smem + 39936);          // [128][36]
  unsigned* hU   = (unsigned*)(smem + 58368);          // [128][36]
  unsigned* gU   = (unsigned*)(smem + 76800);          // [6][64][36]
  float*    trF  = (float*)smem;                       // [64][133] overlaps inU/f1U

  const float2* in2 = (const float2*)in;
#pragma unroll 1
  for (int i = 0; i < 24; ++i) {
    int idx = t + 256 * i;
    int nl = idx / 48, kp = idx - nl * 48;
    float2 v = in2[(size_t)(n0 + nl) * 48 + kp];
    inU[nl * 52 + kp] = f2bf(v.x) | (f2bf(v.y) << 16);
  }
  const float2* f1w2 = (const float2*)fc1w;
#pragma unroll 1
  for (int i = 0; i < 12; ++i) {
    int idx = t + 256 * i;
    int cl = idx / 48, kp = idx - cl * 48;
    float2 v = f1w2[cl * 48 + kp];
    f1U[cl * 52 + kp] = f2bf(v.x) | (f2bf(v.y) << 16);
  }
  const float2* h2 = (const float2*)hprev;
#pragma unroll 1
  for (int i = 0; i < 16; ++i) {
    int idx = t + 256 * i;
    int nl = idx >> 5, kp = idx & 31;
    float2 v = h2[(size_t)(n0 + nl) * 32 + kp];
    hU[nl * 36 + kp] = f2bf(v.x) | (f2bf(v.y) << 16);
  }
  const float2* wih2 = (const float2*)wih;
  const float2* whh2 = (const float2*)whh;
#pragma unroll 1
  for (int i = 0; i < 24; ++i) {
    int idx = t + 256 * i;
    int row = idx >> 5, kp = idx & 31;
    float2 v = wih2[row * 32 + kp];
    int gate = row >> 6, cl = row & 63;
    gU[(gate * 64 + cl) * 36 + kp] = f2bf(v.x) | (f2bf(v.y) << 16);
  }
#pragma unroll 1
  for (int i = 0; i < 24; ++i) {
    int idx = t + 256 * i;
    int row = idx >> 5, kp = idx & 31;
    float2 v = whh2[row * 32 + kp];
    int gate = row >> 6, cl = row & 63;
    gU[((gate + 3) * 64 + cl) * 36 + kp] = f2bf(v.x) | (f2bf(v.y) << 16);
  }
  __syncthreads();

  const int w = t >> 6, l = t & 63;
  const int m = l & 15, g = l >> 4;
  const short* inS = (const short*)inU;
  const short* f1S = (const short*)f1U;
  short*       xS  = (short*)xU;
  const short* hS  = (const short*)hU;
  const short* gS  = (const short*)gU;

  // ---- fc1 phase ----
  {
    f32x4 accx[2][4];
#pragma unroll
    for (int mt = 0; mt < 2; ++mt)
#pragma unroll
      for (int ct = 0; ct < 4; ++ct) accx[mt][ct] = (f32x4){0.f, 0.f, 0.f, 0.f};
    bf16x8 af[2][3];
#pragma unroll
    for (int mt = 0; mt < 2; ++mt)
#pragma unroll
      for (int ks = 0; ks < 3; ++ks)
        af[mt][ks] = *(const bf16x8*)(inS + (w * 32 + mt * 16 + m) * 104 + ks * 32 + g * 8);
#pragma unroll
    for (int ct = 0; ct < 4; ++ct)
#pragma unroll
      for (int ks = 0; ks < 3; ++ks) {
        bf16x8 bw = *(const bf16x8*)(f1S + (ct * 16 + m) * 104 + ks * 32 + g * 8);
#pragma unroll
        for (int mt = 0; mt < 2; ++mt)
          accx[mt][ct] = __builtin_amdgcn_mfma_f32_16x16x32_bf16(af[mt][ks], bw, accx[mt][ct], 0, 0, 0);
      }
#pragma unroll
    for (int mt = 0; mt < 2; ++mt)
#pragma unroll
      for (int ct = 0; ct < 4; ++ct) {
        int c = ct * 16 + m;
        float bc = fc1b[c];
#pragma unroll
        for (int reg = 0; reg < 4; ++reg) {
          int nl = w * 32 + mt * 16 + g * 4 + reg;
          float v = fmaxf(accx[mt][ct][reg] + bc, 0.f);
          xS[nl * 72 + c] = (short)f2bf(v);
        }
      }
  }
  __syncthreads();

  // ---- GRU phase ----
  bf16x8 ax[2][2], ah[2][2];
#pragma unroll
  for (int mt = 0; mt < 2; ++mt)
#pragma unroll
    for (int ks = 0; ks < 2; ++ks) {
      ax[mt][ks] = *(const bf16x8*)((const short*)xU + (w * 32 + mt * 16 + m) * 72 + ks * 32 + g * 8);
      ah[mt][ks] = *(const bf16x8*)(hS + (w * 32 + mt * 16 + m) * 72 + ks * 32 + g * 8);
    }
#pragma unroll 1
  for (int ct = 0; ct < 4; ++ct) {
    f32x4 a_ir[2], a_iz[2], a_in[2], a_hr[2], a_hz[2], a_hn[2];
#pragma unroll
    for (int mt = 0; mt < 2; ++mt) {
      a_ir[mt] = (f32x4){0.f, 0.f, 0.f, 0.f}; a_iz[mt] = (f32x4){0.f, 0.f, 0.f, 0.f};
      a_in[mt] = (f32x4){0.f, 0.f, 0.f, 0.f}; a_hr[mt] = (f32x4){0.f, 0.f, 0.f, 0.f};
      a_hz[mt] = (f32x4){0.f, 0.f, 0.f, 0.f}; a_hn[mt] = (f32x4){0.f, 0.f, 0.f, 0.f};
    }
    int crow = ct * 16 + m;
#pragma unroll
    for (int ks = 0; ks < 2; ++ks) {
      bf16x8 b0 = *(const bf16x8*)(gS + (0 * 64 + crow) * 72 + ks * 32 + g * 8);
      bf16x8 b1 = *(const bf16x8*)(gS + (1 * 64 + crow) * 72 + ks * 32 + g * 8);
      bf16x8 b2 = *(const bf16x8*)(gS + (2 * 64 + crow) * 72 + ks * 32 + g * 8);
      bf16x8 b3 = *(const bf16x8*)(gS + (3 * 64 + crow) * 72 + ks * 32 + g * 8);
      bf16x8 b4 = *(const bf16x8*)(gS + (4 * 64 + crow) * 72 + ks * 32 + g * 8);
      bf16x8 b5 = *(const bf16x8*)(gS + (5 * 64 + crow) * 72 + ks * 32 + g * 8);
#pragma unroll
      for (int mt = 0; mt < 2; ++mt) {
        a_ir[mt] = __builtin_amdgcn_mfma_f32_16x16x32_bf16(ax[mt][ks], b0, a_ir[mt], 0, 0, 0);
        a_iz[mt] = __builtin_amdgcn_mfma_f32_16x16x32_bf16(ax[mt][ks], b1, a_iz[mt], 0, 0, 0);
        a_in[mt] = __builtin_amdgcn_mfma_f32_16x16x32_bf16(ax[mt][ks], b2, a_in[mt], 0, 0, 0);
        a_hr[mt] = __builtin_amdgcn_mfma_f32_16x16x32_bf16(ah[mt][ks], b3, a_hr[mt], 0, 0, 0);
        a_hz[mt] = __builtin_amdgcn_mfma_f32_16x16x32_bf16(ah[mt][ks], b4, a_hz[mt], 0, 0, 0);
        a_hn[mt] = __builtin_amdgcn_mfma_f32_16x16x32_bf16(ah[mt][ks], b5, a_hn[mt], 0, 0, 0);
      }
    }
    int c = crow;
    float bir = bih[c], biz = bih[64 + c], bin = bih[128 + c];
    float bhr = bhh[c], bhz = bhh[64 + c], bhn = bhh[128 + c];
#pragma unroll
    for (int mt = 0; mt < 2; ++mt)
#pragma unroll
      for (int reg = 0; reg < 4; ++reg) {
        int nl = w * 32 + mt * 16 + g * 4 + reg;
        float hv = hprev[(size_t)(n0 + nl) * 64 + c];
        float r  = sigmoidf_(a_ir[mt][reg] + bir + a_hr[mt][reg] + bhr);
        float z  = sigmoidf_(a_iz[mt][reg] + biz + a_hz[mt][reg] + bhz);
        float nn = tanhf(a_in[mt][reg] + bin + r * (a_hn[mt][reg] + bhn));
        float hc = (1.f - z) * nn + z * hv;
        trF[c * 133 + nl] = hc;
      }
  }
  __syncthreads();
#pragma unroll 1
  for (int i = 0; i < 32; ++i) {
    int idx = t + 256 * i;
    int nl = idx & 127, cl = idx >> 7;
    hT[(size_t)cl * NROW + n0 + nl] = trF[cl * 133 + nl];
  }
#pragma unroll 1
  for (int i = 0; i < 32; ++i) {
    int idx = t + 256 * i;
    int c = idx & 63, nl = idx >> 6;
    hout[(size_t)(n0 + nl) * 64 + c] = trF[c * 133 + nl];
  }
}

// K3 (MFMA): 112-channel fused head GEMM (fc2 16 + wq 32 + ew1 64), K=64.
// 256 blocks x 128 rows. BN partials in-register + shfl + LDS combine.
__global__ __launch_bounds__(256) void k_heads(const float* __restrict__ hT,
    const float* __restrict__ fc2w, const float* __restrict__ fc2b,
    const float* __restrict__ wqw, const float* __restrict__ wqb,
    const float* __restrict__ ew1, const float* __restrict__ eb1,
    float* __restrict__ qT, float* __restrict__ queryT, float* __restrict__ z1T,
    float* __restrict__ part) {
  __shared__ char smem[36864];
  const int t = threadIdx.x;
  const int n0 = blockIdx.x * 128;
  unsigned* hU = (unsigned*)smem;                 // [128][36]
  unsigned* wU = (unsigned*)(smem + 18432);       // [112][36]
  float* sp1 = (float*)(smem + 18432 + 16128);    // [4][64]
  float* sp2 = sp1 + 256;                         // [4][64]

#pragma unroll 1
  for (int i = 0; i < 16; ++i) {
    int idx = t + 256 * i;
    int nl = idx & 127, kp = idx >> 7;
    float v0 = hT[(size_t)(2 * kp) * NROW + n0 + nl];
    float v1 = hT[(size_t)(2 * kp + 1) * NROW + n0 + nl];
    hU[nl * 36 + kp] = f2bf(v0) | (f2bf(v1) << 16);
  }
#pragma unroll 1
  for (int i = 0; i < 14; ++i) {
    int idx = t + 256 * i;          // 0..3583
    int kp = idx & 31, cl = idx >> 5;   // cl 0..111
    const float* src = (cl < 16) ? (fc2w + cl * 64)
                     : (cl < 48) ? (wqw + (cl - 16) * 64)
                                 : (ew1 + (cl - 48) * 64);
    float2 v = *(const float2*)(src + 2 * kp);
    wU[cl * 36 + kp] = f2bf(v.x) | (f2bf(v.y) << 16);
  }
  __syncthreads();

  const int w = t >> 6, l = t & 63;
  const int m = l & 15, g = l >> 4;
  const short* sH = (const short*)hU;
  const short* sW = (const short*)wU;

  bf16x8 af[2][2];
#pragma unroll
  for (int mt = 0; mt < 2; ++mt)
#pragma unroll
    for (int ks = 0; ks < 2; ++ks)
      af[mt][ks] = *(const bf16x8*)(sH + (w * 32 + mt * 16 + m) * 72 + ks * 32 + g * 8);

  f32x4 acc[2][7];
#pragma unroll
  for (int mt = 0; mt < 2; ++mt)
#pragma unroll
    for (int ct = 0; ct < 7; ++ct) acc[mt][ct] = (f32x4){0.f, 0.f, 0.f, 0.f};
#pragma unroll
  for (int ct = 0; ct < 7; ++ct)
#pragma unroll
    for (int ks = 0; ks < 2; ++ks) {
      bf16x8 bw = *(const bf16x8*)(sW + (ct * 16 + m) * 72 + ks * 32 + g * 8);
#pragma unroll
      for (int mt = 0; mt < 2; ++mt)
        acc[mt][ct] = __builtin_amdgcn_mfma_f32_16x16x32_bf16(af[mt][ks], bw, acc[mt][ct], 0, 0, 0);
    }

  const float qs = 0.17677669529663687f;  // 1/sqrt(32)
  float s1[4], s2[4];
#pragma unroll
  for (int zt = 0; zt < 4; ++zt) { s1[zt] = 0.f; s2[zt] = 0.f; }
#pragma unroll
  for (int mt = 0; mt < 2; ++mt) {
    int nb = n0 + w * 32 + mt * 16 + g * 4;
    {  // q head: c = m
      float bc = fc2b[m];
      f32x4 v;
#pragma unroll
      for (int reg = 0; reg < 4; ++reg) v[reg] = acc[mt][0][reg] + bc;
      *(f32x4*)(qT + (size_t)m * NROW + nb) = v;
    }
#pragma unroll
    for (int ct = 1; ct < 3; ++ct) {  // query head: a = (ct-1)*16 + m
      int a = (ct - 1) * 16 + m;
      float bc = wqb[a];
      f32x4 v;
#pragma unroll
      for (int reg = 0; reg < 4; ++reg) v[reg] = (acc[mt][ct][reg] + bc) * qs;
      *(f32x4*)(queryT + (size_t)a * NROW + nb) = v;
    }
#pragma unroll
    for (int ct = 3; ct < 7; ++ct) {  // z1 head: z = (ct-3)*16 + m
      int z = (ct - 3) * 16 + m;
      float bc = eb1[z];
      f32x4 v;
#pragma unroll
      for (int reg = 0; reg < 4; ++reg) {
        float zv = acc[mt][ct][reg] + bc;
        v[reg] = zv;
        s1[ct - 3] += zv;
        s2[ct - 3] = fmaf(zv, zv, s2[ct - 3]);
      }
      *(f32x4*)(z1T + (size_t)z * NROW + nb) = v;
    }
  }
  // reduce across g (lanes m, m+16, m+32, m+48)
#pragma unroll
  for (int zt = 0; zt < 4; ++zt) {
    s1[zt] += __shfl_down(s1[zt], 16, 64);
    s1[zt] += __shfl_down(s1[zt], 32, 64);
    s2[zt] += __shfl_down(s2[zt], 16, 64);
    s2[zt] += __shfl_down(s2[zt], 32, 64);
  }
  if (l < 16) {
#pragma unroll
    for (int zt = 0; zt < 4; ++zt) {
      sp1[w * 64 + zt * 16 + m] = s1[zt];
      sp2[w * 64 + zt * 16 + m] = s2[zt];
    }
  }
  __syncthreads();
  if (t < 64) {
    float a1 = sp1[t] + sp1[64 + t] + sp1[128 + t] + sp1[192 + t];
    float a2 = sp2[t] + sp2[64 + t] + sp2[128 + t] + sp2[192 + t];
    part[(size_t)blockIdx.x * 128 + t] = a1;
    part[(size_t)blockIdx.x * 128 + 64 + t] = a2;
  }
}

// K4: finalize BN stats (256 head blocks)
__global__ void k_bnstat(const float* __restrict__ part,
    const float* __restrict__ bng, const float* __restrict__ bnb,
    float* __restrict__ stat) {
  int c = threadIdx.x;  // 64 threads
  float s1 = 0.f, s2 = 0.f;
  for (int b = 0; b < 256; ++b) {
    s1 += part[(size_t)b * 128 + c];
    s2 += part[(size_t)b * 128 + 64 + c];
  }
  float mean = s1 * (1.f / NROW);
  float var = s2 * (1.f / NROW) - mean * mean;
  float rstd = rsqrtf(var + 1e-5f);
  float sc = bng[c] * rstd;
  stat[c] = sc;
  stat[64 + c] = bnb[c] - mean * sc;
}

// K5: MFMA bf16 GEMM -> latR row-major [N][512]
__global__ __launch_bounds__(256) void k_emb_gemm(const float* __restrict__ z1T,
    const float* __restrict__ stat,
    const float* __restrict__ ew2, const float* __restrict__ eb2,
    const float* __restrict__ eps,
    float* __restrict__ latR) {
  __shared__ char smem[36864];
  const int t = threadIdx.x;
  const int nb = blockIdx.x >> 3;
  const int cb = blockIdx.x & 7;
  const int n0 = nb * 128;
  const int c0 = cb * 64;

  unsigned* aU = (unsigned*)smem;                 // A: [128][36]
  unsigned* bmU = (unsigned*)(smem + 18432);      // Wmu: [64][36]
  unsigned* blU = (unsigned*)(smem + 27648);      // Wlv: [64][36]

#pragma unroll 1
  for (int i = 0; i < 16; ++i) {
    int idx = t + 256 * i;
    int nl = idx & 127;
    int kp = idx >> 7;
    float v0 = z1T[(size_t)(2 * kp) * NROW + n0 + nl];
    float v1 = z1T[(size_t)(2 * kp + 1) * NROW + n0 + nl];
    v0 = lrelu_(fmaf(stat[2 * kp], v0, stat[64 + 2 * kp]));
    v1 = lrelu_(fmaf(stat[2 * kp + 1], v1, stat[64 + 2 * kp + 1]));
    aU[nl * 36 + kp] = f2bf(v0) | (f2bf(v1) << 16);
  }
  const float2* ew2_2 = (const float2*)ew2;
#pragma unroll 1
  for (int i = 0; i < 8; ++i) {
    int idx = t + 256 * i;
    int kp = idx & 31;
    int cl = idx >> 5;
    float2 m2 = ew2_2[(size_t)(c0 + cl) * 32 + kp];
    float2 l2 = ew2_2[(size_t)(512 + c0 + cl) * 32 + kp];
    bmU[cl * 36 + kp] = f2bf(m2.x) | (f2bf(m2.y) << 16);
    blU[cl * 36 + kp] = f2bf(l2.x) | (f2bf(l2.y) << 16);
  }
  __syncthreads();

  const int w = t >> 6, l = t & 63;
  const int m = l & 15, g = l >> 4;
  const short* sA = (const short*)smem;
  const short* sBm = (const short*)(smem + 18432);
  const short* sBl = (const short*)(smem + 27648);

  f32x4 accm[2][4], accl[2][4];
#pragma unroll
  for (int mt = 0; mt < 2; ++mt)
#pragma unroll
    for (int ct = 0; ct < 4; ++ct) {
      accm[mt][ct] = (f32x4){0.f, 0.f, 0.f, 0.f};
      accl[mt][ct] = (f32x4){0.f, 0.f, 0.f, 0.f};
    }
  bf16x8 af[2][2];
#pragma unroll
  for (int mt = 0; mt < 2; ++mt)
#pragma unroll
    for (int ks = 0; ks < 2; ++ks)
      af[mt][ks] = *(const bf16x8*)(sA + (w * 32 + mt * 16 + m) * 72 + ks * 32 + g * 8);
#pragma unroll
  for (int ct = 0; ct < 4; ++ct) {
#pragma unroll
    for (int ks = 0; ks < 2; ++ks) {
      bf16x8 bm = *(const bf16x8*)(sBm + (ct * 16 + m) * 72 + ks * 32 + g * 8);
      bf16x8 bl = *(const bf16x8*)(sBl + (ct * 16 + m) * 72 + ks * 32 + g * 8);
#pragma unroll
      for (int mt = 0; mt < 2; ++mt) {
        accm[mt][ct] = __builtin_amdgcn_mfma_f32_16x16x32_bf16(af[mt][ks], bm, accm[mt][ct], 0, 0, 0);
        accl[mt][ct] = __builtin_amdgcn_mfma_f32_16x16x32_bf16(af[mt][ks], bl, accl[mt][ct], 0, 0, 0);
      }
    }
  }

  float lat[2][4][4];
#pragma unroll
  for (int mt = 0; mt < 2; ++mt) {
    int nl = w * 32 + mt * 16 + g * 4;
#pragma unroll
    for (int reg = 0; reg < 4; ++reg) {
      const float* ep = eps + (size_t)(n0 + nl + reg) * DH + c0;
#pragma unroll
      for (int ct = 0; ct < 4; ++ct) {
        int cl = ct * 16 + m;
        float mu = accm[mt][ct][reg] + eb2[c0 + cl];
        float lv = accl[mt][ct][reg] + eb2[DH + c0 + cl];
        lat[mt][ct][reg] = fmaf(sqrtf(fmaxf(__expf(lv), 0.002f)), ep[cl], mu);
      }
    }
  }
  __syncthreads();
  float* outF = (float*)smem;     // [64][133]
#pragma unroll
  for (int mt = 0; mt < 2; ++mt)
#pragma unroll
    for (int ct = 0; ct < 4; ++ct)
#pragma unroll
      for (int reg = 0; reg < 4; ++reg)
        outF[(ct * 16 + m) * 133 + w * 32 + mt * 16 + g * 4 + reg] = lat[mt][ct][reg];
  __syncthreads();
  // row-major store: 64 consecutive c per row, coalesced 256B per wave
#pragma unroll 1
  for (int i = 0; i < 32; ++i) {
    int idx = t + 256 * i;
    int cl = idx & 63;
    int nl = idx >> 6;
    latR[(size_t)(n0 + nl) * 512 + c0 + cl] = outF[cl * 133 + nl];
  }
}

// K6 v2: one thread per (row, j). Massive TLP; coalesced latR reads; shfl softmax.
__global__ __launch_bounds__(256) void k_alpha(const float* __restrict__ latR,
    const float* __restrict__ queryT,
    const float* __restrict__ wkw, const float* __restrict__ wkb,
    float* __restrict__ alphaR) {
  int t = threadIdx.x;
  int n = blockIdx.x * 8 + (t >> 5);
  int j = t & 31;
  float qk[16];
#pragma unroll
  for (int l = 0; l < 16; ++l) qk[l] = 0.f;
  float qb = 0.f;
#pragma unroll
  for (int a = 0; a < 32; ++a) {
    float q = queryT[(size_t)a * NROW + n];
    qb = fmaf(q, wkb[a], qb);
#pragma unroll
    for (int l = 0; l < 16; ++l) qk[l] = fmaf(q, wkw[a * 16 + l], qk[l]);
  }
  const float4* lp = (const float4*)(latR + (size_t)n * 512 + j * 16);
  float4 v0 = lp[0], v1 = lp[1], v2 = lp[2], v3 = lp[3];
  float acc = qb;
  acc = fmaf(v0.x, qk[0], acc);  acc = fmaf(v0.y, qk[1], acc);
  acc = fmaf(v0.z, qk[2], acc);  acc = fmaf(v0.w, qk[3], acc);
  acc = fmaf(v1.x, qk[4], acc);  acc = fmaf(v1.y, qk[5], acc);
  acc = fmaf(v1.z, qk[6], acc);  acc = fmaf(v1.w, qk[7], acc);
  acc = fmaf(v2.x, qk[8], acc);  acc = fmaf(v2.y, qk[9], acc);
  acc = fmaf(v2.z, qk[10], acc); acc = fmaf(v2.w, qk[11], acc);
  acc = fmaf(v3.x, qk[12], acc); acc = fmaf(v3.y, qk[13], acc);
  acc = fmaf(v3.z, qk[14], acc); acc = fmaf(v3.w, qk[15], acc);
  if (j == (n & 31)) acc = -1e9f;
  float m = acc;
#pragma unroll
  for (int mask = 16; mask > 0; mask >>= 1) m = fmaxf(m, __shfl_xor(m, mask, 64));
  float e = __expf(acc - m);
  float s = e;
#pragma unroll
  for (int mask = 16; mask > 0; mask >>= 1) s += __shfl_xor(s, mask, 64);
  alphaR[(size_t)n * 32 + j] = e / s;
}

// K7 (MFMA): one block per b. See round-6 notes; staging reads latR/alphaR.
constexpr int LATB_OFF = 0;        // [1024][20] bf16, 40B rows (r = i*32+j)
constexpr int H3B_OFF  = 40960;    // [32][72] bf16, 144B rows
constexpr int W1H_OFF  = 45568;    // [64][72] bf16
constexpr int W1L_OFF  = 54784;    // [64][20] bf16
constexpr int W2P_OFF  = 57344;    // [16][72] bf16 (pi-permuted c)
constexpr int ALL_OFF  = 59648;    // [32][33] f32
constexpr int MT_OFF   = 63872;    // 4 waves x 2560B private transpose buf
__global__ __launch_bounds__(256, 1) void k_msg(
    const float* __restrict__ latR, const float* __restrict__ alphaR,
    const float* __restrict__ qT, const float* __restrict__ hrow,
    const float* __restrict__ w1, const float* __restrict__ b1,
    const float* __restrict__ w2, const float* __restrict__ b2,
    float* __restrict__ out) {
  __shared__ char smem[74112];
  const int t = threadIdx.x;
  const int b = blockIdx.x;
  const int b32 = b * 32;
  unsigned* latB_dw = (unsigned*)(smem + LATB_OFF);

  // ---- staging ----
  {  // latB from latR: contiguous sweep
    int ih = t >> 7;            // 0..1
    int j5 = (t >> 2) & 31;     // 0..31
    int lp4 = t & 3;            // 0..3
    const float4* latR4 = (const float4*)latR;
#pragma unroll 1
    for (int i0 = 0; i0 < 32; i0 += 2) {
      int i = i0 + ih;
      float4 v = latR4[((size_t)(b32 + i) * 512 + j5 * 16 + 4 * lp4) >> 2];
      int base = (i * 32 + j5) * 10 + 2 * lp4;
      latB_dw[base]     = f2bf(v.x) | (f2bf(v.y) << 16);
      latB_dw[base + 1] = f2bf(v.z) | (f2bf(v.w) << 16);
    }
  }
  {  // h3B[j][k] bf16 from row-major h (d_out region)
    int cp = t & 31, jj = t >> 5;
    const float2* h2 = (const float2*)hrow;
    unsigned* dst = (unsigned*)(smem + H3B_OFF);
#pragma unroll 1
    for (int it = 0; it < 4; ++it) {
      int j = jj + 8 * it;
      float2 hv = h2[((size_t)(b32 + j) * 64 + 2 * cp) >> 1];
      dst[j * 36 + cp] = f2bf(hv.x) | (f2bf(hv.y) << 16);
    }
  }
  {  // w1hL[c][k] (k<64)
    int kp = t & 31, cc = t >> 5;
    const float2* w12 = (const float2*)w1;
    unsigned* dst = (unsigned*)(smem + W1H_OFF);
#pragma unroll 1
    for (int it = 0; it < 8; ++it) {
      int c = cc + 8 * it;
      float2 wv = w12[(c * 80 + 2 * kp) >> 1];
      dst[c * 36 + kp] = f2bf(wv.x) | (f2bf(wv.y) << 16);
    }
  }
  {  // w1latL[c][l]
    int lp = t & 7, cc = t >> 3;
    const float2* w12 = (const float2*)w1;
    unsigned* dst = (unsigned*)(smem + W1L_OFF);
#pragma unroll 1
    for (int it = 0; it < 2; ++it) {
      int c = cc + 32 * it;
      float2 wv = w12[(c * 80 + 64 + 2 * lp) >> 1];
      dst[c * 10 + lp] = f2bf(wv.x) | (f2bf(wv.y) << 16);
    }
  }
  {  // w2P[nn][p] = w2[nn][c(p)], c(p) = ((p>>2)&3)*16 + (p>>4)*4 + (p&3)
    int pp = t & 31, nn = t >> 5;
    const float2* w22 = (const float2*)w2;
    unsigned* dst = (unsigned*)(smem + W2P_OFF);
#pragma unroll 1
    for (int it = 0; it < 2; ++it) {
      int n2 = nn + 8 * it;
      int p = 2 * pp;
      int c = ((p >> 2) & 3) * 16 + (p >> 4) * 4 + (p & 3);
      float2 wv = w22[(n2 * 64 + c) >> 1];
      dst[n2 * 36 + pp] = f2bf(wv.x) | (f2bf(wv.y) << 16);
    }
  }
  {  // alL[i][j] from alphaR (contiguous)
    int j = t & 31, i8 = t >> 5;
    float* alL = (float*)(smem + ALL_OFF);
#pragma unroll 1
    for (int it = 0; it < 4; ++it) {
      int i = i8 + 8 * it;
      alL[i * 33 + j] = alphaR[(size_t)(b32 + i) * 32 + j];
    }
  }
  __syncthreads();

  const int w = t >> 6, l = t & 63;
  const int n15 = l & 15, q = l >> 4;
  const int jh = w & 1, ibase = (w >> 1) * 16;
  const bool kact = (q < 2);

  // ---- phase 1: hp[ct][reg] for (c = ct*16+q*4+reg, j = jh*16+n15) ----
  f32x4 hp[4];
#pragma unroll
  for (int ct = 0; ct < 4; ++ct) hp[ct] = (f32x4){0.f, 0.f, 0.f, 0.f};
#pragma unroll
  for (int ct = 0; ct < 4; ++ct)
#pragma unroll
    for (int ks = 0; ks < 2; ++ks) {
      bf16x8 aF = *(const bf16x8*)(smem + W1H_OFF + (ct * 16 + n15) * 144 + ks * 64 + q * 16);
      bf16x8 bF = *(const bf16x8*)(smem + H3B_OFF + (jh * 16 + n15) * 144 + ks * 64 + q * 16);
      hp[ct] = __builtin_amdgcn_mfma_f32_16x16x32_bf16(aF, bF, hp[ct], 0, 0, 0);
    }
#pragma unroll
  for (int ct = 0; ct < 4; ++ct)
#pragma unroll
    for (int reg = 0; reg < 4; ++reg)
      hp[ct][reg] += b1[ct * 16 + q * 4 + reg];

  // hoisted fragments
  bf16x8 aL[4];
#pragma unroll
  for (int ct = 0; ct < 4; ++ct) {
    union { unsigned u[4]; bf16x8 h; } tmp;
    tmp.u[0] = tmp.u[1] = tmp.u[2] = tmp.u[3] = 0u;
    if (kact) {
      const unsigned* p = (const unsigned*)(smem + W1L_OFF) + (ct * 16 + n15) * 10 + q * 4;
      uint2e d0 = *(const uint2e*)p;
      uint2e d1 = *(const uint2e*)(p + 2);
      tmp.u[0] = d0.x; tmp.u[1] = d0.y; tmp.u[2] = d1.x; tmp.u[3] = d1.y;
    }
    aL[ct] = tmp.h;
  }
  bf16x8 w2F[2];
#pragma unroll
  for (int ks = 0; ks < 2; ++ks)
    w2F[ks] = *(const bf16x8*)(smem + W2P_OFF + n15 * 144 + ks * 64 + q * 16);
  float b2v[4];
#pragma unroll
  for (int reg = 0; reg < 4; ++reg) b2v[reg] = b2[q * 4 + reg];

  // ---- main i loop ----
  float agg[4] = {0.f, 0.f, 0.f, 0.f};
  char* wb = smem + MT_OFF + w * 2560;
  const float* alLf = (const float*)(smem + ALL_OFF);
#pragma unroll 1
  for (int it = 0; it < 16; ++it) {
    int ii = ibase + it;
    int r = ii * 32 + jh * 16 + n15;
    union { unsigned u[4]; bf16x8 h; } latF;
    latF.u[0] = latF.u[1] = latF.u[2] = latF.u[3] = 0u;
    if (kact) {
      const unsigned* p = latB_dw + r * 10 + q * 4;
      uint2e d0 = *(const uint2e*)p;
      uint2e d1 = *(const uint2e*)(p + 2);
      latF.u[0] = d0.x; latF.u[1] = d0.y; latF.u[2] = d1.x; latF.u[3] = d1.y;
    }
    f32x4 acc[4];
#pragma unroll
    for (int ct = 0; ct < 4; ++ct) {
      acc[ct] = (f32x4){0.f, 0.f, 0.f, 0.f};
      acc[ct] = __builtin_amdgcn_mfma_f32_16x16x32_bf16(aL[ct], latF.h, acc[ct], 0, 0, 0);
    }
    // lrelu + pack + pi-transpose write (per-wave private buffer, no barrier)
#pragma unroll
    for (int h = 0; h < 2; ++h) {
      float m0[4], m1[4];
#pragma unroll
      for (int reg = 0; reg < 4; ++reg) {
        float v0 = acc[2 * h][reg] + hp[2 * h][reg];
        float v1 = acc[2 * h + 1][reg] + hp[2 * h + 1][reg];
        m0[reg] = fmaxf(v0, 0.01f * v0);
        m1[reg] = fmaxf(v1, 0.01f * v1);
      }
      uint4e pk4;
      pk4.x = pkbf(m0[0], m0[1]); pk4.y = pkbf(m0[2], m0[3]);
      pk4.z = pkbf(m1[0], m1[1]); pk4.w = pkbf(m1[2], m1[3]);
      int qp = (2 * q + h) & 3;
      *(uint4e*)(wb + (q >> 1) * 1280 + n15 * 80 + qp * 16) = pk4;
    }
    // phase 3
    f32x4 msg = (f32x4){0.f, 0.f, 0.f, 0.f};
#pragma unroll
    for (int ks = 0; ks < 2; ++ks) {
      bf16x8 mF = *(const bf16x8*)(wb + ks * 1280 + n15 * 80 + q * 16);
      msg = __builtin_amdgcn_mfma_f32_16x16x32_bf16(w2F[ks], mF, msg, 0, 0, 0);
    }
    float aw = alLf[ii * 33 + jh * 16 + n15];
#pragma unroll
    for (int reg = 0; reg < 4; ++reg)
      agg[reg] = fmaf(aw, msg[reg] + b2v[reg], agg[reg]);
  }
  // park agg in own wave buffer
  {
    f32x4 av; av[0] = agg[0]; av[1] = agg[1]; av[2] = agg[2]; av[3] = agg[3];
    *(f32x4*)(wb + n15 * 80 + q * 16) = av;
  }
  __syncthreads();
  // combine wave pairs (i-low + i-high) and add q head
#pragma unroll
  for (int tt = 0; tt < 2; ++tt) {
    int idx = t + 256 * tt;
    int jg = idx >> 4, nn = idx & 15;
    int jh2 = jg >> 4, jl = jg & 15;
    float a0 = *(const float*)(smem + MT_OFF + jh2 * 2560 + jl * 80 + nn * 4);
    float a1 = *(const float*)(smem + MT_OFF + (jh2 + 2) * 2560 + jl * 80 + nn * 4);
    out[(size_t)b * 512 + idx] = a0 + a1 + qT[(size_t)nn * NROW + b32 + jg];
  }
}

}  // namespace

extern "C" void kernel_launch(void* const* d_in, const int* in_sizes, int n_in,
                              void* d_out, int out_size, void* d_ws, size_t ws_size,
                              hipStream_t stream) {
  (void)in_sizes; (void)n_in; (void)out_size; (void)ws_size;
  const float* inputs = (const float*)d_in[0];
  const float* hidden = (const float*)d_in[1];
  const float* eps    = (const float*)d_in[2];
  const float* fc1w   = (const float*)d_in[3];
  const float* fc1b   = (const float*)d_in[4];
  const float* wih    = (const float*)d_in[5];
  const float* whh    = (const float*)d_in[6];
  const float* bih    = (const float*)d_in[7];
  const float* bhh    = (const float*)d_in[8];
  const float* fc2w   = (const float*)d_in[9];
  const float* fc2b   = (const float*)d_in[10];
  const float* ew1    = (const float*)d_in[11];
  const float* eb1    = (const float*)d_in[12];
  const float* bng    = (const float*)d_in[13];
  const float* bnb    = (const float*)d_in[14];
  const float* ew2    = (const float*)d_in[15];
  const float* eb2    = (const float*)d_in[16];
  const float* w1     = (const float*)d_in[17];
  const float* b1     = (const float*)d_in[18];
  const float* w2     = (const float*)d_in[19];
  const float* b2     = (const float*)d_in[20];
  const float* wqw    = (const float*)d_in[21];
  const float* wqb    = (const float*)d_in[22];
  const float* wkw    = (const float*)d_in[23];
  const float* wkb    = (const float*)d_in[24];

  float* ws = (float*)d_ws;
  float* hT     = ws;                 // 2097152
  float* qT     = ws + 2097152;       // 524288
  float* queryT = ws + 2621440;       // 1048576
  float* z1T    = ws + 3670016;       // 2097152
  float* part   = ws + 5767168;       // 65536
  float* stat   = ws + 5832704;       // 128
  float* latR   = ws + 5832832;       // 16777216  (row-major [N][512])
  float* alphaR = ws + 22610048;      // 1048576   (row-major [N][32])

  float* out_q = (float*)d_out;             // 32768 x 16
  float* out_h = (float*)d_out + 524288;    // 32768 x 64

  hipLaunchKernelGGL(k_fgru, dim3(256), dim3(256), 0, stream,
                     inputs, hidden, fc1w, fc1b, wih, whh, bih, bhh, hT, out_h);
  hipLaunchKernelGGL(k_heads, dim3(256), dim3(256), 0, stream, hT, fc2w, fc2b, wqw, wqb, ew1, eb1, qT, queryT, z1T, part);
  hipLaunchKernelGGL(k_bnstat, dim3(1), dim3(64), 0, stream, part, bng, bnb, stat);
  hipLaunchKernelGGL(k_emb_gemm, dim3(2048), dim3(256), 0, stream, z1T, stat, ew2, eb2, eps, latR);
  hipLaunchKernelGGL(k_alpha, dim3(4096), dim3(256), 0, stream, latR, queryT, wkw, wkb, alphaR);
  hipLaunchKernelGGL(k_msg, dim3(1024), dim3(256), 0, stream,
                     latR, alphaR, qT, out_h, w1, b1, w2, b2, out_q);
}

// Round 9
// 273.460 us; speedup vs baseline: 6.1736x; 1.0872x over previous
//
#include <hip/hip_runtime.h>
#include <math.h>

namespace {

constexpr int NROW = 32768;   // BS*A rows
constexpr int HDIM = 64;
constexpr int DH   = 512;     // latent half-dim

typedef __attribute__((ext_vector_type(8))) short bf16x8;
typedef __attribute__((ext_vector_type(4))) float f32x4;
typedef __attribute__((ext_vector_type(4))) unsigned uint4e;
typedef __attribute__((ext_vector_type(2))) unsigned uint2e;

__device__ __forceinline__ float sigmoidf_(float x) { return 1.f / (1.f + __expf(-x)); }
__device__ __forceinline__ float lrelu_(float x) { return x > 0.f ? x : 0.01f * x; }
__device__ __forceinline__ unsigned f2bf(float x) {  // RNE float->bf16 (as low 16 bits)
  unsigned u = __float_as_uint(x);
  return (u + 0x7fffu + ((u >> 16) & 1u)) >> 16;
}
// fast pack: round-half-up bf16 pair (a -> low16, b -> high16), 3 VALU
__device__ __forceinline__ unsigned pkbf(float a, float b) {
  unsigned ua = __float_as_uint(a) + 0x8000u;
  unsigned ub = __float_as_uint(b) + 0x8000u;
  return __builtin_amdgcn_perm(ub, ua, 0x07060302);
}

// K1+K2 fused: x = relu(inputs @ fc1_w^T + b); GRU via 6 MFMA gate GEMMs.
__global__ __launch_bounds__(256, 1) void k_fgru(
    const float* __restrict__ in,      // [N][96]
    const float* __restrict__ hprev,   // [N][64]
    const float* __restrict__ fc1w, const float* __restrict__ fc1b,
    const float* __restrict__ wih, const float* __restrict__ whh,
    const float* __restrict__ bih, const float* __restrict__ bhh,
    float* __restrict__ hT, float* __restrict__ hout) {
  __shared__ char smem[132096];
  const int t = threadIdx.x;
  const int n0 = blockIdx.x * 128;
  unsigned* inU  = (unsigned*)smem;                    // [128][52]
  unsigned* f1U  = (unsigned*)(smem + 26624);          // [64][52]
  unsigned* xU   = (unsigned*)(smem + 39936);          // [128][36]
  unsigned* hU   = (unsigned*)(smem + 58368);          // [128][36]
  unsigned* gU   = (unsigned*)(smem + 76800);          // [6][64][36]
  float*    trF  = (float*)smem;                       // [64][133] overlaps inU/f1U

  const float2* in2 = (const float2*)in;
#pragma unroll 1
  for (int i = 0; i < 24; ++i) {
    int idx = t + 256 * i;
    int nl = idx / 48, kp = idx - nl * 48;
    float2 v = in2[(size_t)(n0 + nl) * 48 + kp];
    inU[nl * 52 + kp] = f2bf(v.x) | (f2bf(v.y) << 16);
  }
  const float2* f1w2 = (const float2*)fc1w;
#pragma unroll 1
  for (int i = 0; i < 12; ++i) {
    int idx = t + 256 * i;
    int cl = idx / 48, kp = idx - cl * 48;
    float2 v = f1w2[cl * 48 + kp];
    f1U[cl * 52 + kp] = f2bf(v.x) | (f2bf(v.y) << 16);
  }
  const float2* h2 = (const float2*)hprev;
#pragma unroll 1
  for (int i = 0; i < 16; ++i) {
    int idx = t + 256 * i;
    int nl = idx >> 5, kp = idx & 31;
    float2 v = h2[(size_t)(n0 + nl) * 32 + kp];
    hU[nl * 36 + kp] = f2bf(v.x) | (f2bf(v.y) << 16);
  }
  const float2* wih2 = (const float2*)wih;
  const float2* whh2 = (const float2*)whh;
#pragma unroll 1
  for (int i = 0; i < 24; ++i) {
    int idx = t + 256 * i;
    int row = idx >> 5, kp = idx & 31;
    float2 v = wih2[row * 32 + kp];
    int gate = row >> 6, cl = row & 63;
    gU[(gate * 64 + cl) * 36 + kp] = f2bf(v.x) | (f2bf(v.y) << 16);
  }
#pragma unroll 1
  for (int i = 0; i < 24; ++i) {
    int idx = t + 256 * i;
    int row = idx >> 5, kp = idx & 31;
    float2 v = whh2[row * 32 + kp];
    int gate = row >> 6, cl = row & 63;
    gU[((gate + 3) * 64 + cl) * 36 + kp] = f2bf(v.x) | (f2bf(v.y) << 16);
  }
  __syncthreads();

  const int w = t >> 6, l = t & 63;
  const int m = l & 15, g = l >> 4;
  const short* inS = (const short*)inU;
  const short* f1S = (const short*)f1U;
  short*       xS  = (short*)xU;
  const short* hS  = (const short*)hU;
  const short* gS  = (const short*)gU;

  // ---- fc1 phase ----
  {
    f32x4 accx[2][4];
#pragma unroll
    for (int mt = 0; mt < 2; ++mt)
#pragma unroll
      for (int ct = 0; ct < 4; ++ct) accx[mt][ct] = (f32x4){0.f, 0.f, 0.f, 0.f};
    bf16x8 af[2][3];
#pragma unroll
    for (int mt = 0; mt < 2; ++mt)
#pragma unroll
      for (int ks = 0; ks < 3; ++ks)
        af[mt][ks] = *(const bf16x8*)(inS + (w * 32 + mt * 16 + m) * 104 + ks * 32 + g * 8);
#pragma unroll
    for (int ct = 0; ct < 4; ++ct)
#pragma unroll
      for (int ks = 0; ks < 3; ++ks) {
        bf16x8 bw = *(const bf16x8*)(f1S + (ct * 16 + m) * 104 + ks * 32 + g * 8);
#pragma unroll
        for (int mt = 0; mt < 2; ++mt)
          accx[mt][ct] = __builtin_amdgcn_mfma_f32_16x16x32_bf16(af[mt][ks], bw, accx[mt][ct], 0, 0, 0);
      }
#pragma unroll
    for (int mt = 0; mt < 2; ++mt)
#pragma unroll
      for (int ct = 0; ct < 4; ++ct) {
        int c = ct * 16 + m;
        float bc = fc1b[c];
#pragma unroll
        for (int reg = 0; reg < 4; ++reg) {
          int nl = w * 32 + mt * 16 + g * 4 + reg;
          float v = fmaxf(accx[mt][ct][reg] + bc, 0.f);
          xS[nl * 72 + c] = (short)f2bf(v);
        }
      }
  }
  __syncthreads();

  // ---- GRU phase ----
  bf16x8 ax[2][2], ah[2][2];
#pragma unroll
  for (int mt = 0; mt < 2; ++mt)
#pragma unroll
    for (int ks = 0; ks < 2; ++ks) {
      ax[mt][ks] = *(const bf16x8*)((const short*)xU + (w * 32 + mt * 16 + m) * 72 + ks * 32 + g * 8);
      ah[mt][ks] = *(const bf16x8*)(hS + (w * 32 + mt * 16 + m) * 72 + ks * 32 + g * 8);
    }
#pragma unroll 1
  for (int ct = 0; ct < 4; ++ct) {
    f32x4 a_ir[2], a_iz[2], a_in[2], a_hr[2], a_hz[2], a_hn[2];
#pragma unroll
    for (int mt = 0; mt < 2; ++mt) {
      a_ir[mt] = (f32x4){0.f, 0.f, 0.f, 0.f}; a_iz[mt] = (f32x4){0.f, 0.f, 0.f, 0.f};
      a_in[mt] = (f32x4){0.f, 0.f, 0.f, 0.f}; a_hr[mt] = (f32x4){0.f, 0.f, 0.f, 0.f};
      a_hz[mt] = (f32x4){0.f, 0.f, 0.f, 0.f}; a_hn[mt] = (f32x4){0.f, 0.f, 0.f, 0.f};
    }
    int crow = ct * 16 + m;
#pragma unroll
    for (int ks = 0; ks < 2; ++ks) {
      bf16x8 b0 = *(const bf16x8*)(gS + (0 * 64 + crow) * 72 + ks * 32 + g * 8);
      bf16x8 b1 = *(const bf16x8*)(gS + (1 * 64 + crow) * 72 + ks * 32 + g * 8);
      bf16x8 b2 = *(const bf16x8*)(gS + (2 * 64 + crow) * 72 + ks * 32 + g * 8);
      bf16x8 b3 = *(const bf16x8*)(gS + (3 * 64 + crow) * 72 + ks * 32 + g * 8);
      bf16x8 b4 = *(const bf16x8*)(gS + (4 * 64 + crow) * 72 + ks * 32 + g * 8);
      bf16x8 b5 = *(const bf16x8*)(gS + (5 * 64 + crow) * 72 + ks * 32 + g * 8);
#pragma unroll
      for (int mt = 0; mt < 2; ++mt) {
        a_ir[mt] = __builtin_amdgcn_mfma_f32_16x16x32_bf16(ax[mt][ks], b0, a_ir[mt], 0, 0, 0);
        a_iz[mt] = __builtin_amdgcn_mfma_f32_16x16x32_bf16(ax[mt][ks], b1, a_iz[mt], 0, 0, 0);
        a_in[mt] = __builtin_amdgcn_mfma_f32_16x16x32_bf16(ax[mt][ks], b2, a_in[mt], 0, 0, 0);
        a_hr[mt] = __builtin_amdgcn_mfma_f32_16x16x32_bf16(ah[mt][ks], b3, a_hr[mt], 0, 0, 0);
        a_hz[mt] = __builtin_amdgcn_mfma_f32_16x16x32_bf16(ah[mt][ks], b4, a_hz[mt], 0, 0, 0);
        a_hn[mt] = __builtin_amdgcn_mfma_f32_16x16x32_bf16(ah[mt][ks], b5, a_hn[mt], 0, 0, 0);
      }
    }
    int c = crow;
    float bir = bih[c], biz = bih[64 + c], bin = bih[128 + c];
    float bhr = bhh[c], bhz = bhh[64 + c], bhn = bhh[128 + c];
#pragma unroll
    for (int mt = 0; mt < 2; ++mt)
#pragma unroll
      for (int reg = 0; reg < 4; ++reg) {
        int nl = w * 32 + mt * 16 + g * 4 + reg;
        float hv = hprev[(size_t)(n0 + nl) * 64 + c];
        float r  = sigmoidf_(a_ir[mt][reg] + bir + a_hr[mt][reg] + bhr);
        float z  = sigmoidf_(a_iz[mt][reg] + biz + a_hz[mt][reg] + bhz);
        float nn = tanhf(a_in[mt][reg] + bin + r * (a_hn[mt][reg] + bhn));
        float hc = (1.f - z) * nn + z * hv;
        trF[c * 133 + nl] = hc;
      }
  }
  __syncthreads();
#pragma unroll 1
  for (int i = 0; i < 32; ++i) {
    int idx = t + 256 * i;
    int nl = idx & 127, cl = idx >> 7;
    hT[(size_t)cl * NROW + n0 + nl] = trF[cl * 133 + nl];
  }
#pragma unroll 1
  for (int i = 0; i < 32; ++i) {
    int idx = t + 256 * i;
    int c = idx & 63, nl = idx >> 6;
    hout[(size_t)(n0 + nl) * 64 + c] = trF[c * 133 + nl];
  }
}

// K3 (MFMA): 96-channel fused head GEMM (fc2 16 + qk 16 + ew1 64), K=64.
// qk head = h @ (qs * Wk^T Wq)^T computed inline during staging; the constant
// part of the attention logit cancels in softmax, so no bias needed.
__global__ __launch_bounds__(256) void k_heads(const float* __restrict__ hT,
    const float* __restrict__ fc2w, const float* __restrict__ fc2b,
    const float* __restrict__ wqw, const float* __restrict__ wkw,
    const float* __restrict__ ew1, const float* __restrict__ eb1,
    float* __restrict__ qT, float* __restrict__ qkT, float* __restrict__ z1T,
    float* __restrict__ part) {
  __shared__ char smem[36864];
  const int t = threadIdx.x;
  const int n0 = blockIdx.x * 128;
  unsigned* hU = (unsigned*)smem;                 // [128][36]
  unsigned* wU = (unsigned*)(smem + 18432);       // [96][36]
  float* sp1 = (float*)(smem + 18432 + 13824);    // [4][64]
  float* sp2 = sp1 + 256;                         // [4][64]
  const float qs = 0.17677669529663687f;          // 1/sqrt(32)

#pragma unroll 1
  for (int i = 0; i < 16; ++i) {
    int idx = t + 256 * i;
    int nl = idx & 127, kp = idx >> 7;
    float v0 = hT[(size_t)(2 * kp) * NROW + n0 + nl];
    float v1 = hT[(size_t)(2 * kp + 1) * NROW + n0 + nl];
    hU[nl * 36 + kp] = f2bf(v0) | (f2bf(v1) << 16);
  }
#pragma unroll 1
  for (int i = 0; i < 12; ++i) {
    int idx = t + 256 * i;          // 0..3071
    int kp = idx & 31, cl = idx >> 5;   // cl 0..95
    unsigned val;
    if (cl < 16) {
      float2 v = *(const float2*)(fc2w + cl * 64 + 2 * kp);
      val = f2bf(v.x) | (f2bf(v.y) << 16);
    } else if (cl < 32) {
      int ll = cl - 16;
      float s0 = 0.f, s1 = 0.f;
#pragma unroll 1
      for (int a = 0; a < 32; ++a) {
        float wk = wkw[a * 16 + ll];
        s0 = fmaf(wk, wqw[a * 64 + 2 * kp], s0);
        s1 = fmaf(wk, wqw[a * 64 + 2 * kp + 1], s1);
      }
      val = f2bf(s0 * qs) | (f2bf(s1 * qs) << 16);
    } else {
      float2 v = *(const float2*)(ew1 + (cl - 32) * 64 + 2 * kp);
      val = f2bf(v.x) | (f2bf(v.y) << 16);
    }
    wU[cl * 36 + kp] = val;
  }
  __syncthreads();

  const int w = t >> 6, l = t & 63;
  const int m = l & 15, g = l >> 4;
  const short* sH = (const short*)hU;
  const short* sW = (const short*)wU;

  bf16x8 af[2][2];
#pragma unroll
  for (int mt = 0; mt < 2; ++mt)
#pragma unroll
    for (int ks = 0; ks < 2; ++ks)
      af[mt][ks] = *(const bf16x8*)(sH + (w * 32 + mt * 16 + m) * 72 + ks * 32 + g * 8);

  f32x4 acc[2][6];
#pragma unroll
  for (int mt = 0; mt < 2; ++mt)
#pragma unroll
    for (int ct = 0; ct < 6; ++ct) acc[mt][ct] = (f32x4){0.f, 0.f, 0.f, 0.f};
#pragma unroll
  for (int ct = 0; ct < 6; ++ct)
#pragma unroll
    for (int ks = 0; ks < 2; ++ks) {
      bf16x8 bw = *(const bf16x8*)(sW + (ct * 16 + m) * 72 + ks * 32 + g * 8);
#pragma unroll
      for (int mt = 0; mt < 2; ++mt)
        acc[mt][ct] = __builtin_amdgcn_mfma_f32_16x16x32_bf16(af[mt][ks], bw, acc[mt][ct], 0, 0, 0);
    }

  float s1[4], s2[4];
#pragma unroll
  for (int zt = 0; zt < 4; ++zt) { s1[zt] = 0.f; s2[zt] = 0.f; }
#pragma unroll
  for (int mt = 0; mt < 2; ++mt) {
    int nb = n0 + w * 32 + mt * 16 + g * 4;
    {  // q head: c = m
      float bc = fc2b[m];
      f32x4 v;
#pragma unroll
      for (int reg = 0; reg < 4; ++reg) v[reg] = acc[mt][0][reg] + bc;
      *(f32x4*)(qT + (size_t)m * NROW + nb) = v;
    }
    // qk head: l' = m, no bias
    *(f32x4*)(qkT + (size_t)m * NROW + nb) = acc[mt][1];
#pragma unroll
    for (int ct = 2; ct < 6; ++ct) {  // z1 head: z = (ct-2)*16 + m
      int z = (ct - 2) * 16 + m;
      float bc = eb1[z];
      f32x4 v;
#pragma unroll
      for (int reg = 0; reg < 4; ++reg) {
        float zv = acc[mt][ct][reg] + bc;
        v[reg] = zv;
        s1[ct - 2] += zv;
        s2[ct - 2] = fmaf(zv, zv, s2[ct - 2]);
      }
      *(f32x4*)(z1T + (size_t)z * NROW + nb) = v;
    }
  }
#pragma unroll
  for (int zt = 0; zt < 4; ++zt) {
    s1[zt] += __shfl_down(s1[zt], 16, 64);
    s1[zt] += __shfl_down(s1[zt], 32, 64);
    s2[zt] += __shfl_down(s2[zt], 16, 64);
    s2[zt] += __shfl_down(s2[zt], 32, 64);
  }
  if (l < 16) {
#pragma unroll
    for (int zt = 0; zt < 4; ++zt) {
      sp1[w * 64 + zt * 16 + m] = s1[zt];
      sp2[w * 64 + zt * 16 + m] = s2[zt];
    }
  }
  __syncthreads();
  if (t < 64) {
    float a1 = sp1[t] + sp1[64 + t] + sp1[128 + t] + sp1[192 + t];
    float a2 = sp2[t] + sp2[64 + t] + sp2[128 + t] + sp2[192 + t];
    part[(size_t)blockIdx.x * 128 + t] = a1;
    part[(size_t)blockIdx.x * 128 + 64 + t] = a2;
  }
}

// K4: finalize BN stats (256 head blocks)
__global__ void k_bnstat(const float* __restrict__ part,
    const float* __restrict__ bng, const float* __restrict__ bnb,
    float* __restrict__ stat) {
  int c = threadIdx.x;  // 64 threads
  float s1 = 0.f, s2 = 0.f;
  for (int b = 0; b < 256; ++b) {
    s1 += part[(size_t)b * 128 + c];
    s2 += part[(size_t)b * 128 + 64 + c];
  }
  float mean = s1 * (1.f / NROW);
  float var = s2 * (1.f / NROW) - mean * mean;
  float rstd = rsqrtf(var + 1e-5f);
  float sc = bng[c] * rstd;
  stat[c] = sc;
  stat[64 + c] = bnb[c] - mean * sc;
}

// K5: MFMA bf16 GEMM -> latB16g bf16 row-major [N][512] (u32-packed pairs)
__global__ __launch_bounds__(256) void k_emb_gemm(const float* __restrict__ z1T,
    const float* __restrict__ stat,
    const float* __restrict__ ew2, const float* __restrict__ eb2,
    const float* __restrict__ eps,
    unsigned* __restrict__ latB16g) {
  __shared__ char smem[36864];
  const int t = threadIdx.x;
  const int nb = blockIdx.x >> 3;
  const int cb = blockIdx.x & 7;
  const int n0 = nb * 128;
  const int c0 = cb * 64;

  unsigned* aU = (unsigned*)smem;                 // A: [128][36]
  unsigned* bmU = (unsigned*)(smem + 18432);      // Wmu: [64][36]
  unsigned* blU = (unsigned*)(smem + 27648);      // Wlv: [64][36]

#pragma unroll 1
  for (int i = 0; i < 16; ++i) {
    int idx = t + 256 * i;
    int nl = idx & 127;
    int kp = idx >> 7;
    float v0 = z1T[(size_t)(2 * kp) * NROW + n0 + nl];
    float v1 = z1T[(size_t)(2 * kp + 1) * NROW + n0 + nl];
    v0 = lrelu_(fmaf(stat[2 * kp], v0, stat[64 + 2 * kp]));
    v1 = lrelu_(fmaf(stat[2 * kp + 1], v1, stat[64 + 2 * kp + 1]));
    aU[nl * 36 + kp] = f2bf(v0) | (f2bf(v1) << 16);
  }
  const float2* ew2_2 = (const float2*)ew2;
#pragma unroll 1
  for (int i = 0; i < 8; ++i) {
    int idx = t + 256 * i;
    int kp = idx & 31;
    int cl = idx >> 5;
    float2 m2 = ew2_2[(size_t)(c0 + cl) * 32 + kp];
    float2 l2 = ew2_2[(size_t)(512 + c0 + cl) * 32 + kp];
    bmU[cl * 36 + kp] = f2bf(m2.x) | (f2bf(m2.y) << 16);
    blU[cl * 36 + kp] = f2bf(l2.x) | (f2bf(l2.y) << 16);
  }
  __syncthreads();

  const int w = t >> 6, l = t & 63;
  const int m = l & 15, g = l >> 4;
  const short* sA = (const short*)smem;
  const short* sBm = (const short*)(smem + 18432);
  const short* sBl = (const short*)(smem + 27648);

  f32x4 accm[2][4], accl[2][4];
#pragma unroll
  for (int mt = 0; mt < 2; ++mt)
#pragma unroll
    for (int ct = 0; ct < 4; ++ct) {
      accm[mt][ct] = (f32x4){0.f, 0.f, 0.f, 0.f};
      accl[mt][ct] = (f32x4){0.f, 0.f, 0.f, 0.f};
    }
  bf16x8 af[2][2];
#pragma unroll
  for (int mt = 0; mt < 2; ++mt)
#pragma unroll
    for (int ks = 0; ks < 2; ++ks)
      af[mt][ks] = *(const bf16x8*)(sA + (w * 32 + mt * 16 + m) * 72 + ks * 32 + g * 8);
#pragma unroll
  for (int ct = 0; ct < 4; ++ct) {
#pragma unroll
    for (int ks = 0; ks < 2; ++ks) {
      bf16x8 bm = *(const bf16x8*)(sBm + (ct * 16 + m) * 72 + ks * 32 + g * 8);
      bf16x8 bl = *(const bf16x8*)(sBl + (ct * 16 + m) * 72 + ks * 32 + g * 8);
#pragma unroll
      for (int mt = 0; mt < 2; ++mt) {
        accm[mt][ct] = __builtin_amdgcn_mfma_f32_16x16x32_bf16(af[mt][ks], bm, accm[mt][ct], 0, 0, 0);
        accl[mt][ct] = __builtin_amdgcn_mfma_f32_16x16x32_bf16(af[mt][ks], bl, accl[mt][ct], 0, 0, 0);
      }
    }
  }

  float lat[2][4][4];
#pragma unroll
  for (int mt = 0; mt < 2; ++mt) {
    int nl = w * 32 + mt * 16 + g * 4;
#pragma unroll
    for (int reg = 0; reg < 4; ++reg) {
      const float* ep = eps + (size_t)(n0 + nl + reg) * DH + c0;
#pragma unroll
      for (int ct = 0; ct < 4; ++ct) {
        int cl = ct * 16 + m;
        float mu = accm[mt][ct][reg] + eb2[c0 + cl];
        float lv = accl[mt][ct][reg] + eb2[DH + c0 + cl];
        lat[mt][ct][reg] = fmaf(sqrtf(fmaxf(__expf(lv), 0.002f)), ep[cl], mu);
      }
    }
  }
  __syncthreads();
  float* outF = (float*)smem;     // [64][133]
#pragma unroll
  for (int mt = 0; mt < 2; ++mt)
#pragma unroll
    for (int ct = 0; ct < 4; ++ct)
#pragma unroll
      for (int reg = 0; reg < 4; ++reg)
        outF[(ct * 16 + m) * 133 + w * 32 + mt * 16 + g * 4 + reg] = lat[mt][ct][reg];
  __syncthreads();
  // bf16-packed row-major store: 32 u32 per row segment, coalesced
#pragma unroll 1
  for (int i = 0; i < 16; ++i) {
    int idx = t + 256 * i;          // 0..4095
    int cp = idx & 31;
    int nl = idx >> 5;
    float v0 = outF[(2 * cp) * 133 + nl];
    float v1 = outF[(2 * cp + 1) * 133 + nl];
    latB16g[(size_t)(n0 + nl) * 256 + cb * 32 + cp] = f2bf(v0) | (f2bf(v1) << 16);
  }
}

// K7 (MFMA): one block per b. Logit+softmax computed in-kernel from bf16 latent
// (alpha kernel eliminated; logit const term cancels in softmax).
constexpr int LATB_OFF = 0;        // [1024][20] bf16, 40B rows (r = i*32+j)
constexpr int H3B_OFF  = 40960;    // [32][72] bf16, 144B rows
constexpr int W1H_OFF  = 45568;    // [64][72] bf16
constexpr int W1L_OFF  = 54784;    // [64][20] bf16
constexpr int W2P_OFF  = 57344;    // [16][72] bf16 (pi-permuted c)
constexpr int ALL_OFF  = 59648;    // [32][33] f32 alpha
constexpr int MT_OFF   = 63872;    // 4 waves x 2560B private transpose buf
constexpr int QKL_OFF  = 74112;    // [32][20] f32 qk
__global__ __launch_bounds__(256, 1) void k_msg(
    const unsigned* __restrict__ latB16g, const float* __restrict__ qkT,
    const float* __restrict__ qT, const float* __restrict__ hrow,
    const float* __restrict__ w1, const float* __restrict__ b1,
    const float* __restrict__ w2, const float* __restrict__ b2,
    float* __restrict__ out) {
  __shared__ char smem[76672];
  const int t = threadIdx.x;
  const int b = blockIdx.x;
  const int b32 = b * 32;
  unsigned* latB_dw = (unsigned*)(smem + LATB_OFF);

  // ---- staging ----
  {  // latB: straight bf16 copy from latB16g (contiguous 16B segments)
    const uint4e* g4 = (const uint4e*)latB16g + (size_t)b32 * 64;
#pragma unroll 1
    for (int it = 0; it < 8; ++it) {
      int idx = t + 256 * it;          // 0..2047
      uint4e v = g4[idx];
      int i = idx >> 6;
      int rem = idx & 63;
      int j = rem >> 1, half = rem & 1;
      unsigned* dst = latB_dw + (i * 32 + j) * 10 + half * 4;
      *(uint2e*)dst = (uint2e){v.x, v.y};
      *(uint2e*)(dst + 2) = (uint2e){v.z, v.w};
    }
  }
  {  // qkL[i][l] from qkT
    float* qkL = (float*)(smem + QKL_OFF);
    int i = t & 31;
#pragma unroll
    for (int it = 0; it < 2; ++it) {
      int ll = (t >> 5) + 8 * it;
      qkL[i * 20 + ll] = qkT[(size_t)ll * NROW + b32 + i];
    }
  }
  {  // h3B[j][k] bf16 from row-major h (d_out region)
    int cp = t & 31, jj = t >> 5;
    const float2* h2 = (const float2*)hrow;
    unsigned* dst = (unsigned*)(smem + H3B_OFF);
#pragma unroll 1
    for (int it = 0; it < 4; ++it) {
      int j = jj + 8 * it;
      float2 hv = h2[((size_t)(b32 + j) * 64 + 2 * cp) >> 1];
      dst[j * 36 + cp] = f2bf(hv.x) | (f2bf(hv.y) << 16);
    }
  }
  {  // w1hL[c][k] (k<64)
    int kp = t & 31, cc = t >> 5;
    const float2* w12 = (const float2*)w1;
    unsigned* dst = (unsigned*)(smem + W1H_OFF);
#pragma unroll 1
    for (int it = 0; it < 8; ++it) {
      int c = cc + 8 * it;
      float2 wv = w12[(c * 80 + 2 * kp) >> 1];
      dst[c * 36 + kp] = f2bf(wv.x) | (f2bf(wv.y) << 16);
    }
  }
  {  // w1latL[c][l]
    int lp = t & 7, cc = t >> 3;
    const float2* w12 = (const float2*)w1;
    unsigned* dst = (unsigned*)(smem + W1L_OFF);
#pragma unroll 1
    for (int it = 0; it < 2; ++it) {
      int c = cc + 32 * it;
      float2 wv = w12[(c * 80 + 64 + 2 * lp) >> 1];
      dst[c * 10 + lp] = f2bf(wv.x) | (f2bf(wv.y) << 16);
    }
  }
  {  // w2P[nn][p] = w2[nn][c(p)], c(p) = ((p>>2)&3)*16 + (p>>4)*4 + (p&3)
    int pp = t & 31, nn = t >> 5;
    const float2* w22 = (const float2*)w2;
    unsigned* dst = (unsigned*)(smem + W2P_OFF);
#pragma unroll 1
    for (int it = 0; it < 2; ++it) {
      int n2 = nn + 8 * it;
      int p = 2 * pp;
      int c = ((p >> 2) & 3) * 16 + (p >> 4) * 4 + (p & 3);
      float2 wv = w22[(n2 * 64 + c) >> 1];
      dst[n2 * 36 + pp] = f2bf(wv.x) | (f2bf(wv.y) << 16);
    }
  }
  __syncthreads();

  // ---- logits + softmax -> alL (reads latB + qkL) ----
  {
    const float* qkL = (const float*)(smem + QKL_OFF);
    float* alL = (float*)(smem + ALL_OFF);
#pragma unroll 1
    for (int p = 0; p < 4; ++p) {
      int i = (t >> 5) + 8 * p;
      int j = t & 31;
      const unsigned* lr = latB_dw + (i * 32 + j) * 10;
      float acc = 0.f;
#pragma unroll
      for (int d = 0; d < 8; ++d) {
        unsigned u = lr[d];
        float lo = __uint_as_float(u << 16);
        float hi = __uint_as_float(u & 0xffff0000u);
        acc = fmaf(lo, qkL[i * 20 + 2 * d], acc);
        acc = fmaf(hi, qkL[i * 20 + 2 * d + 1], acc);
      }
      if (j == i) acc = -1e9f;
      float mx = acc;
#pragma unroll
      for (int msk = 16; msk > 0; msk >>= 1) mx = fmaxf(mx, __shfl_xor(mx, msk, 32));
      float e = __expf(acc - mx);
      float s = e;
#pragma unroll
      for (int msk = 16; msk > 0; msk >>= 1) s += __shfl_xor(s, msk, 32);
      alL[i * 33 + j] = e / s;
    }
  }

  const int w = t >> 6, l = t & 63;
  const int n15 = l & 15, q = l >> 4;
  const int jh = w & 1, ibase = (w >> 1) * 16;
  const bool kact = (q < 2);

  // ---- phase 1: hp[ct][reg] for (c = ct*16+q*4+reg, j = jh*16+n15) ----
  f32x4 hp[4];
#pragma unroll
  for (int ct = 0; ct < 4; ++ct) hp[ct] = (f32x4){0.f, 0.f, 0.f, 0.f};
#pragma unroll
  for (int ct = 0; ct < 4; ++ct)
#pragma unroll
    for (int ks = 0; ks < 2; ++ks) {
      bf16x8 aF = *(const bf16x8*)(smem + W1H_OFF + (ct * 16 + n15) * 144 + ks * 64 + q * 16);
      bf16x8 bF = *(const bf16x8*)(smem + H3B_OFF + (jh * 16 + n15) * 144 + ks * 64 + q * 16);
      hp[ct] = __builtin_amdgcn_mfma_f32_16x16x32_bf16(aF, bF, hp[ct], 0, 0, 0);
    }
#pragma unroll
  for (int ct = 0; ct < 4; ++ct)
#pragma unroll
    for (int reg = 0; reg < 4; ++reg)
      hp[ct][reg] += b1[ct * 16 + q * 4 + reg];

  // hoisted fragments
  bf16x8 aL[4];
#pragma unroll
  for (int ct = 0; ct < 4; ++ct) {
    union { unsigned u[4]; bf16x8 h; } tmp;
    tmp.u[0] = tmp.u[1] = tmp.u[2] = tmp.u[3] = 0u;
    if (kact) {
      const unsigned* p = (const unsigned*)(smem + W1L_OFF) + (ct * 16 + n15) * 10 + q * 4;
      uint2e d0 = *(const uint2e*)p;
      uint2e d1 = *(const uint2e*)(p + 2);
      tmp.u[0] = d0.x; tmp.u[1] = d0.y; tmp.u[2] = d1.x; tmp.u[3] = d1.y;
    }
    aL[ct] = tmp.h;
  }
  bf16x8 w2F[2];
#pragma unroll
  for (int ks = 0; ks < 2; ++ks)
    w2F[ks] = *(const bf16x8*)(smem + W2P_OFF + n15 * 144 + ks * 64 + q * 16);
  float b2v[4];
#pragma unroll
  for (int reg = 0; reg < 4; ++reg) b2v[reg] = b2[q * 4 + reg];

  __syncthreads();  // alL complete before main loop reads it

  // ---- main i loop ----
  float agg[4] = {0.f, 0.f, 0.f, 0.f};
  char* wb = smem + MT_OFF + w * 2560;
  const float* alLf = (const float*)(smem + ALL_OFF);
#pragma unroll 1
  for (int it = 0; it < 16; ++it) {
    int ii = ibase + it;
    int r = ii * 32 + jh * 16 + n15;
    union { unsigned u[4]; bf16x8 h; } latF;
    latF.u[0] = latF.u[1] = latF.u[2] = latF.u[3] = 0u;
    if (kact) {
      const unsigned* p = latB_dw + r * 10 + q * 4;
      uint2e d0 = *(const uint2e*)p;
      uint2e d1 = *(const uint2e*)(p + 2);
      latF.u[0] = d0.x; latF.u[1] = d0.y; latF.u[2] = d1.x; latF.u[3] = d1.y;
    }
    f32x4 acc[4];
#pragma unroll
    for (int ct = 0; ct < 4; ++ct) {
      acc[ct] = (f32x4){0.f, 0.f, 0.f, 0.f};
      acc[ct] = __builtin_amdgcn_mfma_f32_16x16x32_bf16(aL[ct], latF.h, acc[ct], 0, 0, 0);
    }
    // lrelu + pack + pi-transpose write (per-wave private buffer, no barrier)
#pragma unroll
    for (int h = 0; h < 2; ++h) {
      float m0[4], m1[4];
#pragma unroll
      for (int reg = 0; reg < 4; ++reg) {
        float v0 = acc[2 * h][reg] + hp[2 * h][reg];
        float v1 = acc[2 * h + 1][reg] + hp[2 * h + 1][reg];
        m0[reg] = fmaxf(v0, 0.01f * v0);
        m1[reg] = fmaxf(v1, 0.01f * v1);
      }
      uint4e pk4;
      pk4.x = pkbf(m0[0], m0[1]); pk4.y = pkbf(m0[2], m0[3]);
      pk4.z = pkbf(m1[0], m1[1]); pk4.w = pkbf(m1[2], m1[3]);
      int qp = (2 * q + h) & 3;
      *(uint4e*)(wb + (q >> 1) * 1280 + n15 * 80 + qp * 16) = pk4;
    }
    // phase 3
    f32x4 msg = (f32x4){0.f, 0.f, 0.f, 0.f};
#pragma unroll
    for (int ks = 0; ks < 2; ++ks) {
      bf16x8 mF = *(const bf16x8*)(wb + ks * 1280 + n15 * 80 + q * 16);
      msg = __builtin_amdgcn_mfma_f32_16x16x32_bf16(w2F[ks], mF, msg, 0, 0, 0);
    }
    float aw = alLf[ii * 33 + jh * 16 + n15];
#pragma unroll
    for (int reg = 0; reg < 4; ++reg)
      agg[reg] = fmaf(aw, msg[reg] + b2v[reg], agg[reg]);
  }
  // park agg in own wave buffer
  {
    f32x4 av; av[0] = agg[0]; av[1] = agg[1]; av[2] = agg[2]; av[3] = agg[3];
    *(f32x4*)(wb + n15 * 80 + q * 16) = av;
  }
  __syncthreads();
  // combine wave pairs (i-low + i-high) and add q head
#pragma unroll
  for (int tt = 0; tt < 2; ++tt) {
    int idx = t + 256 * tt;
    int jg = idx >> 4, nn = idx & 15;
    int jh2 = jg >> 4, jl = jg & 15;
    float a0 = *(const float*)(smem + MT_OFF + jh2 * 2560 + jl * 80 + nn * 4);
    float a1 = *(const float*)(smem + MT_OFF + (jh2 + 2) * 2560 + jl * 80 + nn * 4);
    out[(size_t)b * 512 + idx] = a0 + a1 + qT[(size_t)nn * NROW + b32 + jg];
  }
}

}  // namespace

extern "C" void kernel_launch(void* const* d_in, const int* in_sizes, int n_in,
                              void* d_out, int out_size, void* d_ws, size_t ws_size,
                              hipStream_t stream) {
  (void)in_sizes; (void)n_in; (void)out_size; (void)ws_size;
  const float* inputs = (const float*)d_in[0];
  const float* hidden = (const float*)d_in[1];
  const float* eps    = (const float*)d_in[2];
  const float* fc1w   = (const float*)d_in[3];
  const float* fc1b   = (const float*)d_in[4];
  const float* wih    = (const float*)d_in[5];
  const float* whh    = (const float*)d_in[6];
  const float* bih    = (const float*)d_in[7];
  const float* bhh    = (const float*)d_in[8];
  const float* fc2w   = (const float*)d_in[9];
  const float* fc2b   = (const float*)d_in[10];
  const float* ew1    = (const float*)d_in[11];
  const float* eb1    = (const float*)d_in[12];
  const float* bng    = (const float*)d_in[13];
  const float* bnb    = (const float*)d_in[14];
  const float* ew2    = (const float*)d_in[15];
  const float* eb2    = (const float*)d_in[16];
  const float* w1     = (const float*)d_in[17];
  const float* b1     = (const float*)d_in[18];
  const float* w2     = (const float*)d_in[19];
  const float* b2     = (const float*)d_in[20];
  const float* wqw    = (const float*)d_in[21];
  const float* wkw    = (const float*)d_in[23];

  float* ws = (float*)d_ws;
  float* hT     = ws;                 // 2097152
  float* qT     = ws + 2097152;       // 524288
  float* qkT    = ws + 2621440;       // 524288 (reuses old queryT slot)
  float* z1T    = ws + 3670016;       // 2097152
  float* part   = ws + 5767168;       // 32768 used
  float* stat   = ws + 5832704;       // 128
  unsigned* latB16g = (unsigned*)(ws + 5832832);  // [N][256] u32 (bf16 pairs), 33.5 MB

  float* out_q = (float*)d_out;             // 32768 x 16
  float* out_h = (float*)d_out + 524288;    // 32768 x 64

  hipLaunchKernelGGL(k_fgru, dim3(256), dim3(256), 0, stream,
                     inputs, hidden, fc1w, fc1b, wih, whh, bih, bhh, hT, out_h);
  hipLaunchKernelGGL(k_heads, dim3(256), dim3(256), 0, stream,
                     hT, fc2w, fc2b, wqw, wkw, ew1, eb1, qT, qkT, z1T, part);
  hipLaunchKernelGGL(k_bnstat, dim3(1), dim3(64), 0, stream, part, bng, bnb, stat);
  hipLaunchKernelGGL(k_emb_gemm, dim3(2048), dim3(256), 0, stream, z1T, stat, ew2, eb2, eps, latB16g);
  hipLaunchKernelGGL(k_msg, dim3(1024), dim3(256), 0, stream,
                     latB16g, qkT, qT, out_h, w1, b1, w2, b2, out_q);
}

// Round 10
// 271.729 us; speedup vs baseline: 6.2130x; 1.0064x over previous
//
#include <hip/hip_runtime.h>
#include <math.h>

namespace {

constexpr int NROW = 32768;   // BS*A rows
constexpr int HDIM = 64;
constexpr int DH   = 512;     // latent half-dim

typedef __attribute__((ext_vector_type(8))) short bf16x8;
typedef __attribute__((ext_vector_type(4))) float f32x4;
typedef __attribute__((ext_vector_type(4))) unsigned uint4e;
typedef __attribute__((ext_vector_type(2))) unsigned uint2e;

__device__ __forceinline__ float sigmoidf_(float x) { return 1.f / (1.f + __expf(-x)); }
__device__ __forceinline__ float lrelu_(float x) { return x > 0.f ? x : 0.01f * x; }
__device__ __forceinline__ unsigned f2bf(float x) {  // RNE float->bf16 (as low 16 bits)
  unsigned u = __float_as_uint(x);
  return (u + 0x7fffu + ((u >> 16) & 1u)) >> 16;
}
// fast pack: round-half-up bf16 pair (a -> low16, b -> high16)
__device__ __forceinline__ unsigned pkbf(float a, float b) {
  unsigned ua = __float_as_uint(a) + 0x8000u;
  unsigned ub = __float_as_uint(b) + 0x8000u;
  return __builtin_amdgcn_perm(ub, ua, 0x07060302);
}

// K1+K2 fused (v2): 512 threads, 8 waves x 16 rows; A/B frags packed in-register
// from global fp32 (no inU/f1U/hU staging). LDS = xU + gU = 73.7 KB -> 2 blocks/CU.
__global__ __launch_bounds__(512, 1) void k_fgru(
    const float* __restrict__ in,      // [N][96]
    const float* __restrict__ hprev,   // [N][64]
    const float* __restrict__ fc1w, const float* __restrict__ fc1b,
    const float* __restrict__ wih, const float* __restrict__ whh,
    const float* __restrict__ bih, const float* __restrict__ bhh,
    float* __restrict__ hT, float* __restrict__ hout) {
  __shared__ char smem[73728];
  const int t = threadIdx.x;
  const int n0 = blockIdx.x * 128;
  short*    xS = (short*)smem;                 // [128][72] shorts (18432 B)
  unsigned* gU = (unsigned*)(smem + 18432);    // [6][64][36] (55296 B)
  float*    trF = (float*)(smem + 18432);      // [64][133] f32, overlays gU after GRU

  // stage gate weights (bf16)
  const float2* wih2 = (const float2*)wih;
  const float2* whh2 = (const float2*)whh;
#pragma unroll 1
  for (int i = 0; i < 12; ++i) {
    int idx = t + 512 * i;               // 6144
    int row = idx >> 5, kp = idx & 31;
    float2 v = wih2[row * 32 + kp];
    int gate = row >> 6, cl = row & 63;
    gU[(gate * 64 + cl) * 36 + kp] = pkbf(v.x, v.y);
  }
#pragma unroll 1
  for (int i = 0; i < 12; ++i) {
    int idx = t + 512 * i;
    int row = idx >> 5, kp = idx & 31;
    float2 v = whh2[row * 32 + kp];
    int gate = row >> 6, cl = row & 63;
    gU[((gate + 3) * 64 + cl) * 36 + kp] = pkbf(v.x, v.y);
  }

  const int w = t >> 6, l = t & 63;
  const int m = l & 15, g = l >> 4;
  const int rowA = n0 + w * 16 + m;      // A-operand row for this lane

  // ---- fc1 phase: A frags direct from inputs (fp32 -> bf16) ----
  bf16x8 af[3];
#pragma unroll
  for (int ks = 0; ks < 3; ++ks) {
    const float4* p = (const float4*)(in + (size_t)rowA * 96 + ks * 32 + g * 8);
    float4 a = p[0], b = p[1];
    union { unsigned u[4]; bf16x8 h; } tw;
    tw.u[0] = pkbf(a.x, a.y); tw.u[1] = pkbf(a.z, a.w);
    tw.u[2] = pkbf(b.x, b.y); tw.u[3] = pkbf(b.z, b.w);
    af[ks] = tw.h;
  }
  {
    f32x4 accx[4];
#pragma unroll
    for (int ct = 0; ct < 4; ++ct) accx[ct] = (f32x4){0.f, 0.f, 0.f, 0.f};
#pragma unroll
    for (int ct = 0; ct < 4; ++ct)
#pragma unroll
      for (int ks = 0; ks < 3; ++ks) {
        const float4* p = (const float4*)(fc1w + (ct * 16 + m) * 96 + ks * 32 + g * 8);
        float4 a = p[0], b = p[1];
        union { unsigned u[4]; bf16x8 h; } tw;
        tw.u[0] = pkbf(a.x, a.y); tw.u[1] = pkbf(a.z, a.w);
        tw.u[2] = pkbf(b.x, b.y); tw.u[3] = pkbf(b.z, b.w);
        accx[ct] = __builtin_amdgcn_mfma_f32_16x16x32_bf16(af[ks], tw.h, accx[ct], 0, 0, 0);
      }
#pragma unroll
    for (int ct = 0; ct < 4; ++ct) {
      int c = ct * 16 + m;
      float bc = fc1b[c];
#pragma unroll
      for (int reg = 0; reg < 4; ++reg) {
        int nl = w * 16 + g * 4 + reg;
        float v = fmaxf(accx[ct][reg] + bc, 0.f);
        xS[nl * 72 + c] = (short)((__float_as_uint(v) + 0x8000u) >> 16);
      }
    }
  }
  __syncthreads();   // xS ready + gU ready

  // ---- GRU phase ----
  bf16x8 ax[2], ah[2];
#pragma unroll
  for (int ks = 0; ks < 2; ++ks) {
    ax[ks] = *(const bf16x8*)(xS + (w * 16 + m) * 72 + ks * 32 + g * 8);
    const float4* p = (const float4*)(hprev + (size_t)rowA * 64 + ks * 32 + g * 8);
    float4 a = p[0], b = p[1];
    union { unsigned u[4]; bf16x8 h; } tw;
    tw.u[0] = pkbf(a.x, a.y); tw.u[1] = pkbf(a.z, a.w);
    tw.u[2] = pkbf(b.x, b.y); tw.u[3] = pkbf(b.z, b.w);
    ah[ks] = tw.h;
  }
  const short* gS = (const short*)gU;
  float hc[4][4];
#pragma unroll 1
  for (int ct = 0; ct < 4; ++ct) {
    f32x4 a_ir = (f32x4){0.f,0.f,0.f,0.f}, a_iz = (f32x4){0.f,0.f,0.f,0.f},
          a_in = (f32x4){0.f,0.f,0.f,0.f}, a_hr = (f32x4){0.f,0.f,0.f,0.f},
          a_hz = (f32x4){0.f,0.f,0.f,0.f}, a_hn = (f32x4){0.f,0.f,0.f,0.f};
    int crow = ct * 16 + m;
#pragma unroll
    for (int ks = 0; ks < 2; ++ks) {
      bf16x8 b0 = *(const bf16x8*)(gS + (0 * 64 + crow) * 72 + ks * 32 + g * 8);
      bf16x8 b1 = *(const bf16x8*)(gS + (1 * 64 + crow) * 72 + ks * 32 + g * 8);
      bf16x8 b2 = *(const bf16x8*)(gS + (2 * 64 + crow) * 72 + ks * 32 + g * 8);
      bf16x8 b3 = *(const bf16x8*)(gS + (3 * 64 + crow) * 72 + ks * 32 + g * 8);
      bf16x8 b4 = *(const bf16x8*)(gS + (4 * 64 + crow) * 72 + ks * 32 + g * 8);
      bf16x8 b5 = *(const bf16x8*)(gS + (5 * 64 + crow) * 72 + ks * 32 + g * 8);
      a_ir = __builtin_amdgcn_mfma_f32_16x16x32_bf16(ax[ks], b0, a_ir, 0, 0, 0);
      a_iz = __builtin_amdgcn_mfma_f32_16x16x32_bf16(ax[ks], b1, a_iz, 0, 0, 0);
      a_in = __builtin_amdgcn_mfma_f32_16x16x32_bf16(ax[ks], b2, a_in, 0, 0, 0);
      a_hr = __builtin_amdgcn_mfma_f32_16x16x32_bf16(ah[ks], b3, a_hr, 0, 0, 0);
      a_hz = __builtin_amdgcn_mfma_f32_16x16x32_bf16(ah[ks], b4, a_hz, 0, 0, 0);
      a_hn = __builtin_amdgcn_mfma_f32_16x16x32_bf16(ah[ks], b5, a_hn, 0, 0, 0);
    }
    float bir = bih[crow], biz = bih[64 + crow], bin = bih[128 + crow];
    float bhr = bhh[crow], bhz = bhh[64 + crow], bhn = bhh[128 + crow];
#pragma unroll
    for (int reg = 0; reg < 4; ++reg) {
      int nl = w * 16 + g * 4 + reg;
      float hv = hprev[(size_t)(n0 + nl) * 64 + crow];
      float r  = sigmoidf_(a_ir[reg] + bir + a_hr[reg] + bhr);
      float z  = sigmoidf_(a_iz[reg] + biz + a_hz[reg] + bhz);
      float nn = tanhf(a_in[reg] + bin + r * (a_hn[reg] + bhn));
      hc[ct][reg] = (1.f - z) * nn + z * hv;
    }
  }
  __syncthreads();   // all waves done reading gU before trF overlay
#pragma unroll
  for (int ct = 0; ct < 4; ++ct)
#pragma unroll
    for (int reg = 0; reg < 4; ++reg)
      trF[(ct * 16 + m) * 133 + w * 16 + g * 4 + reg] = hc[ct][reg];
  __syncthreads();
#pragma unroll 1
  for (int i = 0; i < 16; ++i) {
    int idx = t + 512 * i;
    int nl = idx & 127, cl = idx >> 7;
    hT[(size_t)cl * NROW + n0 + nl] = trF[cl * 133 + nl];
  }
#pragma unroll 1
  for (int i = 0; i < 16; ++i) {
    int idx = t + 512 * i;
    int c = idx & 63, nl = idx >> 6;
    hout[(size_t)(n0 + nl) * 64 + c] = trF[c * 133 + nl];
  }
}

// K3 (MFMA): 96-channel fused head GEMM (fc2 16 + qk 16 + ew1 64), K=64.
__global__ __launch_bounds__(256) void k_heads(const float* __restrict__ hT,
    const float* __restrict__ fc2w, const float* __restrict__ fc2b,
    const float* __restrict__ wqw, const float* __restrict__ wkw,
    const float* __restrict__ ew1, const float* __restrict__ eb1,
    float* __restrict__ qT, float* __restrict__ qkT, float* __restrict__ z1T,
    float* __restrict__ part) {
  __shared__ char smem[36864];
  const int t = threadIdx.x;
  const int n0 = blockIdx.x * 128;
  unsigned* hU = (unsigned*)smem;                 // [128][36]
  unsigned* wU = (unsigned*)(smem + 18432);       // [96][36]
  float* sp1 = (float*)(smem + 18432 + 13824);    // [4][64]
  float* sp2 = sp1 + 256;                         // [4][64]
  const float qs = 0.17677669529663687f;          // 1/sqrt(32)

#pragma unroll 1
  for (int i = 0; i < 16; ++i) {
    int idx = t + 256 * i;
    int nl = idx & 127, kp = idx >> 7;
    float v0 = hT[(size_t)(2 * kp) * NROW + n0 + nl];
    float v1 = hT[(size_t)(2 * kp + 1) * NROW + n0 + nl];
    hU[nl * 36 + kp] = pkbf(v0, v1);
  }
#pragma unroll 1
  for (int i = 0; i < 12; ++i) {
    int idx = t + 256 * i;          // 0..3071
    int kp = idx & 31, cl = idx >> 5;   // cl 0..95
    unsigned val;
    if (cl < 16) {
      float2 v = *(const float2*)(fc2w + cl * 64 + 2 * kp);
      val = pkbf(v.x, v.y);
    } else if (cl < 32) {
      int ll = cl - 16;
      float s0 = 0.f, s1 = 0.f;
#pragma unroll 1
      for (int a = 0; a < 32; ++a) {
        float wk = wkw[a * 16 + ll];
        s0 = fmaf(wk, wqw[a * 64 + 2 * kp], s0);
        s1 = fmaf(wk, wqw[a * 64 + 2 * kp + 1], s1);
      }
      val = pkbf(s0 * qs, s1 * qs);
    } else {
      float2 v = *(const float2*)(ew1 + (cl - 32) * 64 + 2 * kp);
      val = pkbf(v.x, v.y);
    }
    wU[cl * 36 + kp] = val;
  }
  __syncthreads();

  const int w = t >> 6, l = t & 63;
  const int m = l & 15, g = l >> 4;
  const short* sH = (const short*)hU;
  const short* sW = (const short*)wU;

  bf16x8 af[2][2];
#pragma unroll
  for (int mt = 0; mt < 2; ++mt)
#pragma unroll
    for (int ks = 0; ks < 2; ++ks)
      af[mt][ks] = *(const bf16x8*)(sH + (w * 32 + mt * 16 + m) * 72 + ks * 32 + g * 8);

  f32x4 acc[2][6];
#pragma unroll
  for (int mt = 0; mt < 2; ++mt)
#pragma unroll
    for (int ct = 0; ct < 6; ++ct) acc[mt][ct] = (f32x4){0.f, 0.f, 0.f, 0.f};
#pragma unroll
  for (int ct = 0; ct < 6; ++ct)
#pragma unroll
    for (int ks = 0; ks < 2; ++ks) {
      bf16x8 bw = *(const bf16x8*)(sW + (ct * 16 + m) * 72 + ks * 32 + g * 8);
#pragma unroll
      for (int mt = 0; mt < 2; ++mt)
        acc[mt][ct] = __builtin_amdgcn_mfma_f32_16x16x32_bf16(af[mt][ks], bw, acc[mt][ct], 0, 0, 0);
    }

  float s1[4], s2[4];
#pragma unroll
  for (int zt = 0; zt < 4; ++zt) { s1[zt] = 0.f; s2[zt] = 0.f; }
#pragma unroll
  for (int mt = 0; mt < 2; ++mt) {
    int nb = n0 + w * 32 + mt * 16 + g * 4;
    {  // q head: c = m
      float bc = fc2b[m];
      f32x4 v;
#pragma unroll
      for (int reg = 0; reg < 4; ++reg) v[reg] = acc[mt][0][reg] + bc;
      *(f32x4*)(qT + (size_t)m * NROW + nb) = v;
    }
    // qk head: l' = m, no bias
    *(f32x4*)(qkT + (size_t)m * NROW + nb) = acc[mt][1];
#pragma unroll
    for (int ct = 2; ct < 6; ++ct) {  // z1 head: z = (ct-2)*16 + m
      int z = (ct - 2) * 16 + m;
      float bc = eb1[z];
      f32x4 v;
#pragma unroll
      for (int reg = 0; reg < 4; ++reg) {
        float zv = acc[mt][ct][reg] + bc;
        v[reg] = zv;
        s1[ct - 2] += zv;
        s2[ct - 2] = fmaf(zv, zv, s2[ct - 2]);
      }
      *(f32x4*)(z1T + (size_t)z * NROW + nb) = v;
    }
  }
#pragma unroll
  for (int zt = 0; zt < 4; ++zt) {
    s1[zt] += __shfl_down(s1[zt], 16, 64);
    s1[zt] += __shfl_down(s1[zt], 32, 64);
    s2[zt] += __shfl_down(s2[zt], 16, 64);
    s2[zt] += __shfl_down(s2[zt], 32, 64);
  }
  if (l < 16) {
#pragma unroll
    for (int zt = 0; zt < 4; ++zt) {
      sp1[w * 64 + zt * 16 + m] = s1[zt];
      sp2[w * 64 + zt * 16 + m] = s2[zt];
    }
  }
  __syncthreads();
  if (t < 64) {
    float a1 = sp1[t] + sp1[64 + t] + sp1[128 + t] + sp1[192 + t];
    float a2 = sp2[t] + sp2[64 + t] + sp2[128 + t] + sp2[192 + t];
    part[(size_t)blockIdx.x * 128 + t] = a1;
    part[(size_t)blockIdx.x * 128 + 64 + t] = a2;
  }
}

// K4: finalize BN stats (256 head blocks)
__global__ void k_bnstat(const float* __restrict__ part,
    const float* __restrict__ bng, const float* __restrict__ bnb,
    float* __restrict__ stat) {
  int c = threadIdx.x;  // 64 threads
  float s1 = 0.f, s2 = 0.f;
  for (int b = 0; b < 256; ++b) {
    s1 += part[(size_t)b * 128 + c];
    s2 += part[(size_t)b * 128 + 64 + c];
  }
  float mean = s1 * (1.f / NROW);
  float var = s2 * (1.f / NROW) - mean * mean;
  float rstd = rsqrtf(var + 1e-5f);
  float sc = bng[c] * rstd;
  stat[c] = sc;
  stat[64 + c] = bnb[c] - mean * sc;
}

// K5 (v3): MFMA bf16 GEMM -> bf16 latent, direct short stores from C-layout.
// Epilogue: std = max(exp(0.5*lv), sqrt(0.002)); eps staged to LDS coalesced.
__global__ __launch_bounds__(256) void k_emb_gemm(const float* __restrict__ z1T,
    const float* __restrict__ stat,
    const float* __restrict__ ew2, const float* __restrict__ eb2,
    const float* __restrict__ eps,
    unsigned* __restrict__ latB16g) {
  __shared__ char smem[36864];
  const int t = threadIdx.x;
  const int nb = blockIdx.x >> 3;
  const int cb = blockIdx.x & 7;
  const int n0 = nb * 128;
  const int c0 = cb * 64;
  unsigned short* latH = (unsigned short*)latB16g;   // [N][512] bf16

  unsigned* aU = (unsigned*)smem;                 // A: [128][36]
  unsigned* bmU = (unsigned*)(smem + 18432);      // Wmu: [64][36]
  unsigned* blU = (unsigned*)(smem + 27648);      // Wlv: [64][36]

#pragma unroll 1
  for (int i = 0; i < 16; ++i) {
    int idx = t + 256 * i;
    int nl = idx & 127;
    int kp = idx >> 7;
    float v0 = z1T[(size_t)(2 * kp) * NROW + n0 + nl];
    float v1 = z1T[(size_t)(2 * kp + 1) * NROW + n0 + nl];
    v0 = lrelu_(fmaf(stat[2 * kp], v0, stat[64 + 2 * kp]));
    v1 = lrelu_(fmaf(stat[2 * kp + 1], v1, stat[64 + 2 * kp + 1]));
    aU[nl * 36 + kp] = pkbf(v0, v1);
  }
  const float2* ew2_2 = (const float2*)ew2;
#pragma unroll 1
  for (int i = 0; i < 8; ++i) {
    int idx = t + 256 * i;
    int kp = idx & 31;
    int cl = idx >> 5;
    float2 m2 = ew2_2[(size_t)(c0 + cl) * 32 + kp];
    float2 l2 = ew2_2[(size_t)(512 + c0 + cl) * 32 + kp];
    bmU[cl * 36 + kp] = pkbf(m2.x, m2.y);
    blU[cl * 36 + kp] = pkbf(l2.x, l2.y);
  }
  __syncthreads();

  const int w = t >> 6, l = t & 63;
  const int m = l & 15, g = l >> 4;
  const short* sA = (const short*)smem;
  const short* sBm = (const short*)(smem + 18432);
  const short* sBl = (const short*)(smem + 27648);

  f32x4 accm[2][4], accl[2][4];
#pragma unroll
  for (int mt = 0; mt < 2; ++mt)
#pragma unroll
    for (int ct = 0; ct < 4; ++ct) {
      accm[mt][ct] = (f32x4){0.f, 0.f, 0.f, 0.f};
      accl[mt][ct] = (f32x4){0.f, 0.f, 0.f, 0.f};
    }
  bf16x8 af[2][2];
#pragma unroll
  for (int mt = 0; mt < 2; ++mt)
#pragma unroll
    for (int ks = 0; ks < 2; ++ks)
      af[mt][ks] = *(const bf16x8*)(sA + (w * 32 + mt * 16 + m) * 72 + ks * 32 + g * 8);
#pragma unroll
  for (int ct = 0; ct < 4; ++ct) {
#pragma unroll
    for (int ks = 0; ks < 2; ++ks) {
      bf16x8 bm = *(const bf16x8*)(sBm + (ct * 16 + m) * 72 + ks * 32 + g * 8);
      bf16x8 bl = *(const bf16x8*)(sBl + (ct * 16 + m) * 72 + ks * 32 + g * 8);
#pragma unroll
      for (int mt = 0; mt < 2; ++mt) {
        accm[mt][ct] = __builtin_amdgcn_mfma_f32_16x16x32_bf16(af[mt][ks], bm, accm[mt][ct], 0, 0, 0);
        accl[mt][ct] = __builtin_amdgcn_mfma_f32_16x16x32_bf16(af[mt][ks], bl, accl[mt][ct], 0, 0, 0);
      }
    }
  }
  __syncthreads();
  // stage eps tile [128][68] f32 (coalesced float4)
  float* epsL = (float*)smem;
  const float4* eps4 = (const float4*)eps;
#pragma unroll 1
  for (int i = 0; i < 8; ++i) {
    int idx = t + 256 * i;          // 0..2047
    int nl = idx >> 4, c4 = idx & 15;
    float4 v = eps4[((size_t)(n0 + nl) * 512 + c0 + 4 * c4) >> 2];
    *(float4*)(epsL + nl * 68 + 4 * c4) = v;
  }
  __syncthreads();
  // epilogue: direct bf16 short stores from C-layout
  const float stdfloor = 0.04472135955f;   // sqrt(0.002)
#pragma unroll
  for (int ct = 0; ct < 4; ++ct) {
    int cl = ct * 16 + m;
    float ebm = eb2[c0 + cl], ebl = eb2[DH + c0 + cl];
#pragma unroll
    for (int mt = 0; mt < 2; ++mt) {
#pragma unroll
      for (int reg = 0; reg < 4; ++reg) {
        int nl = w * 32 + mt * 16 + g * 4 + reg;
        float mu = accm[mt][ct][reg] + ebm;
        float lv = accl[mt][ct][reg] + ebl;
        float sd = fmaxf(__expf(0.5f * lv), stdfloor);
        float lat = fmaf(sd, epsL[nl * 68 + cl], mu);
        latH[(size_t)(n0 + nl) * 512 + c0 + cl] =
            (unsigned short)((__float_as_uint(lat) + 0x8000u) >> 16);
      }
    }
  }
}

// K7 (MFMA): one block per b. Logit+softmax in-kernel from bf16 latent.
constexpr int LATB_OFF = 0;        // [1024][20] bf16, 40B rows (r = i*32+j)
constexpr int H3B_OFF  = 40960;    // [32][72] bf16, 144B rows
constexpr int W1H_OFF  = 45568;    // [64][72] bf16
constexpr int W1L_OFF  = 54784;    // [64][20] bf16
constexpr int W2P_OFF  = 57344;    // [16][72] bf16 (pi-permuted c)
constexpr int ALL_OFF  = 59648;    // [32][33] f32 alpha
constexpr int MT_OFF   = 63872;    // 4 waves x 2560B private transpose buf
constexpr int QKL_OFF  = 74112;    // [32][20] f32 qk
__global__ __launch_bounds__(256, 1) void k_msg(
    const unsigned* __restrict__ latB16g, const float* __restrict__ qkT,
    const float* __restrict__ qT, const float* __restrict__ hrow,
    const float* __restrict__ w1, const float* __restrict__ b1,
    const float* __restrict__ w2, const float* __restrict__ b2,
    float* __restrict__ out) {
  __shared__ char smem[76672];
  const int t = threadIdx.x;
  const int b = blockIdx.x;
  const int b32 = b * 32;
  unsigned* latB_dw = (unsigned*)(smem + LATB_OFF);

  // ---- staging ----
  {  // latB: straight bf16 copy from latB16g (contiguous 16B segments)
    const uint4e* g4 = (const uint4e*)latB16g + (size_t)b32 * 64;
#pragma unroll 1
    for (int it = 0; it < 8; ++it) {
      int idx = t + 256 * it;          // 0..2047
      uint4e v = g4[idx];
      int i = idx >> 6;
      int rem = idx & 63;
      int j = rem >> 1, half = rem & 1;
      unsigned* dst = latB_dw + (i * 32 + j) * 10 + half * 4;
      *(uint2e*)dst = (uint2e){v.x, v.y};
      *(uint2e*)(dst + 2) = (uint2e){v.z, v.w};
    }
  }
  {  // qkL[i][l] from qkT
    float* qkL = (float*)(smem + QKL_OFF);
    int i = t & 31;
#pragma unroll
    for (int it = 0; it < 2; ++it) {
      int ll = (t >> 5) + 8 * it;
      qkL[i * 20 + ll] = qkT[(size_t)ll * NROW + b32 + i];
    }
  }
  {  // h3B[j][k] bf16 from row-major h (d_out region)
    int cp = t & 31, jj = t >> 5;
    const float2* h2 = (const float2*)hrow;
    unsigned* dst = (unsigned*)(smem + H3B_OFF);
#pragma unroll 1
    for (int it = 0; it < 4; ++it) {
      int j = jj + 8 * it;
      float2 hv = h2[((size_t)(b32 + j) * 64 + 2 * cp) >> 1];
      dst[j * 36 + cp] = pkbf(hv.x, hv.y);
    }
  }
  {  // w1hL[c][k] (k<64)
    int kp = t & 31, cc = t >> 5;
    const float2* w12 = (const float2*)w1;
    unsigned* dst = (unsigned*)(smem + W1H_OFF);
#pragma unroll 1
    for (int it = 0; it < 8; ++it) {
      int c = cc + 8 * it;
      float2 wv = w12[(c * 80 + 2 * kp) >> 1];
      dst[c * 36 + kp] = pkbf(wv.x, wv.y);
    }
  }
  {  // w1latL[c][l]
    int lp = t & 7, cc = t >> 3;
    const float2* w12 = (const float2*)w1;
    unsigned* dst = (unsigned*)(smem + W1L_OFF);
#pragma unroll 1
    for (int it = 0; it < 2; ++it) {
      int c = cc + 32 * it;
      float2 wv = w12[(c * 80 + 64 + 2 * lp) >> 1];
      dst[c * 10 + lp] = pkbf(wv.x, wv.y);
    }
  }
  {  // w2P[nn][p] = w2[nn][c(p)], c(p) = ((p>>2)&3)*16 + (p>>4)*4 + (p&3)
    int pp = t & 31, nn = t >> 5;
    const float2* w22 = (const float2*)w2;
    unsigned* dst = (unsigned*)(smem + W2P_OFF);
#pragma unroll 1
    for (int it = 0; it < 2; ++it) {
      int n2 = nn + 8 * it;
      int p = 2 * pp;
      int c = ((p >> 2) & 3) * 16 + (p >> 4) * 4 + (p & 3);
      float2 wv = w22[(n2 * 64 + c) >> 1];
      dst[n2 * 36 + pp] = pkbf(wv.x, wv.y);
    }
  }
  __syncthreads();

  // ---- logits + softmax -> alL (reads latB + qkL) ----
  {
    const float* qkL = (const float*)(smem + QKL_OFF);
    float* alL = (float*)(smem + ALL_OFF);
#pragma unroll 1
    for (int p = 0; p < 4; ++p) {
      int i = (t >> 5) + 8 * p;
      int j = t & 31;
      const unsigned* lr = latB_dw + (i * 32 + j) * 10;
      float acc = 0.f;
#pragma unroll
      for (int d = 0; d < 8; ++d) {
        unsigned u = lr[d];
        float lo = __uint_as_float(u << 16);
        float hi = __uint_as_float(u & 0xffff0000u);
        acc = fmaf(lo, qkL[i * 20 + 2 * d], acc);
        acc = fmaf(hi, qkL[i * 20 + 2 * d + 1], acc);
      }
      if (j == i) acc = -1e9f;
      float mx = acc;
#pragma unroll
      for (int msk = 16; msk > 0; msk >>= 1) mx = fmaxf(mx, __shfl_xor(mx, msk, 32));
      float e = __expf(acc - mx);
      float s = e;
#pragma unroll
      for (int msk = 16; msk > 0; msk >>= 1) s += __shfl_xor(s, msk, 32);
      alL[i * 33 + j] = e / s;
    }
  }

  const int w = t >> 6, l = t & 63;
  const int n15 = l & 15, q = l >> 4;
  const int jh = w & 1, ibase = (w >> 1) * 16;
  const bool kact = (q < 2);

  // ---- phase 1: hp[ct][reg] for (c = ct*16+q*4+reg, j = jh*16+n15) ----
  f32x4 hp[4];
#pragma unroll
  for (int ct = 0; ct < 4; ++ct) hp[ct] = (f32x4){0.f, 0.f, 0.f, 0.f};
#pragma unroll
  for (int ct = 0; ct < 4; ++ct)
#pragma unroll
    for (int ks = 0; ks < 2; ++ks) {
      bf16x8 aF = *(const bf16x8*)(smem + W1H_OFF + (ct * 16 + n15) * 144 + ks * 64 + q * 16);
      bf16x8 bF = *(const bf16x8*)(smem + H3B_OFF + (jh * 16 + n15) * 144 + ks * 64 + q * 16);
      hp[ct] = __builtin_amdgcn_mfma_f32_16x16x32_bf16(aF, bF, hp[ct], 0, 0, 0);
    }
#pragma unroll
  for (int ct = 0; ct < 4; ++ct)
#pragma unroll
    for (int reg = 0; reg < 4; ++reg)
      hp[ct][reg] += b1[ct * 16 + q * 4 + reg];

  // hoisted fragments
  bf16x8 aL[4];
#pragma unroll
  for (int ct = 0; ct < 4; ++ct) {
    union { unsigned u[4]; bf16x8 h; } tmp;
    tmp.u[0] = tmp.u[1] = tmp.u[2] = tmp.u[3] = 0u;
    if (kact) {
      const unsigned* p = (const unsigned*)(smem + W1L_OFF) + (ct * 16 + n15) * 10 + q * 4;
      uint2e d0 = *(const uint2e*)p;
      uint2e d1 = *(const uint2e*)(p + 2);
      tmp.u[0] = d0.x; tmp.u[1] = d0.y; tmp.u[2] = d1.x; tmp.u[3] = d1.y;
    }
    aL[ct] = tmp.h;
  }
  bf16x8 w2F[2];
#pragma unroll
  for (int ks = 0; ks < 2; ++ks)
    w2F[ks] = *(const bf16x8*)(smem + W2P_OFF + n15 * 144 + ks * 64 + q * 16);
  float b2v[4];
#pragma unroll
  for (int reg = 0; reg < 4; ++reg) b2v[reg] = b2[q * 4 + reg];

  __syncthreads();  // alL complete before main loop reads it

  // ---- main i loop ----
  float agg[4] = {0.f, 0.f, 0.f, 0.f};
  char* wb = smem + MT_OFF + w * 2560;
  const float* alLf = (const float*)(smem + ALL_OFF);
#pragma unroll 1
  for (int it = 0; it < 16; ++it) {
    int ii = ibase + it;
    int r = ii * 32 + jh * 16 + n15;
    union { unsigned u[4]; bf16x8 h; } latF;
    latF.u[0] = latF.u[1] = latF.u[2] = latF.u[3] = 0u;
    if (kact) {
      const unsigned* p = latB_dw + r * 10 + q * 4;
      uint2e d0 = *(const uint2e*)p;
      uint2e d1 = *(const uint2e*)(p + 2);
      latF.u[0] = d0.x; latF.u[1] = d0.y; latF.u[2] = d1.x; latF.u[3] = d1.y;
    }
    f32x4 acc[4];
#pragma unroll
    for (int ct = 0; ct < 4; ++ct) {
      acc[ct] = (f32x4){0.f, 0.f, 0.f, 0.f};
      acc[ct] = __builtin_amdgcn_mfma_f32_16x16x32_bf16(aL[ct], latF.h, acc[ct], 0, 0, 0);
    }
    // lrelu + pack + pi-transpose write (per-wave private buffer, no barrier)
#pragma unroll
    for (int h = 0; h < 2; ++h) {
      float m0[4], m1[4];
#pragma unroll
      for (int reg = 0; reg < 4; ++reg) {
        float v0 = acc[2 * h][reg] + hp[2 * h][reg];
        float v1 = acc[2 * h + 1][reg] + hp[2 * h + 1][reg];
        m0[reg] = fmaxf(v0, 0.01f * v0);
        m1[reg] = fmaxf(v1, 0.01f * v1);
      }
      uint4e pk4;
      pk4.x = pkbf(m0[0], m0[1]); pk4.y = pkbf(m0[2], m0[3]);
      pk4.z = pkbf(m1[0], m1[1]); pk4.w = pkbf(m1[2], m1[3]);
      int qp = (2 * q + h) & 3;
      *(uint4e*)(wb + (q >> 1) * 1280 + n15 * 80 + qp * 16) = pk4;
    }
    // phase 3
    f32x4 msg = (f32x4){0.f, 0.f, 0.f, 0.f};
#pragma unroll
    for (int ks = 0; ks < 2; ++ks) {
      bf16x8 mF = *(const bf16x8*)(wb + ks * 1280 + n15 * 80 + q * 16);
      msg = __builtin_amdgcn_mfma_f32_16x16x32_bf16(w2F[ks], mF, msg, 0, 0, 0);
    }
    float aw = alLf[ii * 33 + jh * 16 + n15];
#pragma unroll
    for (int reg = 0; reg < 4; ++reg)
      agg[reg] = fmaf(aw, msg[reg] + b2v[reg], agg[reg]);
  }
  // park agg in own wave buffer
  {
    f32x4 av; av[0] = agg[0]; av[1] = agg[1]; av[2] = agg[2]; av[3] = agg[3];
    *(f32x4*)(wb + n15 * 80 + q * 16) = av;
  }
  __syncthreads();
  // combine wave pairs (i-low + i-high) and add q head
#pragma unroll
  for (int tt = 0; tt < 2; ++tt) {
    int idx = t + 256 * tt;
    int jg = idx >> 4, nn = idx & 15;
    int jh2 = jg >> 4, jl = jg & 15;
    float a0 = *(const float*)(smem + MT_OFF + jh2 * 2560 + jl * 80 + nn * 4);
    float a1 = *(const float*)(smem + MT_OFF + (jh2 + 2) * 2560 + jl * 80 + nn * 4);
    out[(size_t)b * 512 + idx] = a0 + a1 + qT[(size_t)nn * NROW + b32 + jg];
  }
}

}  // namespace

extern "C" void kernel_launch(void* const* d_in, const int* in_sizes, int n_in,
                              void* d_out, int out_size, void* d_ws, size_t ws_size,
                              hipStream_t stream) {
  (void)in_sizes; (void)n_in; (void)out_size; (void)ws_size;
  const float* inputs = (const float*)d_in[0];
  const float* hidden = (const float*)d_in[1];
  const float* eps    = (const float*)d_in[2];
  const float* fc1w   = (const float*)d_in[3];
  const float* fc1b   = (const float*)d_in[4];
  const float* wih    = (const float*)d_in[5];
  const float* whh    = (const float*)d_in[6];
  const float* bih    = (const float*)d_in[7];
  const float* bhh    = (const float*)d_in[8];
  const float* fc2w   = (const float*)d_in[9];
  const float* fc2b   = (const float*)d_in[10];
  const float* ew1    = (const float*)d_in[11];
  const float* eb1    = (const float*)d_in[12];
  const float* bng    = (const float*)d_in[13];
  const float* bnb    = (const float*)d_in[14];
  const float* ew2    = (const float*)d_in[15];
  const float* eb2    = (const float*)d_in[16];
  const float* w1     = (const float*)d_in[17];
  const float* b1     = (const float*)d_in[18];
  const float* w2     = (const float*)d_in[19];
  const float* b2     = (const float*)d_in[20];
  const float* wqw    = (const float*)d_in[21];
  const float* wkw    = (const float*)d_in[23];

  float* ws = (float*)d_ws;
  float* hT     = ws;                 // 2097152
  float* qT     = ws + 2097152;       // 524288
  float* qkT    = ws + 2621440;       // 524288
  float* z1T    = ws + 3670016;       // 2097152
  float* part   = ws + 5767168;       // 32768 used
  float* stat   = ws + 5832704;       // 128
  unsigned* latB16g = (unsigned*)(ws + 5832832);  // [N][256] u32 (bf16 pairs)

  float* out_q = (float*)d_out;             // 32768 x 16
  float* out_h = (float*)d_out + 524288;    // 32768 x 64

  hipLaunchKernelGGL(k_fgru, dim3(256), dim3(512), 0, stream,
                     inputs, hidden, fc1w, fc1b, wih, whh, bih, bhh, hT, out_h);
  hipLaunchKernelGGL(k_heads, dim3(256), dim3(256), 0, stream,
                     hT, fc2w, fc2b, wqw, wkw, ew1, eb1, qT, qkT, z1T, part);
  hipLaunchKernelGGL(k_bnstat, dim3(1), dim3(64), 0, stream, part, bng, bnb, stat);
  hipLaunchKernelGGL(k_emb_gemm, dim3(2048), dim3(256), 0, stream, z1T, stat, ew2, eb2, eps, latB16g);
  hipLaunchKernelGGL(k_msg, dim3(1024), dim3(256), 0, stream,
                     latB16g, qkT, qT, out_h, w1, b1, w2, b2, out_q);
}

// Round 11
// 271.235 us; speedup vs baseline: 6.2243x; 1.0018x over previous
//
#include <hip/hip_runtime.h>
#include <math.h>

namespace {

constexpr int NROW = 32768;   // BS*A rows
constexpr int HDIM = 64;
constexpr int DH   = 512;     // latent half-dim

typedef __attribute__((ext_vector_type(8))) short bf16x8;
typedef __attribute__((ext_vector_type(4))) float f32x4;
typedef __attribute__((ext_vector_type(4))) unsigned uint4e;
typedef __attribute__((ext_vector_type(2))) unsigned uint2e;

__device__ __forceinline__ float sigmoidf_(float x) { return 1.f / (1.f + __expf(-x)); }
__device__ __forceinline__ float lrelu_(float x) { return x > 0.f ? x : 0.01f * x; }
__device__ __forceinline__ unsigned f2bf(float x) {  // RNE float->bf16 (as low 16 bits)
  unsigned u = __float_as_uint(x);
  return (u + 0x7fffu + ((u >> 16) & 1u)) >> 16;
}
// fast pack: round-half-up bf16 pair (a -> low16, b -> high16)
__device__ __forceinline__ unsigned pkbf(float a, float b) {
  unsigned ua = __float_as_uint(a) + 0x8000u;
  unsigned ub = __float_as_uint(b) + 0x8000u;
  return __builtin_amdgcn_perm(ub, ua, 0x07060302);
}

// K1+K2 fused (v2): 512 threads, 8 waves x 16 rows; A/B frags packed in-register
// from global fp32 (no inU/f1U/hU staging). LDS = xU + gU = 73.7 KB -> 2 blocks/CU.
__global__ __launch_bounds__(512, 1) void k_fgru(
    const float* __restrict__ in,      // [N][96]
    const float* __restrict__ hprev,   // [N][64]
    const float* __restrict__ fc1w, const float* __restrict__ fc1b,
    const float* __restrict__ wih, const float* __restrict__ whh,
    const float* __restrict__ bih, const float* __restrict__ bhh,
    float* __restrict__ hT, float* __restrict__ hout) {
  __shared__ char smem[73728];
  const int t = threadIdx.x;
  const int n0 = blockIdx.x * 128;
  short*    xS = (short*)smem;                 // [128][72] shorts (18432 B)
  unsigned* gU = (unsigned*)(smem + 18432);    // [6][64][36] (55296 B)
  float*    trF = (float*)(smem + 18432);      // [64][133] f32, overlays gU after GRU

  // stage gate weights (bf16)
  const float2* wih2 = (const float2*)wih;
  const float2* whh2 = (const float2*)whh;
#pragma unroll 1
  for (int i = 0; i < 12; ++i) {
    int idx = t + 512 * i;               // 6144
    int row = idx >> 5, kp = idx & 31;
    float2 v = wih2[row * 32 + kp];
    int gate = row >> 6, cl = row & 63;
    gU[(gate * 64 + cl) * 36 + kp] = pkbf(v.x, v.y);
  }
#pragma unroll 1
  for (int i = 0; i < 12; ++i) {
    int idx = t + 512 * i;
    int row = idx >> 5, kp = idx & 31;
    float2 v = whh2[row * 32 + kp];
    int gate = row >> 6, cl = row & 63;
    gU[((gate + 3) * 64 + cl) * 36 + kp] = pkbf(v.x, v.y);
  }

  const int w = t >> 6, l = t & 63;
  const int m = l & 15, g = l >> 4;
  const int rowA = n0 + w * 16 + m;      // A-operand row for this lane

  // ---- fc1 phase: A frags direct from inputs (fp32 -> bf16) ----
  bf16x8 af[3];
#pragma unroll
  for (int ks = 0; ks < 3; ++ks) {
    const float4* p = (const float4*)(in + (size_t)rowA * 96 + ks * 32 + g * 8);
    float4 a = p[0], b = p[1];
    union { unsigned u[4]; bf16x8 h; } tw;
    tw.u[0] = pkbf(a.x, a.y); tw.u[1] = pkbf(a.z, a.w);
    tw.u[2] = pkbf(b.x, b.y); tw.u[3] = pkbf(b.z, b.w);
    af[ks] = tw.h;
  }
  {
    f32x4 accx[4];
#pragma unroll
    for (int ct = 0; ct < 4; ++ct) accx[ct] = (f32x4){0.f, 0.f, 0.f, 0.f};
#pragma unroll
    for (int ct = 0; ct < 4; ++ct)
#pragma unroll
      for (int ks = 0; ks < 3; ++ks) {
        const float4* p = (const float4*)(fc1w + (ct * 16 + m) * 96 + ks * 32 + g * 8);
        float4 a = p[0], b = p[1];
        union { unsigned u[4]; bf16x8 h; } tw;
        tw.u[0] = pkbf(a.x, a.y); tw.u[1] = pkbf(a.z, a.w);
        tw.u[2] = pkbf(b.x, b.y); tw.u[3] = pkbf(b.z, b.w);
        accx[ct] = __builtin_amdgcn_mfma_f32_16x16x32_bf16(af[ks], tw.h, accx[ct], 0, 0, 0);
      }
#pragma unroll
    for (int ct = 0; ct < 4; ++ct) {
      int c = ct * 16 + m;
      float bc = fc1b[c];
#pragma unroll
      for (int reg = 0; reg < 4; ++reg) {
        int nl = w * 16 + g * 4 + reg;
        float v = fmaxf(accx[ct][reg] + bc, 0.f);
        xS[nl * 72 + c] = (short)((__float_as_uint(v) + 0x8000u) >> 16);
      }
    }
  }
  __syncthreads();   // xS ready + gU ready

  // ---- GRU phase ----
  bf16x8 ax[2], ah[2];
#pragma unroll
  for (int ks = 0; ks < 2; ++ks) {
    ax[ks] = *(const bf16x8*)(xS + (w * 16 + m) * 72 + ks * 32 + g * 8);
    const float4* p = (const float4*)(hprev + (size_t)rowA * 64 + ks * 32 + g * 8);
    float4 a = p[0], b = p[1];
    union { unsigned u[4]; bf16x8 h; } tw;
    tw.u[0] = pkbf(a.x, a.y); tw.u[1] = pkbf(a.z, a.w);
    tw.u[2] = pkbf(b.x, b.y); tw.u[3] = pkbf(b.z, b.w);
    ah[ks] = tw.h;
  }
  const short* gS = (const short*)gU;
  float hc[4][4];
#pragma unroll 1
  for (int ct = 0; ct < 4; ++ct) {
    f32x4 a_ir = (f32x4){0.f,0.f,0.f,0.f}, a_iz = (f32x4){0.f,0.f,0.f,0.f},
          a_in = (f32x4){0.f,0.f,0.f,0.f}, a_hr = (f32x4){0.f,0.f,0.f,0.f},
          a_hz = (f32x4){0.f,0.f,0.f,0.f}, a_hn = (f32x4){0.f,0.f,0.f,0.f};
    int crow = ct * 16 + m;
#pragma unroll
    for (int ks = 0; ks < 2; ++ks) {
      bf16x8 b0 = *(const bf16x8*)(gS + (0 * 64 + crow) * 72 + ks * 32 + g * 8);
      bf16x8 b1 = *(const bf16x8*)(gS + (1 * 64 + crow) * 72 + ks * 32 + g * 8);
      bf16x8 b2 = *(const bf16x8*)(gS + (2 * 64 + crow) * 72 + ks * 32 + g * 8);
      bf16x8 b3 = *(const bf16x8*)(gS + (3 * 64 + crow) * 72 + ks * 32 + g * 8);
      bf16x8 b4 = *(const bf16x8*)(gS + (4 * 64 + crow) * 72 + ks * 32 + g * 8);
      bf16x8 b5 = *(const bf16x8*)(gS + (5 * 64 + crow) * 72 + ks * 32 + g * 8);
      a_ir = __builtin_amdgcn_mfma_f32_16x16x32_bf16(ax[ks], b0, a_ir, 0, 0, 0);
      a_iz = __builtin_amdgcn_mfma_f32_16x16x32_bf16(ax[ks], b1, a_iz, 0, 0, 0);
      a_in = __builtin_amdgcn_mfma_f32_16x16x32_bf16(ax[ks], b2, a_in, 0, 0, 0);
      a_hr = __builtin_amdgcn_mfma_f32_16x16x32_bf16(ah[ks], b3, a_hr, 0, 0, 0);
      a_hz = __builtin_amdgcn_mfma_f32_16x16x32_bf16(ah[ks], b4, a_hz, 0, 0, 0);
      a_hn = __builtin_amdgcn_mfma_f32_16x16x32_bf16(ah[ks], b5, a_hn, 0, 0, 0);
    }
    float bir = bih[crow], biz = bih[64 + crow], bin = bih[128 + crow];
    float bhr = bhh[crow], bhz = bhh[64 + crow], bhn = bhh[128 + crow];
#pragma unroll
    for (int reg = 0; reg < 4; ++reg) {
      int nl = w * 16 + g * 4 + reg;
      float hv = hprev[(size_t)(n0 + nl) * 64 + crow];
      float r  = sigmoidf_(a_ir[reg] + bir + a_hr[reg] + bhr);
      float z  = sigmoidf_(a_iz[reg] + biz + a_hz[reg] + bhz);
      float nn = tanhf(a_in[reg] + bin + r * (a_hn[reg] + bhn));
      hc[ct][reg] = (1.f - z) * nn + z * hv;
    }
  }
  __syncthreads();   // all waves done reading gU before trF overlay
#pragma unroll
  for (int ct = 0; ct < 4; ++ct)
#pragma unroll
    for (int reg = 0; reg < 4; ++reg)
      trF[(ct * 16 + m) * 133 + w * 16 + g * 4 + reg] = hc[ct][reg];
  __syncthreads();
#pragma unroll 1
  for (int i = 0; i < 16; ++i) {
    int idx = t + 512 * i;
    int nl = idx & 127, cl = idx >> 7;
    hT[(size_t)cl * NROW + n0 + nl] = trF[cl * 133 + nl];
  }
#pragma unroll 1
  for (int i = 0; i < 16; ++i) {
    int idx = t + 512 * i;
    int c = idx & 63, nl = idx >> 6;
    hout[(size_t)(n0 + nl) * 64 + c] = trF[c * 133 + nl];
  }
}

// K3 (MFMA): 96-channel fused head GEMM (fc2 16 + qk 16 + ew1 64), K=64.
__global__ __launch_bounds__(256) void k_heads(const float* __restrict__ hT,
    const float* __restrict__ fc2w, const float* __restrict__ fc2b,
    const float* __restrict__ wqw, const float* __restrict__ wkw,
    const float* __restrict__ ew1, const float* __restrict__ eb1,
    float* __restrict__ qT, float* __restrict__ qkT, float* __restrict__ z1T,
    float* __restrict__ part) {
  __shared__ char smem[36864];
  const int t = threadIdx.x;
  const int n0 = blockIdx.x * 128;
  unsigned* hU = (unsigned*)smem;                 // [128][36]
  unsigned* wU = (unsigned*)(smem + 18432);       // [96][36]
  float* sp1 = (float*)(smem + 18432 + 13824);    // [4][64]
  float* sp2 = sp1 + 256;                         // [4][64]
  const float qs = 0.17677669529663687f;          // 1/sqrt(32)

#pragma unroll 1
  for (int i = 0; i < 16; ++i) {
    int idx = t + 256 * i;
    int nl = idx & 127, kp = idx >> 7;
    float v0 = hT[(size_t)(2 * kp) * NROW + n0 + nl];
    float v1 = hT[(size_t)(2 * kp + 1) * NROW + n0 + nl];
    hU[nl * 36 + kp] = pkbf(v0, v1);
  }
#pragma unroll 1
  for (int i = 0; i < 12; ++i) {
    int idx = t + 256 * i;          // 0..3071
    int kp = idx & 31, cl = idx >> 5;   // cl 0..95
    unsigned val;
    if (cl < 16) {
      float2 v = *(const float2*)(fc2w + cl * 64 + 2 * kp);
      val = pkbf(v.x, v.y);
    } else if (cl < 32) {
      int ll = cl - 16;
      float s0 = 0.f, s1 = 0.f;
#pragma unroll 1
      for (int a = 0; a < 32; ++a) {
        float wk = wkw[a * 16 + ll];
        s0 = fmaf(wk, wqw[a * 64 + 2 * kp], s0);
        s1 = fmaf(wk, wqw[a * 64 + 2 * kp + 1], s1);
      }
      val = pkbf(s0 * qs, s1 * qs);
    } else {
      float2 v = *(const float2*)(ew1 + (cl - 32) * 64 + 2 * kp);
      val = pkbf(v.x, v.y);
    }
    wU[cl * 36 + kp] = val;
  }
  __syncthreads();

  const int w = t >> 6, l = t & 63;
  const int m = l & 15, g = l >> 4;
  const short* sH = (const short*)hU;
  const short* sW = (const short*)wU;

  bf16x8 af[2][2];
#pragma unroll
  for (int mt = 0; mt < 2; ++mt)
#pragma unroll
    for (int ks = 0; ks < 2; ++ks)
      af[mt][ks] = *(const bf16x8*)(sH + (w * 32 + mt * 16 + m) * 72 + ks * 32 + g * 8);

  f32x4 acc[2][6];
#pragma unroll
  for (int mt = 0; mt < 2; ++mt)
#pragma unroll
    for (int ct = 0; ct < 6; ++ct) acc[mt][ct] = (f32x4){0.f, 0.f, 0.f, 0.f};
#pragma unroll
  for (int ct = 0; ct < 6; ++ct)
#pragma unroll
    for (int ks = 0; ks < 2; ++ks) {
      bf16x8 bw = *(const bf16x8*)(sW + (ct * 16 + m) * 72 + ks * 32 + g * 8);
#pragma unroll
      for (int mt = 0; mt < 2; ++mt)
        acc[mt][ct] = __builtin_amdgcn_mfma_f32_16x16x32_bf16(af[mt][ks], bw, acc[mt][ct], 0, 0, 0);
    }

  float s1[4], s2[4];
#pragma unroll
  for (int zt = 0; zt < 4; ++zt) { s1[zt] = 0.f; s2[zt] = 0.f; }
#pragma unroll
  for (int mt = 0; mt < 2; ++mt) {
    int nb = n0 + w * 32 + mt * 16 + g * 4;
    {  // q head: c = m
      float bc = fc2b[m];
      f32x4 v;
#pragma unroll
      for (int reg = 0; reg < 4; ++reg) v[reg] = acc[mt][0][reg] + bc;
      *(f32x4*)(qT + (size_t)m * NROW + nb) = v;
    }
    // qk head: l' = m, no bias
    *(f32x4*)(qkT + (size_t)m * NROW + nb) = acc[mt][1];
#pragma unroll
    for (int ct = 2; ct < 6; ++ct) {  // z1 head: z = (ct-2)*16 + m
      int z = (ct - 2) * 16 + m;
      float bc = eb1[z];
      f32x4 v;
#pragma unroll
      for (int reg = 0; reg < 4; ++reg) {
        float zv = acc[mt][ct][reg] + bc;
        v[reg] = zv;
        s1[ct - 2] += zv;
        s2[ct - 2] = fmaf(zv, zv, s2[ct - 2]);
      }
      *(f32x4*)(z1T + (size_t)z * NROW + nb) = v;
    }
  }
#pragma unroll
  for (int zt = 0; zt < 4; ++zt) {
    s1[zt] += __shfl_down(s1[zt], 16, 64);
    s1[zt] += __shfl_down(s1[zt], 32, 64);
    s2[zt] += __shfl_down(s2[zt], 16, 64);
    s2[zt] += __shfl_down(s2[zt], 32, 64);
  }
  if (l < 16) {
#pragma unroll
    for (int zt = 0; zt < 4; ++zt) {
      sp1[w * 64 + zt * 16 + m] = s1[zt];
      sp2[w * 64 + zt * 16 + m] = s2[zt];
    }
  }
  __syncthreads();
  if (t < 64) {
    float a1 = sp1[t] + sp1[64 + t] + sp1[128 + t] + sp1[192 + t];
    float a2 = sp2[t] + sp2[64 + t] + sp2[128 + t] + sp2[192 + t];
    part[(size_t)blockIdx.x * 128 + t] = a1;
    part[(size_t)blockIdx.x * 128 + 64 + t] = a2;
  }
}

// K4: finalize BN stats (256 head blocks)
__global__ void k_bnstat(const float* __restrict__ part,
    const float* __restrict__ bng, const float* __restrict__ bnb,
    float* __restrict__ stat) {
  int c = threadIdx.x;  // 64 threads
  float s1 = 0.f, s2 = 0.f;
  for (int b = 0; b < 256; ++b) {
    s1 += part[(size_t)b * 128 + c];
    s2 += part[(size_t)b * 128 + 64 + c];
  }
  float mean = s1 * (1.f / NROW);
  float var = s2 * (1.f / NROW) - mean * mean;
  float rstd = rsqrtf(var + 1e-5f);
  float sc = bng[c] * rstd;
  stat[c] = sc;
  stat[64 + c] = bnb[c] - mean * sc;
}

// K5 (v4): MFMA bf16 GEMM -> bf16 latent.
// eps prefetched into registers BEFORE the staging barrier (latency hidden under
// the same wait); f32 LDS transpose + coalesced u32 pkbf stores (round-8 path);
// std = max(exp(0.5*lv), sqrt(0.002)).
__global__ __launch_bounds__(256) void k_emb_gemm(const float* __restrict__ z1T,
    const float* __restrict__ stat,
    const float* __restrict__ ew2, const float* __restrict__ eb2,
    const float* __restrict__ eps,
    unsigned* __restrict__ latB16g) {
  __shared__ char smem[36864];
  const int t = threadIdx.x;
  const int nb = blockIdx.x >> 3;
  const int cb = blockIdx.x & 7;
  const int n0 = nb * 128;
  const int c0 = cb * 64;

  unsigned* aU = (unsigned*)smem;                 // A: [128][36]
  unsigned* bmU = (unsigned*)(smem + 18432);      // Wmu: [64][36]
  unsigned* blU = (unsigned*)(smem + 27648);      // Wlv: [64][36]

  const int w = t >> 6, l = t & 63;
  const int m = l & 15, g = l >> 4;

#pragma unroll 1
  for (int i = 0; i < 16; ++i) {
    int idx = t + 256 * i;
    int nl = idx & 127;
    int kp = idx >> 7;
    float v0 = z1T[(size_t)(2 * kp) * NROW + n0 + nl];
    float v1 = z1T[(size_t)(2 * kp + 1) * NROW + n0 + nl];
    v0 = lrelu_(fmaf(stat[2 * kp], v0, stat[64 + 2 * kp]));
    v1 = lrelu_(fmaf(stat[2 * kp + 1], v1, stat[64 + 2 * kp + 1]));
    aU[nl * 36 + kp] = pkbf(v0, v1);
  }
  const float2* ew2_2 = (const float2*)ew2;
#pragma unroll 1
  for (int i = 0; i < 8; ++i) {
    int idx = t + 256 * i;
    int kp = idx & 31;
    int cl = idx >> 5;
    float2 m2 = ew2_2[(size_t)(c0 + cl) * 32 + kp];
    float2 l2 = ew2_2[(size_t)(512 + c0 + cl) * 32 + kp];
    bmU[cl * 36 + kp] = pkbf(m2.x, m2.y);
    blU[cl * 36 + kp] = pkbf(l2.x, l2.y);
  }
  // eps prefetch: 32 dwords/lane in C-layout (issued before barrier; latency
  // overlaps the staging drain). 16-lane groups read 64B contiguous segments.
  float epsR[4][2][4];
#pragma unroll
  for (int ct = 0; ct < 4; ++ct)
#pragma unroll
    for (int mt = 0; mt < 2; ++mt)
#pragma unroll
      for (int reg = 0; reg < 4; ++reg)
        epsR[ct][mt][reg] =
            eps[(size_t)(n0 + w * 32 + mt * 16 + g * 4 + reg) * 512 + c0 + ct * 16 + m];
  __syncthreads();

  const short* sA = (const short*)smem;
  const short* sBm = (const short*)(smem + 18432);
  const short* sBl = (const short*)(smem + 27648);

  f32x4 accm[2][4], accl[2][4];
#pragma unroll
  for (int mt = 0; mt < 2; ++mt)
#pragma unroll
    for (int ct = 0; ct < 4; ++ct) {
      accm[mt][ct] = (f32x4){0.f, 0.f, 0.f, 0.f};
      accl[mt][ct] = (f32x4){0.f, 0.f, 0.f, 0.f};
    }
  bf16x8 af[2][2];
#pragma unroll
  for (int mt = 0; mt < 2; ++mt)
#pragma unroll
    for (int ks = 0; ks < 2; ++ks)
      af[mt][ks] = *(const bf16x8*)(sA + (w * 32 + mt * 16 + m) * 72 + ks * 32 + g * 8);
#pragma unroll
  for (int ct = 0; ct < 4; ++ct) {
#pragma unroll
    for (int ks = 0; ks < 2; ++ks) {
      bf16x8 bm = *(const bf16x8*)(sBm + (ct * 16 + m) * 72 + ks * 32 + g * 8);
      bf16x8 bl = *(const bf16x8*)(sBl + (ct * 16 + m) * 72 + ks * 32 + g * 8);
#pragma unroll
      for (int mt = 0; mt < 2; ++mt) {
        accm[mt][ct] = __builtin_amdgcn_mfma_f32_16x16x32_bf16(af[mt][ks], bm, accm[mt][ct], 0, 0, 0);
        accl[mt][ct] = __builtin_amdgcn_mfma_f32_16x16x32_bf16(af[mt][ks], bl, accl[mt][ct], 0, 0, 0);
      }
    }
  }

  // epilogue: lat in regs, f32 transpose through LDS, coalesced u32 stores
  const float stdfloor = 0.04472135955f;   // sqrt(0.002)
  float lat[2][4][4];
#pragma unroll
  for (int ct = 0; ct < 4; ++ct) {
    int cl = ct * 16 + m;
    float ebm = eb2[c0 + cl], ebl = eb2[DH + c0 + cl];
#pragma unroll
    for (int mt = 0; mt < 2; ++mt)
#pragma unroll
      for (int reg = 0; reg < 4; ++reg) {
        float mu = accm[mt][ct][reg] + ebm;
        float lv = accl[mt][ct][reg] + ebl;
        float sd = fmaxf(__expf(0.5f * lv), stdfloor);
        lat[mt][ct][reg] = fmaf(sd, epsR[ct][mt][reg], mu);
      }
  }
  __syncthreads();
  float* outF = (float*)smem;     // [64][133]
#pragma unroll
  for (int mt = 0; mt < 2; ++mt)
#pragma unroll
    for (int ct = 0; ct < 4; ++ct)
#pragma unroll
      for (int reg = 0; reg < 4; ++reg)
        outF[(ct * 16 + m) * 133 + w * 32 + mt * 16 + g * 4 + reg] = lat[mt][ct][reg];
  __syncthreads();
#pragma unroll 1
  for (int i = 0; i < 16; ++i) {
    int idx = t + 256 * i;          // 0..4095
    int cp = idx & 31;
    int nl = idx >> 5;
    float v0 = outF[(2 * cp) * 133 + nl];
    float v1 = outF[(2 * cp + 1) * 133 + nl];
    latB16g[(size_t)(n0 + nl) * 256 + cb * 32 + cp] = pkbf(v0, v1);
  }
}

// K7 (MFMA): one block per b. Logit+softmax in-kernel from bf16 latent.
constexpr int LATB_OFF = 0;        // [1024][20] bf16, 40B rows (r = i*32+j)
constexpr int H3B_OFF  = 40960;    // [32][72] bf16, 144B rows
constexpr int W1H_OFF  = 45568;    // [64][72] bf16
constexpr int W1L_OFF  = 54784;    // [64][20] bf16
constexpr int W2P_OFF  = 57344;    // [16][72] bf16 (pi-permuted c)
constexpr int ALL_OFF  = 59648;    // [32][33] f32 alpha
constexpr int MT_OFF   = 63872;    // 4 waves x 2560B private transpose buf
constexpr int QKL_OFF  = 74112;    // [32][20] f32 qk
__global__ __launch_bounds__(256, 1) void k_msg(
    const unsigned* __restrict__ latB16g, const float* __restrict__ qkT,
    const float* __restrict__ qT, const float* __restrict__ hrow,
    const float* __restrict__ w1, const float* __restrict__ b1,
    const float* __restrict__ w2, const float* __restrict__ b2,
    float* __restrict__ out) {
  __shared__ char smem[76672];
  const int t = threadIdx.x;
  const int b = blockIdx.x;
  const int b32 = b * 32;
  unsigned* latB_dw = (unsigned*)(smem + LATB_OFF);

  // ---- staging ----
  {  // latB: straight bf16 copy from latB16g (contiguous 16B segments)
    const uint4e* g4 = (const uint4e*)latB16g + (size_t)b32 * 64;
#pragma unroll 1
    for (int it = 0; it < 8; ++it) {
      int idx = t + 256 * it;          // 0..2047
      uint4e v = g4[idx];
      int i = idx >> 6;
      int rem = idx & 63;
      int j = rem >> 1, half = rem & 1;
      unsigned* dst = latB_dw + (i * 32 + j) * 10 + half * 4;
      *(uint2e*)dst = (uint2e){v.x, v.y};
      *(uint2e*)(dst + 2) = (uint2e){v.z, v.w};
    }
  }
  {  // qkL[i][l] from qkT
    float* qkL = (float*)(smem + QKL_OFF);
    int i = t & 31;
#pragma unroll
    for (int it = 0; it < 2; ++it) {
      int ll = (t >> 5) + 8 * it;
      qkL[i * 20 + ll] = qkT[(size_t)ll * NROW + b32 + i];
    }
  }
  {  // h3B[j][k] bf16 from row-major h (d_out region)
    int cp = t & 31, jj = t >> 5;
    const float2* h2 = (const float2*)hrow;
    unsigned* dst = (unsigned*)(smem + H3B_OFF);
#pragma unroll 1
    for (int it = 0; it < 4; ++it) {
      int j = jj + 8 * it;
      float2 hv = h2[((size_t)(b32 + j) * 64 + 2 * cp) >> 1];
      dst[j * 36 + cp] = pkbf(hv.x, hv.y);
    }
  }
  {  // w1hL[c][k] (k<64)
    int kp = t & 31, cc = t >> 5;
    const float2* w12 = (const float2*)w1;
    unsigned* dst = (unsigned*)(smem + W1H_OFF);
#pragma unroll 1
    for (int it = 0; it < 8; ++it) {
      int c = cc + 8 * it;
      float2 wv = w12[(c * 80 + 2 * kp) >> 1];
      dst[c * 36 + kp] = pkbf(wv.x, wv.y);
    }
  }
  {  // w1latL[c][l]
    int lp = t & 7, cc = t >> 3;
    const float2* w12 = (const float2*)w1;
    unsigned* dst = (unsigned*)(smem + W1L_OFF);
#pragma unroll 1
    for (int it = 0; it < 2; ++it) {
      int c = cc + 32 * it;
      float2 wv = w12[(c * 80 + 64 + 2 * lp) >> 1];
      dst[c * 10 + lp] = pkbf(wv.x, wv.y);
    }
  }
  {  // w2P[nn][p] = w2[nn][c(p)], c(p) = ((p>>2)&3)*16 + (p>>4)*4 + (p&3)
    int pp = t & 31, nn = t >> 5;
    const float2* w22 = (const float2*)w2;
    unsigned* dst = (unsigned*)(smem + W2P_OFF);
#pragma unroll 1
    for (int it = 0; it < 2; ++it) {
      int n2 = nn + 8 * it;
      int p = 2 * pp;
      int c = ((p >> 2) & 3) * 16 + (p >> 4) * 4 + (p & 3);
      float2 wv = w22[(n2 * 64 + c) >> 1];
      dst[n2 * 36 + pp] = pkbf(wv.x, wv.y);
    }
  }
  __syncthreads();

  // ---- logits + softmax -> alL (reads latB + qkL) ----
  {
    const float* qkL = (const float*)(smem + QKL_OFF);
    float* alL = (float*)(smem + ALL_OFF);
#pragma unroll 1
    for (int p = 0; p < 4; ++p) {
      int i = (t >> 5) + 8 * p;
      int j = t & 31;
      const unsigned* lr = latB_dw + (i * 32 + j) * 10;
      float acc = 0.f;
#pragma unroll
      for (int d = 0; d < 8; ++d) {
        unsigned u = lr[d];
        float lo = __uint_as_float(u << 16);
        float hi = __uint_as_float(u & 0xffff0000u);
        acc = fmaf(lo, qkL[i * 20 + 2 * d], acc);
        acc = fmaf(hi, qkL[i * 20 + 2 * d + 1], acc);
      }
      if (j == i) acc = -1e9f;
      float mx = acc;
#pragma unroll
      for (int msk = 16; msk > 0; msk >>= 1) mx = fmaxf(mx, __shfl_xor(mx, msk, 32));
      float e = __expf(acc - mx);
      float s = e;
#pragma unroll
      for (int msk = 16; msk > 0; msk >>= 1) s += __shfl_xor(s, msk, 32);
      alL[i * 33 + j] = e / s;
    }
  }

  const int w = t >> 6, l = t & 63;
  const int n15 = l & 15, q = l >> 4;
  const int jh = w & 1, ibase = (w >> 1) * 16;
  const bool kact = (q < 2);

  // ---- phase 1: hp[ct][reg] for (c = ct*16+q*4+reg, j = jh*16+n15) ----
  f32x4 hp[4];
#pragma unroll
  for (int ct = 0; ct < 4; ++ct) hp[ct] = (f32x4){0.f, 0.f, 0.f, 0.f};
#pragma unroll
  for (int ct = 0; ct < 4; ++ct)
#pragma unroll
    for (int ks = 0; ks < 2; ++ks) {
      bf16x8 aF = *(const bf16x8*)(smem + W1H_OFF + (ct * 16 + n15) * 144 + ks * 64 + q * 16);
      bf16x8 bF = *(const bf16x8*)(smem + H3B_OFF + (jh * 16 + n15) * 144 + ks * 64 + q * 16);
      hp[ct] = __builtin_amdgcn_mfma_f32_16x16x32_bf16(aF, bF, hp[ct], 0, 0, 0);
    }
#pragma unroll
  for (int ct = 0; ct < 4; ++ct)
#pragma unroll
    for (int reg = 0; reg < 4; ++reg)
      hp[ct][reg] += b1[ct * 16 + q * 4 + reg];

  // hoisted fragments
  bf16x8 aL[4];
#pragma unroll
  for (int ct = 0; ct < 4; ++ct) {
    union { unsigned u[4]; bf16x8 h; } tmp;
    tmp.u[0] = tmp.u[1] = tmp.u[2] = tmp.u[3] = 0u;
    if (kact) {
      const unsigned* p = (const unsigned*)(smem + W1L_OFF) + (ct * 16 + n15) * 10 + q * 4;
      uint2e d0 = *(const uint2e*)p;
      uint2e d1 = *(const uint2e*)(p + 2);
      tmp.u[0] = d0.x; tmp.u[1] = d0.y; tmp.u[2] = d1.x; tmp.u[3] = d1.y;
    }
    aL[ct] = tmp.h;
  }
  bf16x8 w2F[2];
#pragma unroll
  for (int ks = 0; ks < 2; ++ks)
    w2F[ks] = *(const bf16x8*)(smem + W2P_OFF + n15 * 144 + ks * 64 + q * 16);
  float b2v[4];
#pragma unroll
  for (int reg = 0; reg < 4; ++reg) b2v[reg] = b2[q * 4 + reg];

  __syncthreads();  // alL complete before main loop reads it

  // ---- main i loop ----
  float agg[4] = {0.f, 0.f, 0.f, 0.f};
  char* wb = smem + MT_OFF + w * 2560;
  const float* alLf = (const float*)(smem + ALL_OFF);
#pragma unroll 1
  for (int it = 0; it < 16; ++it) {
    int ii = ibase + it;
    int r = ii * 32 + jh * 16 + n15;
    union { unsigned u[4]; bf16x8 h; } latF;
    latF.u[0] = latF.u[1] = latF.u[2] = latF.u[3] = 0u;
    if (kact) {
      const unsigned* p = latB_dw + r * 10 + q * 4;
      uint2e d0 = *(const uint2e*)p;
      uint2e d1 = *(const uint2e*)(p + 2);
      latF.u[0] = d0.x; latF.u[1] = d0.y; latF.u[2] = d1.x; latF.u[3] = d1.y;
    }
    f32x4 acc[4];
#pragma unroll
    for (int ct = 0; ct < 4; ++ct) {
      acc[ct] = (f32x4){0.f, 0.f, 0.f, 0.f};
      acc[ct] = __builtin_amdgcn_mfma_f32_16x16x32_bf16(aL[ct], latF.h, acc[ct], 0, 0, 0);
    }
    // lrelu + pack + pi-transpose write (per-wave private buffer, no barrier)
#pragma unroll
    for (int h = 0; h < 2; ++h) {
      float m0[4], m1[4];
#pragma unroll
      for (int reg = 0; reg < 4; ++reg) {
        float v0 = acc[2 * h][reg] + hp[2 * h][reg];
        float v1 = acc[2 * h + 1][reg] + hp[2 * h + 1][reg];
        m0[reg] = fmaxf(v0, 0.01f * v0);
        m1[reg] = fmaxf(v1, 0.01f * v1);
      }
      uint4e pk4;
      pk4.x = pkbf(m0[0], m0[1]); pk4.y = pkbf(m0[2], m0[3]);
      pk4.z = pkbf(m1[0], m1[1]); pk4.w = pkbf(m1[2], m1[3]);
      int qp = (2 * q + h) & 3;
      *(uint4e*)(wb + (q >> 1) * 1280 + n15 * 80 + qp * 16) = pk4;
    }
    // phase 3
    f32x4 msg = (f32x4){0.f, 0.f, 0.f, 0.f};
#pragma unroll
    for (int ks = 0; ks < 2; ++ks) {
      bf16x8 mF = *(const bf16x8*)(wb + ks * 1280 + n15 * 80 + q * 16);
      msg = __builtin_amdgcn_mfma_f32_16x16x32_bf16(w2F[ks], mF, msg, 0, 0, 0);
    }
    float aw = alLf[ii * 33 + jh * 16 + n15];
#pragma unroll
    for (int reg = 0; reg < 4; ++reg)
      agg[reg] = fmaf(aw, msg[reg] + b2v[reg], agg[reg]);
  }
  // park agg in own wave buffer
  {
    f32x4 av; av[0] = agg[0]; av[1] = agg[1]; av[2] = agg[2]; av[3] = agg[3];
    *(f32x4*)(wb + n15 * 80 + q * 16) = av;
  }
  __syncthreads();
  // combine wave pairs (i-low + i-high) and add q head
#pragma unroll
  for (int tt = 0; tt < 2; ++tt) {
    int idx = t + 256 * tt;
    int jg = idx >> 4, nn = idx & 15;
    int jh2 = jg >> 4, jl = jg & 15;
    float a0 = *(const float*)(smem + MT_OFF + jh2 * 2560 + jl * 80 + nn * 4);
    float a1 = *(const float*)(smem + MT_OFF + (jh2 + 2) * 2560 + jl * 80 + nn * 4);
    out[(size_t)b * 512 + idx] = a0 + a1 + qT[(size_t)nn * NROW + b32 + jg];
  }
}

}  // namespace

extern "C" void kernel_launch(void* const* d_in, const int* in_sizes, int n_in,
                              void* d_out, int out_size, void* d_ws, size_t ws_size,
                              hipStream_t stream) {
  (void)in_sizes; (void)n_in; (void)out_size; (void)ws_size;
  const float* inputs = (const float*)d_in[0];
  const float* hidden = (const float*)d_in[1];
  const float* eps    = (const float*)d_in[2];
  const float* fc1w   = (const float*)d_in[3];
  const float* fc1b   = (const float*)d_in[4];
  const float* wih    = (const float*)d_in[5];
  const float* whh    = (const float*)d_in[6];
  const float* bih    = (const float*)d_in[7];
  const float* bhh    = (const float*)d_in[8];
  const float* fc2w   = (const float*)d_in[9];
  const float* fc2b   = (const float*)d_in[10];
  const float* ew1    = (const float*)d_in[11];
  const float* eb1    = (const float*)d_in[12];
  const float* bng    = (const float*)d_in[13];
  const float* bnb    = (const float*)d_in[14];
  const float* ew2    = (const float*)d_in[15];
  const float* eb2    = (const float*)d_in[16];
  const float* w1     = (const float*)d_in[17];
  const float* b1     = (const float*)d_in[18];
  const float* w2     = (const float*)d_in[19];
  const float* b2     = (const float*)d_in[20];
  const float* wqw    = (const float*)d_in[21];
  const float* wkw    = (const float*)d_in[23];

  float* ws = (float*)d_ws;
  float* hT     = ws;                 // 2097152
  float* qT     = ws + 2097152;       // 524288
  float* qkT    = ws + 2621440;       // 524288
  float* z1T    = ws + 3670016;       // 2097152
  float* part   = ws + 5767168;       // 32768 used
  float* stat   = ws + 5832704;       // 128
  unsigned* latB16g = (unsigned*)(ws + 5832832);  // [N][256] u32 (bf16 pairs)

  float* out_q = (float*)d_out;             // 32768 x 16
  float* out_h = (float*)d_out + 524288;    // 32768 x 64

  hipLaunchKernelGGL(k_fgru, dim3(256), dim3(512), 0, stream,
                     inputs, hidden, fc1w, fc1b, wih, whh, bih, bhh, hT, out_h);
  hipLaunchKernelGGL(k_heads, dim3(256), dim3(256), 0, stream,
                     hT, fc2w, fc2b, wqw, wkw, ew1, eb1, qT, qkT, z1T, part);
  hipLaunchKernelGGL(k_bnstat, dim3(1), dim3(64), 0, stream, part, bng, bnb, stat);
  hipLaunchKernelGGL(k_emb_gemm, dim3(2048), dim3(256), 0, stream, z1T, stat, ew2, eb2, eps, latB16g);
  hipLaunchKernelGGL(k_msg, dim3(1024), dim3(256), 0, stream,
                     latB16g, qkT, qT, out_h, w1, b1, w2, b2, out_q);
}

// Round 12
// 260.118 us; speedup vs baseline: 6.4903x; 1.0427x over previous
//
#include <hip/hip_runtime.h>
#include <math.h>

namespace {

constexpr int NROW = 32768;   // BS*A rows
constexpr int HDIM = 64;
constexpr int DH   = 512;     // latent half-dim

typedef __attribute__((ext_vector_type(8))) short bf16x8;
typedef __attribute__((ext_vector_type(4))) float f32x4;
typedef __attribute__((ext_vector_type(4))) unsigned uint4e;
typedef __attribute__((ext_vector_type(2))) unsigned uint2e;

__device__ __forceinline__ float sigmoidf_(float x) { return 1.f / (1.f + __expf(-x)); }
__device__ __forceinline__ float lrelu_(float x) { return x > 0.f ? x : 0.01f * x; }
// fast pack: round-half-up bf16 pair (a -> low16, b -> high16)
__device__ __forceinline__ unsigned pkbf(float a, float b) {
  unsigned ua = __float_as_uint(a) + 0x8000u;
  unsigned ub = __float_as_uint(b) + 0x8000u;
  return __builtin_amdgcn_perm(ub, ua, 0x07060302);
}

// K1+K2 fused: 512 threads, 8 waves x 16 rows; staging loads batched (unrolled).
__global__ __launch_bounds__(512, 1) void k_fgru(
    const float* __restrict__ in,      // [N][96]
    const float* __restrict__ hprev,   // [N][64]
    const float* __restrict__ fc1w, const float* __restrict__ fc1b,
    const float* __restrict__ wih, const float* __restrict__ whh,
    const float* __restrict__ bih, const float* __restrict__ bhh,
    float* __restrict__ hT, float* __restrict__ hout) {
  __shared__ char smem[73728];
  const int t = threadIdx.x;
  const int n0 = blockIdx.x * 128;
  short*    xS = (short*)smem;                 // [128][72] shorts
  unsigned* gU = (unsigned*)(smem + 18432);    // [6][64][36]
  float*    trF = (float*)(smem + 18432);      // [64][133] f32, overlays gU after GRU

  const float2* wih2 = (const float2*)wih;
  const float2* whh2 = (const float2*)whh;
  {  // gate weight staging: batched loads, then packs
    float2 wv[12];
#pragma unroll
    for (int i = 0; i < 12; ++i) {
      int idx = t + 512 * i;
      int row = idx >> 5, kp = idx & 31;
      wv[i] = wih2[row * 32 + kp];
    }
#pragma unroll
    for (int i = 0; i < 12; ++i) {
      int idx = t + 512 * i;
      int row = idx >> 5, kp = idx & 31;
      int gate = row >> 6, cl = row & 63;
      gU[(gate * 64 + cl) * 36 + kp] = pkbf(wv[i].x, wv[i].y);
    }
#pragma unroll
    for (int i = 0; i < 12; ++i) {
      int idx = t + 512 * i;
      int row = idx >> 5, kp = idx & 31;
      wv[i] = whh2[row * 32 + kp];
    }
#pragma unroll
    for (int i = 0; i < 12; ++i) {
      int idx = t + 512 * i;
      int row = idx >> 5, kp = idx & 31;
      int gate = row >> 6, cl = row & 63;
      gU[((gate + 3) * 64 + cl) * 36 + kp] = pkbf(wv[i].x, wv[i].y);
    }
  }

  const int w = t >> 6, l = t & 63;
  const int m = l & 15, g = l >> 4;
  const int rowA = n0 + w * 16 + m;      // A-operand row for this lane

  // ---- fc1 phase ----
  bf16x8 af[3];
#pragma unroll
  for (int ks = 0; ks < 3; ++ks) {
    const float4* p = (const float4*)(in + (size_t)rowA * 96 + ks * 32 + g * 8);
    float4 a = p[0], b = p[1];
    union { unsigned u[4]; bf16x8 h; } tw;
    tw.u[0] = pkbf(a.x, a.y); tw.u[1] = pkbf(a.z, a.w);
    tw.u[2] = pkbf(b.x, b.y); tw.u[3] = pkbf(b.z, b.w);
    af[ks] = tw.h;
  }
  {
    f32x4 accx[4];
#pragma unroll
    for (int ct = 0; ct < 4; ++ct) accx[ct] = (f32x4){0.f, 0.f, 0.f, 0.f};
#pragma unroll
    for (int ct = 0; ct < 4; ++ct)
#pragma unroll
      for (int ks = 0; ks < 3; ++ks) {
        const float4* p = (const float4*)(fc1w + (ct * 16 + m) * 96 + ks * 32 + g * 8);
        float4 a = p[0], b = p[1];
        union { unsigned u[4]; bf16x8 h; } tw;
        tw.u[0] = pkbf(a.x, a.y); tw.u[1] = pkbf(a.z, a.w);
        tw.u[2] = pkbf(b.x, b.y); tw.u[3] = pkbf(b.z, b.w);
        accx[ct] = __builtin_amdgcn_mfma_f32_16x16x32_bf16(af[ks], tw.h, accx[ct], 0, 0, 0);
      }
#pragma unroll
    for (int ct = 0; ct < 4; ++ct) {
      int c = ct * 16 + m;
      float bc = fc1b[c];
#pragma unroll
      for (int reg = 0; reg < 4; ++reg) {
        int nl = w * 16 + g * 4 + reg;
        float v = fmaxf(accx[ct][reg] + bc, 0.f);
        xS[nl * 72 + c] = (short)((__float_as_uint(v) + 0x8000u) >> 16);
      }
    }
  }
  __syncthreads();   // xS ready + gU ready

  // ---- GRU phase ----
  bf16x8 ax[2], ah[2];
#pragma unroll
  for (int ks = 0; ks < 2; ++ks) {
    ax[ks] = *(const bf16x8*)(xS + (w * 16 + m) * 72 + ks * 32 + g * 8);
    const float4* p = (const float4*)(hprev + (size_t)rowA * 64 + ks * 32 + g * 8);
    float4 a = p[0], b = p[1];
    union { unsigned u[4]; bf16x8 h; } tw;
    tw.u[0] = pkbf(a.x, a.y); tw.u[1] = pkbf(a.z, a.w);
    tw.u[2] = pkbf(b.x, b.y); tw.u[3] = pkbf(b.z, b.w);
    ah[ks] = tw.h;
  }
  const short* gS = (const short*)gU;
  float hc[4][4];
#pragma unroll 1
  for (int ct = 0; ct < 4; ++ct) {
    f32x4 a_ir = (f32x4){0.f,0.f,0.f,0.f}, a_iz = (f32x4){0.f,0.f,0.f,0.f},
          a_in = (f32x4){0.f,0.f,0.f,0.f}, a_hr = (f32x4){0.f,0.f,0.f,0.f},
          a_hz = (f32x4){0.f,0.f,0.f,0.f}, a_hn = (f32x4){0.f,0.f,0.f,0.f};
    int crow = ct * 16 + m;
#pragma unroll
    for (int ks = 0; ks < 2; ++ks) {
      bf16x8 b0 = *(const bf16x8*)(gS + (0 * 64 + crow) * 72 + ks * 32 + g * 8);
      bf16x8 b1 = *(const bf16x8*)(gS + (1 * 64 + crow) * 72 + ks * 32 + g * 8);
      bf16x8 b2 = *(const bf16x8*)(gS + (2 * 64 + crow) * 72 + ks * 32 + g * 8);
      bf16x8 b3 = *(const bf16x8*)(gS + (3 * 64 + crow) * 72 + ks * 32 + g * 8);
      bf16x8 b4 = *(const bf16x8*)(gS + (4 * 64 + crow) * 72 + ks * 32 + g * 8);
      bf16x8 b5 = *(const bf16x8*)(gS + (5 * 64 + crow) * 72 + ks * 32 + g * 8);
      a_ir = __builtin_amdgcn_mfma_f32_16x16x32_bf16(ax[ks], b0, a_ir, 0, 0, 0);
      a_iz = __builtin_amdgcn_mfma_f32_16x16x32_bf16(ax[ks], b1, a_iz, 0, 0, 0);
      a_in = __builtin_amdgcn_mfma_f32_16x16x32_bf16(ax[ks], b2, a_in, 0, 0, 0);
      a_hr = __builtin_amdgcn_mfma_f32_16x16x32_bf16(ah[ks], b3, a_hr, 0, 0, 0);
      a_hz = __builtin_amdgcn_mfma_f32_16x16x32_bf16(ah[ks], b4, a_hz, 0, 0, 0);
      a_hn = __builtin_amdgcn_mfma_f32_16x16x32_bf16(ah[ks], b5, a_hn, 0, 0, 0);
    }
    float bir = bih[crow], biz = bih[64 + crow], bin = bih[128 + crow];
    float bhr = bhh[crow], bhz = bhh[64 + crow], bhn = bhh[128 + crow];
#pragma unroll
    for (int reg = 0; reg < 4; ++reg) {
      int nl = w * 16 + g * 4 + reg;
      float hv = hprev[(size_t)(n0 + nl) * 64 + crow];
      float r  = sigmoidf_(a_ir[reg] + bir + a_hr[reg] + bhr);
      float z  = sigmoidf_(a_iz[reg] + biz + a_hz[reg] + bhz);
      float nn = tanhf(a_in[reg] + bin + r * (a_hn[reg] + bhn));
      hc[ct][reg] = (1.f - z) * nn + z * hv;
    }
  }
  __syncthreads();   // all waves done reading gU before trF overlay
#pragma unroll
  for (int ct = 0; ct < 4; ++ct)
#pragma unroll
    for (int reg = 0; reg < 4; ++reg)
      trF[(ct * 16 + m) * 133 + w * 16 + g * 4 + reg] = hc[ct][reg];
  __syncthreads();
#pragma unroll
  for (int i = 0; i < 16; ++i) {
    int idx = t + 512 * i;
    int nl = idx & 127, cl = idx >> 7;
    hT[(size_t)cl * NROW + n0 + nl] = trF[cl * 133 + nl];
  }
#pragma unroll
  for (int i = 0; i < 16; ++i) {
    int idx = t + 512 * i;
    int c = idx & 63, nl = idx >> 6;
    hout[(size_t)(n0 + nl) * 64 + c] = trF[c * 133 + nl];
  }
}

// K3 (MFMA): 96-channel fused head GEMM (fc2 16 + qk 16 + ew1 64), K=64.
// Staging de-serialized: batched h loads; copy-rows pass + dedicated qk pass.
__global__ __launch_bounds__(256) void k_heads(const float* __restrict__ hT,
    const float* __restrict__ fc2w, const float* __restrict__ fc2b,
    const float* __restrict__ wqw, const float* __restrict__ wkw,
    const float* __restrict__ ew1, const float* __restrict__ eb1,
    float* __restrict__ qT, float* __restrict__ qkT, float* __restrict__ z1T,
    float* __restrict__ part) {
  __shared__ char smem[36864];
  const int t = threadIdx.x;
  const int n0 = blockIdx.x * 128;
  unsigned* hU = (unsigned*)smem;                 // [128][36]
  unsigned* wU = (unsigned*)(smem + 18432);       // [96][36]
  float* sp1 = (float*)(smem + 18432 + 13824);    // [4][64]
  float* sp2 = sp1 + 256;                         // [4][64]
  const float qs = 0.17677669529663687f;          // 1/sqrt(32)

  {  // h staging: batched loads
    float va[16], vb[16];
#pragma unroll
    for (int i = 0; i < 16; ++i) {
      int idx = t + 256 * i;
      int nl = idx & 127, kp = idx >> 7;
      va[i] = hT[(size_t)(2 * kp) * NROW + n0 + nl];
      vb[i] = hT[(size_t)(2 * kp + 1) * NROW + n0 + nl];
    }
#pragma unroll
    for (int i = 0; i < 16; ++i) {
      int idx = t + 256 * i;
      int nl = idx & 127, kp = idx >> 7;
      hU[nl * 36 + kp] = pkbf(va[i], vb[i]);
    }
  }
  {  // weight copies: fc2 (wU rows 0..15) + ew1 (wU rows 32..95)
    float2 wv[10];
#pragma unroll
    for (int i = 0; i < 10; ++i) {
      int idx = t + 256 * i;            // 0..2559
      int kp = idx & 31, cl = idx >> 5; // 0..79
      const float* src = (cl < 16) ? (fc2w + cl * 64) : (ew1 + (cl - 16) * 64);
      wv[i] = *(const float2*)(src + 2 * kp);
    }
#pragma unroll
    for (int i = 0; i < 10; ++i) {
      int idx = t + 256 * i;
      int kp = idx & 31, cl = idx >> 5;
      int dst = (cl < 16) ? cl : (cl + 16);
      wU[dst * 36 + kp] = pkbf(wv[i].x, wv[i].y);
    }
  }
  {  // qk rows (wU rows 16..31): qs * Wk^T Wq, inner loop unrolled
    int kp = t & 31, ll = t >> 5;   // ll 0..7; rows ll, ll+8
#pragma unroll
    for (int h = 0; h < 2; ++h) {
      int row = ll + 8 * h;
      float s0 = 0.f, s1 = 0.f;
#pragma unroll
      for (int a = 0; a < 32; ++a) {
        float wk = wkw[a * 16 + row];
        s0 = fmaf(wk, wqw[a * 64 + 2 * kp], s0);
        s1 = fmaf(wk, wqw[a * 64 + 2 * kp + 1], s1);
      }
      wU[(16 + row) * 36 + kp] = pkbf(s0 * qs, s1 * qs);
    }
  }
  __syncthreads();

  const int w = t >> 6, l = t & 63;
  const int m = l & 15, g = l >> 4;
  const short* sH = (const short*)hU;
  const short* sW = (const short*)wU;

  bf16x8 af[2][2];
#pragma unroll
  for (int mt = 0; mt < 2; ++mt)
#pragma unroll
    for (int ks = 0; ks < 2; ++ks)
      af[mt][ks] = *(const bf16x8*)(sH + (w * 32 + mt * 16 + m) * 72 + ks * 32 + g * 8);

  f32x4 acc[2][6];
#pragma unroll
  for (int mt = 0; mt < 2; ++mt)
#pragma unroll
    for (int ct = 0; ct < 6; ++ct) acc[mt][ct] = (f32x4){0.f, 0.f, 0.f, 0.f};
#pragma unroll
  for (int ct = 0; ct < 6; ++ct)
#pragma unroll
    for (int ks = 0; ks < 2; ++ks) {
      bf16x8 bw = *(const bf16x8*)(sW + (ct * 16 + m) * 72 + ks * 32 + g * 8);
#pragma unroll
      for (int mt = 0; mt < 2; ++mt)
        acc[mt][ct] = __builtin_amdgcn_mfma_f32_16x16x32_bf16(af[mt][ks], bw, acc[mt][ct], 0, 0, 0);
    }

  float s1[4], s2[4];
#pragma unroll
  for (int zt = 0; zt < 4; ++zt) { s1[zt] = 0.f; s2[zt] = 0.f; }
#pragma unroll
  for (int mt = 0; mt < 2; ++mt) {
    int nb = n0 + w * 32 + mt * 16 + g * 4;
    {  // q head: c = m
      float bc = fc2b[m];
      f32x4 v;
#pragma unroll
      for (int reg = 0; reg < 4; ++reg) v[reg] = acc[mt][0][reg] + bc;
      *(f32x4*)(qT + (size_t)m * NROW + nb) = v;
    }
    // qk head: l' = m, no bias
    *(f32x4*)(qkT + (size_t)m * NROW + nb) = acc[mt][1];
#pragma unroll
    for (int ct = 2; ct < 6; ++ct) {  // z1 head: z = (ct-2)*16 + m
      int z = (ct - 2) * 16 + m;
      float bc = eb1[z];
      f32x4 v;
#pragma unroll
      for (int reg = 0; reg < 4; ++reg) {
        float zv = acc[mt][ct][reg] + bc;
        v[reg] = zv;
        s1[ct - 2] += zv;
        s2[ct - 2] = fmaf(zv, zv, s2[ct - 2]);
      }
      *(f32x4*)(z1T + (size_t)z * NROW + nb) = v;
    }
  }
#pragma unroll
  for (int zt = 0; zt < 4; ++zt) {
    s1[zt] += __shfl_down(s1[zt], 16, 64);
    s1[zt] += __shfl_down(s1[zt], 32, 64);
    s2[zt] += __shfl_down(s2[zt], 16, 64);
    s2[zt] += __shfl_down(s2[zt], 32, 64);
  }
  if (l < 16) {
#pragma unroll
    for (int zt = 0; zt < 4; ++zt) {
      sp1[w * 64 + zt * 16 + m] = s1[zt];
      sp2[w * 64 + zt * 16 + m] = s2[zt];
    }
  }
  __syncthreads();
  if (t < 64) {
    float a1 = sp1[t] + sp1[64 + t] + sp1[128 + t] + sp1[192 + t];
    float a2 = sp2[t] + sp2[64 + t] + sp2[128 + t] + sp2[192 + t];
    part[(size_t)blockIdx.x * 128 + t] = a1;
    part[(size_t)blockIdx.x * 128 + 64 + t] = a2;
  }
}

// K4: finalize BN stats (256 head blocks)
__global__ void k_bnstat(const float* __restrict__ part,
    const float* __restrict__ bng, const float* __restrict__ bnb,
    float* __restrict__ stat) {
  int c = threadIdx.x;  // 64 threads
  float s1 = 0.f, s2 = 0.f;
  for (int b = 0; b < 256; ++b) {
    s1 += part[(size_t)b * 128 + c];
    s2 += part[(size_t)b * 128 + 64 + c];
  }
  float mean = s1 * (1.f / NROW);
  float var = s2 * (1.f / NROW) - mean * mean;
  float rstd = rsqrtf(var + 1e-5f);
  float sc = bng[c] * rstd;
  stat[c] = sc;
  stat[64 + c] = bnb[c] - mean * sc;
}

// K5 (v5): MFMA bf16 GEMM -> bf16 latent. Staging de-serialized (batched loads);
// eps prefetch issued after barrier (flies under ds_read+MFMA);
// f32 LDS transpose + coalesced u32 pkbf stores; std = max(exp(0.5*lv), sqrt(.002)).
__global__ __launch_bounds__(256) void k_emb_gemm(const float* __restrict__ z1T,
    const float* __restrict__ stat,
    const float* __restrict__ ew2, const float* __restrict__ eb2,
    const float* __restrict__ eps,
    unsigned* __restrict__ latB16g) {
  __shared__ char smem[36864];
  const int t = threadIdx.x;
  const int nb = blockIdx.x >> 3;
  const int cb = blockIdx.x & 7;
  const int n0 = nb * 128;
  const int c0 = cb * 64;

  unsigned* aU = (unsigned*)smem;                 // A: [128][36]
  unsigned* bmU = (unsigned*)(smem + 18432);      // Wmu: [64][36]
  unsigned* blU = (unsigned*)(smem + 27648);      // Wlv: [64][36]

  const int w = t >> 6, l = t & 63;
  const int m = l & 15, g = l >> 4;

  {  // A staging: batched loads (32 in flight), then BN+lrelu pack
    float za[16], zb[16];
#pragma unroll
    for (int i = 0; i < 16; ++i) {
      int idx = t + 256 * i;
      int nl = idx & 127, kp = idx >> 7;
      za[i] = z1T[(size_t)(2 * kp) * NROW + n0 + nl];
      zb[i] = z1T[(size_t)(2 * kp + 1) * NROW + n0 + nl];
    }
#pragma unroll
    for (int i = 0; i < 16; ++i) {
      int idx = t + 256 * i;
      int nl = idx & 127, kp = idx >> 7;
      float v0 = lrelu_(fmaf(stat[2 * kp], za[i], stat[64 + 2 * kp]));
      float v1 = lrelu_(fmaf(stat[2 * kp + 1], zb[i], stat[64 + 2 * kp + 1]));
      aU[nl * 36 + kp] = pkbf(v0, v1);
    }
  }
  {  // W staging: batched loads
    const float2* ew2_2 = (const float2*)ew2;
    float2 wm[8], wl[8];
#pragma unroll
    for (int i = 0; i < 8; ++i) {
      int idx = t + 256 * i;
      int kp = idx & 31, cl = idx >> 5;
      wm[i] = ew2_2[(size_t)(c0 + cl) * 32 + kp];
      wl[i] = ew2_2[(size_t)(512 + c0 + cl) * 32 + kp];
    }
#pragma unroll
    for (int i = 0; i < 8; ++i) {
      int idx = t + 256 * i;
      int kp = idx & 31, cl = idx >> 5;
      bmU[cl * 36 + kp] = pkbf(wm[i].x, wm[i].y);
      blU[cl * 36 + kp] = pkbf(wl[i].x, wl[i].y);
    }
  }
  __syncthreads();

  // eps prefetch: 32 dwords/lane, issued now so they fly under ds_read + MFMA
  float epsR[4][2][4];
#pragma unroll
  for (int ct = 0; ct < 4; ++ct)
#pragma unroll
    for (int mt = 0; mt < 2; ++mt)
#pragma unroll
      for (int reg = 0; reg < 4; ++reg)
        epsR[ct][mt][reg] =
            eps[(size_t)(n0 + w * 32 + mt * 16 + g * 4 + reg) * 512 + c0 + ct * 16 + m];

  const short* sA = (const short*)smem;
  const short* sBm = (const short*)(smem + 18432);
  const short* sBl = (const short*)(smem + 27648);

  f32x4 accm[2][4], accl[2][4];
#pragma unroll
  for (int mt = 0; mt < 2; ++mt)
#pragma unroll
    for (int ct = 0; ct < 4; ++ct) {
      accm[mt][ct] = (f32x4){0.f, 0.f, 0.f, 0.f};
      accl[mt][ct] = (f32x4){0.f, 0.f, 0.f, 0.f};
    }
  bf16x8 af[2][2];
#pragma unroll
  for (int mt = 0; mt < 2; ++mt)
#pragma unroll
    for (int ks = 0; ks < 2; ++ks)
      af[mt][ks] = *(const bf16x8*)(sA + (w * 32 + mt * 16 + m) * 72 + ks * 32 + g * 8);
#pragma unroll
  for (int ct = 0; ct < 4; ++ct) {
#pragma unroll
    for (int ks = 0; ks < 2; ++ks) {
      bf16x8 bm = *(const bf16x8*)(sBm + (ct * 16 + m) * 72 + ks * 32 + g * 8);
      bf16x8 bl = *(const bf16x8*)(sBl + (ct * 16 + m) * 72 + ks * 32 + g * 8);
#pragma unroll
      for (int mt = 0; mt < 2; ++mt) {
        accm[mt][ct] = __builtin_amdgcn_mfma_f32_16x16x32_bf16(af[mt][ks], bm, accm[mt][ct], 0, 0, 0);
        accl[mt][ct] = __builtin_amdgcn_mfma_f32_16x16x32_bf16(af[mt][ks], bl, accl[mt][ct], 0, 0, 0);
      }
    }
  }

  // epilogue: lat in regs, f32 transpose through LDS, coalesced u32 stores
  const float stdfloor = 0.04472135955f;   // sqrt(0.002)
  float lat[2][4][4];
#pragma unroll
  for (int ct = 0; ct < 4; ++ct) {
    int cl = ct * 16 + m;
    float ebm = eb2[c0 + cl], ebl = eb2[DH + c0 + cl];
#pragma unroll
    for (int mt = 0; mt < 2; ++mt)
#pragma unroll
      for (int reg = 0; reg < 4; ++reg) {
        float mu = accm[mt][ct][reg] + ebm;
        float lv = accl[mt][ct][reg] + ebl;
        float sd = fmaxf(__expf(0.5f * lv), stdfloor);
        lat[mt][ct][reg] = fmaf(sd, epsR[ct][mt][reg], mu);
      }
  }
  __syncthreads();
  float* outF = (float*)smem;     // [64][133]
#pragma unroll
  for (int mt = 0; mt < 2; ++mt)
#pragma unroll
    for (int ct = 0; ct < 4; ++ct)
#pragma unroll
      for (int reg = 0; reg < 4; ++reg)
        outF[(ct * 16 + m) * 133 + w * 32 + mt * 16 + g * 4 + reg] = lat[mt][ct][reg];
  __syncthreads();
#pragma unroll
  for (int i = 0; i < 16; ++i) {
    int idx = t + 256 * i;          // 0..4095
    int cp = idx & 31;
    int nl = idx >> 5;
    float v0 = outF[(2 * cp) * 133 + nl];
    float v1 = outF[(2 * cp + 1) * 133 + nl];
    latB16g[(size_t)(n0 + nl) * 256 + cb * 32 + cp] = pkbf(v0, v1);
  }
}

// K7 (MFMA): one block per b. Logit+softmax in-kernel from bf16 latent.
constexpr int LATB_OFF = 0;        // [1024][20] bf16, 40B rows (r = i*32+j)
constexpr int H3B_OFF  = 40960;    // [32][72] bf16, 144B rows
constexpr int W1H_OFF  = 45568;    // [64][72] bf16
constexpr int W1L_OFF  = 54784;    // [64][20] bf16
constexpr int W2P_OFF  = 57344;    // [16][72] bf16 (pi-permuted c)
constexpr int ALL_OFF  = 59648;    // [32][33] f32 alpha
constexpr int MT_OFF   = 63872;    // 4 waves x 2560B private transpose buf
constexpr int QKL_OFF  = 74112;    // [32][20] f32 qk
__global__ __launch_bounds__(256, 1) void k_msg(
    const unsigned* __restrict__ latB16g, const float* __restrict__ qkT,
    const float* __restrict__ qT, const float* __restrict__ hrow,
    const float* __restrict__ w1, const float* __restrict__ b1,
    const float* __restrict__ w2, const float* __restrict__ b2,
    float* __restrict__ out) {
  __shared__ char smem[76672];
  const int t = threadIdx.x;
  const int b = blockIdx.x;
  const int b32 = b * 32;
  unsigned* latB_dw = (unsigned*)(smem + LATB_OFF);

  // ---- staging (batched loads per scope) ----
  {  // latB: bf16 copy, 2 batches of 4 x 16B
    const uint4e* g4 = (const uint4e*)latB16g + (size_t)b32 * 64;
#pragma unroll
    for (int half = 0; half < 2; ++half) {
      uint4e v[4];
#pragma unroll
      for (int it = 0; it < 4; ++it) v[it] = g4[t + 256 * (4 * half + it)];
#pragma unroll
      for (int it = 0; it < 4; ++it) {
        int idx = t + 256 * (4 * half + it);
        int i = idx >> 6;
        int rem = idx & 63;
        int j = rem >> 1, hh = rem & 1;
        unsigned* dst = latB_dw + (i * 32 + j) * 10 + hh * 4;
        *(uint2e*)dst = (uint2e){v[it].x, v[it].y};
        *(uint2e*)(dst + 2) = (uint2e){v[it].z, v[it].w};
      }
    }
  }
  {  // qkL[i][l] from qkT
    float* qkL = (float*)(smem + QKL_OFF);
    int i = t & 31;
    float v0 = qkT[(size_t)((t >> 5)) * NROW + b32 + i];
    float v1 = qkT[(size_t)((t >> 5) + 8) * NROW + b32 + i];
    qkL[i * 20 + (t >> 5)] = v0;
    qkL[i * 20 + (t >> 5) + 8] = v1;
  }
  {  // h3B[j][k] bf16 from row-major h
    int cp = t & 31, jj = t >> 5;
    const float2* h2 = (const float2*)hrow;
    float2 hv[4];
#pragma unroll
    for (int it = 0; it < 4; ++it)
      hv[it] = h2[((size_t)(b32 + jj + 8 * it) * 64 + 2 * cp) >> 1];
    unsigned* dst = (unsigned*)(smem + H3B_OFF);
#pragma unroll
    for (int it = 0; it < 4; ++it)
      dst[(jj + 8 * it) * 36 + cp] = pkbf(hv[it].x, hv[it].y);
  }
  {  // w1hL[c][k] (k<64)
    int kp = t & 31, cc = t >> 5;
    const float2* w12 = (const float2*)w1;
    float2 wv[8];
#pragma unroll
    for (int it = 0; it < 8; ++it)
      wv[it] = w12[((cc + 8 * it) * 80 + 2 * kp) >> 1];
    unsigned* dst = (unsigned*)(smem + W1H_OFF);
#pragma unroll
    for (int it = 0; it < 8; ++it)
      dst[(cc + 8 * it) * 36 + kp] = pkbf(wv[it].x, wv[it].y);
  }
  {  // w1latL[c][l]
    int lp = t & 7, cc = t >> 3;
    const float2* w12 = (const float2*)w1;
    float2 wv[2];
#pragma unroll
    for (int it = 0; it < 2; ++it)
      wv[it] = w12[((cc + 32 * it) * 80 + 64 + 2 * lp) >> 1];
    unsigned* dst = (unsigned*)(smem + W1L_OFF);
#pragma unroll
    for (int it = 0; it < 2; ++it)
      dst[(cc + 32 * it) * 10 + lp] = pkbf(wv[it].x, wv[it].y);
  }
  {  // w2P[nn][p] = w2[nn][c(p)], c(p) = ((p>>2)&3)*16 + (p>>4)*4 + (p&3)
    int pp = t & 31, nn = t >> 5;
    const float2* w22 = (const float2*)w2;
    int p = 2 * pp;
    int c = ((p >> 2) & 3) * 16 + (p >> 4) * 4 + (p & 3);
    float2 wv0 = w22[(nn * 64 + c) >> 1];
    float2 wv1 = w22[((nn + 8) * 64 + c) >> 1];
    unsigned* dst = (unsigned*)(smem + W2P_OFF);
    dst[nn * 36 + pp] = pkbf(wv0.x, wv0.y);
    dst[(nn + 8) * 36 + pp] = pkbf(wv1.x, wv1.y);
  }
  __syncthreads();

  // ---- logits + softmax -> alL (reads latB + qkL) ----
  {
    const float* qkL = (const float*)(smem + QKL_OFF);
    float* alL = (float*)(smem + ALL_OFF);
#pragma unroll 1
    for (int p = 0; p < 4; ++p) {
      int i = (t >> 5) + 8 * p;
      int j = t & 31;
      const unsigned* lr = latB_dw + (i * 32 + j) * 10;
      float acc = 0.f;
#pragma unroll
      for (int d = 0; d < 8; ++d) {
        unsigned u = lr[d];
        float lo = __uint_as_float(u << 16);
        float hi = __uint_as_float(u & 0xffff0000u);
        acc = fmaf(lo, qkL[i * 20 + 2 * d], acc);
        acc = fmaf(hi, qkL[i * 20 + 2 * d + 1], acc);
      }
      if (j == i) acc = -1e9f;
      float mx = acc;
#pragma unroll
      for (int msk = 16; msk > 0; msk >>= 1) mx = fmaxf(mx, __shfl_xor(mx, msk, 32));
      float e = __expf(acc - mx);
      float s = e;
#pragma unroll
      for (int msk = 16; msk > 0; msk >>= 1) s += __shfl_xor(s, msk, 32);
      alL[i * 33 + j] = e / s;
    }
  }

  const int w = t >> 6, l = t & 63;
  const int n15 = l & 15, q = l >> 4;
  const int jh = w & 1, ibase = (w >> 1) * 16;
  const bool kact = (q < 2);

  // ---- phase 1: hp[ct][reg] for (c = ct*16+q*4+reg, j = jh*16+n15) ----
  f32x4 hp[4];
#pragma unroll
  for (int ct = 0; ct < 4; ++ct) hp[ct] = (f32x4){0.f, 0.f, 0.f, 0.f};
#pragma unroll
  for (int ct = 0; ct < 4; ++ct)
#pragma unroll
    for (int ks = 0; ks < 2; ++ks) {
      bf16x8 aF = *(const bf16x8*)(smem + W1H_OFF + (ct * 16 + n15) * 144 + ks * 64 + q * 16);
      bf16x8 bF = *(const bf16x8*)(smem + H3B_OFF + (jh * 16 + n15) * 144 + ks * 64 + q * 16);
      hp[ct] = __builtin_amdgcn_mfma_f32_16x16x32_bf16(aF, bF, hp[ct], 0, 0, 0);
    }
#pragma unroll
  for (int ct = 0; ct < 4; ++ct)
#pragma unroll
    for (int reg = 0; reg < 4; ++reg)
      hp[ct][reg] += b1[ct * 16 + q * 4 + reg];

  // hoisted fragments
  bf16x8 aL[4];
#pragma unroll
  for (int ct = 0; ct < 4; ++ct) {
    union { unsigned u[4]; bf16x8 h; } tmp;
    tmp.u[0] = tmp.u[1] = tmp.u[2] = tmp.u[3] = 0u;
    if (kact) {
      const unsigned* p = (const unsigned*)(smem + W1L_OFF) + (ct * 16 + n15) * 10 + q * 4;
      uint2e d0 = *(const uint2e*)p;
      uint2e d1 = *(const uint2e*)(p + 2);
      tmp.u[0] = d0.x; tmp.u[1] = d0.y; tmp.u[2] = d1.x; tmp.u[3] = d1.y;
    }
    aL[ct] = tmp.h;
  }
  bf16x8 w2F[2];
#pragma unroll
  for (int ks = 0; ks < 2; ++ks)
    w2F[ks] = *(const bf16x8*)(smem + W2P_OFF + n15 * 144 + ks * 64 + q * 16);
  float b2v[4];
#pragma unroll
  for (int reg = 0; reg < 4; ++reg) b2v[reg] = b2[q * 4 + reg];

  __syncthreads();  // alL complete before main loop reads it

  // ---- main i loop ----
  float agg[4] = {0.f, 0.f, 0.f, 0.f};
  char* wb = smem + MT_OFF + w * 2560;
  const float* alLf = (const float*)(smem + ALL_OFF);
#pragma unroll 1
  for (int it = 0; it < 16; ++it) {
    int ii = ibase + it;
    int r = ii * 32 + jh * 16 + n15;
    union { unsigned u[4]; bf16x8 h; } latF;
    latF.u[0] = latF.u[1] = latF.u[2] = latF.u[3] = 0u;
    if (kact) {
      const unsigned* p = latB_dw + r * 10 + q * 4;
      uint2e d0 = *(const uint2e*)p;
      uint2e d1 = *(const uint2e*)(p + 2);
      latF.u[0] = d0.x; latF.u[1] = d0.y; latF.u[2] = d1.x; latF.u[3] = d1.y;
    }
    f32x4 acc[4];
#pragma unroll
    for (int ct = 0; ct < 4; ++ct) {
      acc[ct] = (f32x4){0.f, 0.f, 0.f, 0.f};
      acc[ct] = __builtin_amdgcn_mfma_f32_16x16x32_bf16(aL[ct], latF.h, acc[ct], 0, 0, 0);
    }
    // lrelu + pack + pi-transpose write (per-wave private buffer, no barrier)
#pragma unroll
    for (int h = 0; h < 2; ++h) {
      float m0[4], m1[4];
#pragma unroll
      for (int reg = 0; reg < 4; ++reg) {
        float v0 = acc[2 * h][reg] + hp[2 * h][reg];
        float v1 = acc[2 * h + 1][reg] + hp[2 * h + 1][reg];
        m0[reg] = fmaxf(v0, 0.01f * v0);
        m1[reg] = fmaxf(v1, 0.01f * v1);
      }
      uint4e pk4;
      pk4.x = pkbf(m0[0], m0[1]); pk4.y = pkbf(m0[2], m0[3]);
      pk4.z = pkbf(m1[0], m1[1]); pk4.w = pkbf(m1[2], m1[3]);
      int qp = (2 * q + h) & 3;
      *(uint4e*)(wb + (q >> 1) * 1280 + n15 * 80 + qp * 16) = pk4;
    }
    // phase 3
    f32x4 msg = (f32x4){0.f, 0.f, 0.f, 0.f};
#pragma unroll
    for (int ks = 0; ks < 2; ++ks) {
      bf16x8 mF = *(const bf16x8*)(wb + ks * 1280 + n15 * 80 + q * 16);
      msg = __builtin_amdgcn_mfma_f32_16x16x32_bf16(w2F[ks], mF, msg, 0, 0, 0);
    }
    float aw = alLf[ii * 33 + jh * 16 + n15];
#pragma unroll
    for (int reg = 0; reg < 4; ++reg)
      agg[reg] = fmaf(aw, msg[reg] + b2v[reg], agg[reg]);
  }
  // park agg in own wave buffer
  {
    f32x4 av; av[0] = agg[0]; av[1] = agg[1]; av[2] = agg[2]; av[3] = agg[3];
    *(f32x4*)(wb + n15 * 80 + q * 16) = av;
  }
  __syncthreads();
  // combine wave pairs (i-low + i-high) and add q head
#pragma unroll
  for (int tt = 0; tt < 2; ++tt) {
    int idx = t + 256 * tt;
    int jg = idx >> 4, nn = idx & 15;
    int jh2 = jg >> 4, jl = jg & 15;
    float a0 = *(const float*)(smem + MT_OFF + jh2 * 2560 + jl * 80 + nn * 4);
    float a1 = *(const float*)(smem + MT_OFF + (jh2 + 2) * 2560 + jl * 80 + nn * 4);
    out[(size_t)b * 512 + idx] = a0 + a1 + qT[(size_t)nn * NROW + b32 + jg];
  }
}

}  // namespace

extern "C" void kernel_launch(void* const* d_in, const int* in_sizes, int n_in,
                              void* d_out, int out_size, void* d_ws, size_t ws_size,
                              hipStream_t stream) {
  (void)in_sizes; (void)n_in; (void)out_size; (void)ws_size;
  const float* inputs = (const float*)d_in[0];
  const float* hidden = (const float*)d_in[1];
  const float* eps    = (const float*)d_in[2];
  const float* fc1w   = (const float*)d_in[3];
  const float* fc1b   = (const float*)d_in[4];
  const float* wih    = (const float*)d_in[5];
  const float* whh    = (const float*)d_in[6];
  const float* bih    = (const float*)d_in[7];
  const float* bhh    = (const float*)d_in[8];
  const float* fc2w   = (const float*)d_in[9];
  const float* fc2b   = (const float*)d_in[10];
  const float* ew1    = (const float*)d_in[11];
  const float* eb1    = (const float*)d_in[12];
  const float* bng    = (const float*)d_in[13];
  const float* bnb    = (const float*)d_in[14];
  const float* ew2    = (const float*)d_in[15];
  const float* eb2    = (const float*)d_in[16];
  const float* w1     = (const float*)d_in[17];
  const float* b1     = (const float*)d_in[18];
  const float* w2     = (const float*)d_in[19];
  const float* b2     = (const float*)d_in[20];
  const float* wqw    = (const float*)d_in[21];
  const float* wkw    = (const float*)d_in[23];

  float* ws = (float*)d_ws;
  float* hT     = ws;                 // 2097152
  float* qT     = ws + 2097152;       // 524288
  float* qkT    = ws + 2621440;       // 524288
  float* z1T    = ws + 3670016;       // 2097152
  float* part   = ws + 5767168;       // 32768 used
  float* stat   = ws + 5832704;       // 128
  unsigned* latB16g = (unsigned*)(ws + 5832832);  // [N][256] u32 (bf16 pairs)

  float* out_q = (float*)d_out;             // 32768 x 16
  float* out_h = (float*)d_out + 524288;    // 32768 x 64

  hipLaunchKernelGGL(k_fgru, dim3(256), dim3(512), 0, stream,
                     inputs, hidden, fc1w, fc1b, wih, whh, bih, bhh, hT, out_h);
  hipLaunchKernelGGL(k_heads, dim3(256), dim3(256), 0, stream,
                     hT, fc2w, fc2b, wqw, wkw, ew1, eb1, qT, qkT, z1T, part);
  hipLaunchKernelGGL(k_bnstat, dim3(1), dim3(64), 0, stream, part, bng, bnb, stat);
  hipLaunchKernelGGL(k_emb_gemm, dim3(2048), dim3(256), 0, stream, z1T, stat, ew2, eb2, eps, latB16g);
  hipLaunchKernelGGL(k_msg, dim3(1024), dim3(256), 0, stream,
                     latB16g, qkT, qT, out_h, w1, b1, w2, b2, out_q);
}